// Round 1
// baseline (697.349 us; speedup 1.0000x reference)
//
#include <hip/hip_runtime.h>

// PointNetRot9d: conv1x1(3->64)+BN+relu -> (64->128)+BN+relu -> (128->1024)+BN
// -> maxpool(N) -> FC(1024->512)+BN+relu -> FC(512->256)+BN+relu -> FC(256->12)
// -> SO(3) projection of p[:, :9] (Horn quaternion method == SVD projection) -> [B,4,4].
//
// Design notes (round 1, correctness-first fp32 baseline):
//  - BN training stats (mean/var over B*N per channel) via block-partial + atomicAdd
//    into a zeroed ws region; finalize kernels fold BN into per-channel (a, s);
//    consumers apply relu(a*y + s) on load (no standalone elementwise passes).
//  - conv3 (17.2 GFLOP, fp32 vector ALU: no fp32 MFMA on CDNA4) never materializes
//    its 268 MB output: each block owns (b, 128-channel o-tile), loops all n,
//    tracks per-(b,o) max/min and per-o sum/sumsq in registers.
//  - maxpool commutes with the BN affine per scale sign: use max if a>=0 else min.
//  - SVD-free orthogonalization: dominant eigenvector of Horn's 4x4 N(M) via
//    16 shifted matrix squarings (convergence ratio^65536), q -> R(q), det=+1.

#define NPT 2048
#define C1 64
#define C2 128
#define EPSV 1e-5f

// ---- workspace layout (float offsets) ----
#define OFF_Y1    0               // 32*64*2048   = 4194304
#define OFF_Y2    4194304         // 32*128*2048  = 8388608
#define OFF_Z     12582912        // zeroed stats region start
#define ZN        3968
#define OFF_SUM1  (OFF_Z)
#define OFF_SQ1   (OFF_Z+64)
#define OFF_SUM2  (OFF_Z+128)
#define OFF_SQ2   (OFF_Z+256)
#define OFF_SUM3  (OFF_Z+384)
#define OFF_SQ3   (OFF_Z+1408)
#define OFF_SUMF1 (OFF_Z+2432)
#define OFF_SQF1  (OFF_Z+2944)
#define OFF_SUMF2 (OFF_Z+3456)
#define OFF_SQF2  (OFF_Z+3712)
#define OFF_A1    (OFF_Z+3968)
#define OFF_S1    (OFF_A1+64)
#define OFF_A2    (OFF_A1+128)
#define OFF_S2    (OFF_A1+256)
#define OFF_A3    (OFF_A1+384)
#define OFF_S3    (OFF_A1+1408)
#define OFF_AF1   (OFF_A1+2432)
#define OFF_SF1   (OFF_AF1+512)
#define OFF_AF2   (OFF_AF1+1024)
#define OFF_SF2   (OFF_AF1+1280)
#define OFF_MX    (OFF_AF1+1536)
#define OFF_MN    (OFF_MX+32768)
#define OFF_POOL  (OFF_MX+65536)
#define OFF_F1R   (OFF_MX+98304)
#define OFF_F2R   (OFF_F1R+16384)
#define OFF_W3T   (OFF_F2R+8192)      // 131072 floats
#define WS_FLOATS (OFF_W3T+131072)    // 12,844,800 floats = 51.4 MB

// conv1: y1[b,o,n] = sum_d w1[o,d]*x[b,d,n] + b1[o]; per-channel sum/sumsq.
// Block covers 256 consecutive float4 within one (b,o) row -> o uniform per block.
__global__ __launch_bounds__(256) void k_conv1(const float* __restrict__ x,
    const float* __restrict__ w1, const float* __restrict__ b1,
    float* __restrict__ y1, float* __restrict__ sum1, float* __restrict__ sq1)
{
  int idx4 = blockIdx.x * 256 + threadIdx.x;     // f4 index into [32][64][2048]
  int n4 = idx4 & 511;
  int o  = (idx4 >> 9) & 63;
  int b  = idx4 >> 15;
  const float4* xr = (const float4*)(x + (size_t)b * 3 * NPT);
  float4 x0 = xr[n4], x1 = xr[512 + n4], x2 = xr[1024 + n4];
  float wa = w1[o*3], wb = w1[o*3+1], wc = w1[o*3+2], bb = b1[o];
  float4 v;
  v.x = fmaf(wa, x0.x, fmaf(wb, x1.x, fmaf(wc, x2.x, bb)));
  v.y = fmaf(wa, x0.y, fmaf(wb, x1.y, fmaf(wc, x2.y, bb)));
  v.z = fmaf(wa, x0.z, fmaf(wb, x1.z, fmaf(wc, x2.z, bb)));
  v.w = fmaf(wa, x0.w, fmaf(wb, x1.w, fmaf(wc, x2.w, bb)));
  ((float4*)y1)[idx4] = v;
  float s = v.x + v.y + v.z + v.w;
  float q = v.x*v.x + v.y*v.y + v.z*v.z + v.w*v.w;
  for (int off = 32; off; off >>= 1) { s += __shfl_down(s, off); q += __shfl_down(q, off); }
  __shared__ float red[8];
  int lane = threadIdx.x & 63, wv = threadIdx.x >> 6;
  if (!lane) { red[wv] = s; red[4 + wv] = q; }
  __syncthreads();
  if (!threadIdx.x) {
    atomicAdd(&sum1[o], red[0] + red[1] + red[2] + red[3]);
    atomicAdd(&sq1[o],  red[4] + red[5] + red[6] + red[7]);
  }
}

// Fold BN into per-channel affine: a = g*rsqrt(var+eps), s = be - a*mean.
__global__ void k_finalize(const float* __restrict__ sum, const float* __restrict__ sq,
    const float* __restrict__ g, const float* __restrict__ be,
    float* __restrict__ a, float* __restrict__ s, int C, float invc)
{
  int c = blockIdx.x * blockDim.x + threadIdx.x;
  if (c >= C) return;
  float m = sum[c] * invc;
  float v = fmaf(-m, m, sq[c] * invc);
  float ia = g[c] * rsqrtf(v + EPSV);
  a[c] = ia;
  s[c] = fmaf(-ia, m, be[c]);
}

// conv2: y2[b,o,n] = sum_c w2[o,c]*relu(a1[c]*y1[b,c,n]+s1[c]) + b2[o]; stats2.
// Block: (b, 16-o tile, 256-n tile); 4o x 4n per thread; K=64 in 2 LDS chunks.
__global__ __launch_bounds__(256) void k_conv2(const float* __restrict__ y1,
    const float* __restrict__ w2, const float* __restrict__ b2,
    const float* __restrict__ a1, const float* __restrict__ s1,
    float* __restrict__ y2, float* __restrict__ sum2, float* __restrict__ sq2)
{
  __shared__ float h1s[32 * 256];
  __shared__ float w2s[64 * 20];   // [c][16o] pad->20: inner read is wave-uniform broadcast
  int t = threadIdx.x;
  int bi = blockIdx.x;
  int nt = bi & 7, ot = (bi >> 3) & 7, b = bi >> 6;
  int n0 = nt * 256, o0 = ot * 16;
  for (int i = 0; i < 4; ++i) {
    int idx = t + i * 256;                 // 1024 elements
    int oj = idx >> 6, c = idx & 63;
    w2s[c * 20 + oj] = w2[(o0 + oj) * 64 + c];
  }
  int to = t >> 6, tn = t & 63;            // to = wave id (4), tn = lane (64)
  float acc[4][4];
  #pragma unroll
  for (int j = 0; j < 4; ++j)
    #pragma unroll
    for (int k = 0; k < 4; ++k) acc[j][k] = 0.f;
  for (int kc = 0; kc < 2; ++kc) {
    __syncthreads();
    for (int i = 0; i < 8; ++i) {
      int idx = t + i * 256;               // 2048 f4
      int cl = idx >> 6, n4 = idx & 63;
      int c = kc * 32 + cl;
      float4 v = *(const float4*)(y1 + (size_t)b * C1 * NPT + (size_t)c * NPT + n0 + n4 * 4);
      float a = a1[c], sf = s1[c];
      v.x = fmaxf(fmaf(a, v.x, sf), 0.f);
      v.y = fmaxf(fmaf(a, v.y, sf), 0.f);
      v.z = fmaxf(fmaf(a, v.z, sf), 0.f);
      v.w = fmaxf(fmaf(a, v.w, sf), 0.f);
      *(float4*)&h1s[cl * 256 + n4 * 4] = v;
    }
    __syncthreads();
    #pragma unroll 8
    for (int cl = 0; cl < 32; ++cl) {
      float4 hv = *(const float4*)&h1s[cl * 256 + tn * 4];
      float4 wv = *(const float4*)&w2s[(kc * 32 + cl) * 20 + to * 4];
      float hr[4] = {hv.x, hv.y, hv.z, hv.w};
      float wr[4] = {wv.x, wv.y, wv.z, wv.w};
      #pragma unroll
      for (int j = 0; j < 4; ++j)
        #pragma unroll
        for (int k = 0; k < 4; ++k) acc[j][k] = fmaf(wr[j], hr[k], acc[j][k]);
    }
  }
  #pragma unroll
  for (int j = 0; j < 4; ++j) {
    int o = o0 + to * 4 + j;
    float bb = b2[o];
    float4 v;
    v.x = acc[j][0] + bb; v.y = acc[j][1] + bb; v.z = acc[j][2] + bb; v.w = acc[j][3] + bb;
    *(float4*)(y2 + (size_t)b * C2 * NPT + (size_t)o * NPT + n0 + tn * 4) = v;
    float s = v.x + v.y + v.z + v.w;
    float q = v.x*v.x + v.y*v.y + v.z*v.z + v.w*v.w;
    for (int off = 32; off; off >>= 1) { s += __shfl_down(s, off); q += __shfl_down(q, off); }
    if (tn == 0) { atomicAdd(&sum2[o], s); atomicAdd(&sq2[o], q); }
  }
}

// One-time transpose w3 [1024][128] -> w3t [128][1024] (coalesced stores).
__global__ __launch_bounds__(256) void k_tw3(const float* __restrict__ w3, float* __restrict__ w3t)
{
  int idx = blockIdx.x * 256 + threadIdx.x;   // 131072, grid 512
  int c = idx >> 10, o = idx & 1023;
  w3t[idx] = w3[o * 128 + c];
}

// conv3: block = (b, 128-o tile); loops all 2048 n in 64-chunks; K=128 in 2x64 LDS chunks.
// Tracks per-(b,o) max/min (for pooling) and per-o sum/sumsq (for BN3); y3 never stored.
__global__ __launch_bounds__(256) void k_conv3(const float* __restrict__ y2,
    const float* __restrict__ w3t, const float* __restrict__ b3,
    const float* __restrict__ a2, const float* __restrict__ s2,
    float* __restrict__ mxb, float* __restrict__ mnb,
    float* __restrict__ sum3, float* __restrict__ sq3)
{
  __shared__ float w3s[64 * 132];  // [c][128o] pad->132 (inner read: 4 addrs -> 32 banks)
  __shared__ float h2s[64 * 64];   // [c][64n]
  int t = threadIdx.x;
  int bi = blockIdx.x;
  int ot = bi & 7, b = bi >> 3;
  int o0 = ot * 128;
  int to = t >> 4, tn = t & 15;    // 16 o-groups x 8, 16 n-groups x 4
  float breg[8], mx[8], mn[8], sm[8], sq[8];
  #pragma unroll
  for (int j = 0; j < 8; ++j) {
    breg[j] = b3[o0 + to * 8 + j];
    mx[j] = -3.4e38f; mn[j] = 3.4e38f; sm[j] = 0.f; sq[j] = 0.f;
  }
  for (int nc = 0; nc < 32; ++nc) {
    int n0 = nc * 64;
    float acc[8][4];
    #pragma unroll
    for (int j = 0; j < 8; ++j)
      #pragma unroll
      for (int k = 0; k < 4; ++k) acc[j][k] = 0.f;
    for (int kc = 0; kc < 2; ++kc) {
      __syncthreads();
      for (int i = 0; i < 8; ++i) {
        int idx = t + i * 256;            // 2048 f4: w3s stage
        int c = idx >> 5, o4 = idx & 31;
        *(float4*)&w3s[c * 132 + o4 * 4] =
            *(const float4*)(w3t + (size_t)(kc * 64 + c) * 1024 + o0 + o4 * 4);
      }
      for (int i = 0; i < 4; ++i) {
        int idx = t + i * 256;            // 1024 f4: h2s stage with BN2+relu
        int c = idx >> 4, n4 = idx & 15;
        int cg = kc * 64 + c;
        float4 v = *(const float4*)(y2 + (size_t)b * C2 * NPT + (size_t)cg * NPT + n0 + n4 * 4);
        float a = a2[cg], sf = s2[cg];
        v.x = fmaxf(fmaf(a, v.x, sf), 0.f);
        v.y = fmaxf(fmaf(a, v.y, sf), 0.f);
        v.z = fmaxf(fmaf(a, v.z, sf), 0.f);
        v.w = fmaxf(fmaf(a, v.w, sf), 0.f);
        *(float4*)&h2s[c * 64 + n4 * 4] = v;
      }
      __syncthreads();
      #pragma unroll 4
      for (int c = 0; c < 64; ++c) {
        float4 w0 = *(const float4*)&w3s[c * 132 + to * 8];
        float4 w1 = *(const float4*)&w3s[c * 132 + to * 8 + 4];
        float4 hv = *(const float4*)&h2s[c * 64 + tn * 4];
        float wr[8] = {w0.x, w0.y, w0.z, w0.w, w1.x, w1.y, w1.z, w1.w};
        float hr[4] = {hv.x, hv.y, hv.z, hv.w};
        #pragma unroll
        for (int j = 0; j < 8; ++j)
          #pragma unroll
          for (int k = 0; k < 4; ++k) acc[j][k] = fmaf(wr[j], hr[k], acc[j][k]);
      }
    }
    #pragma unroll
    for (int j = 0; j < 8; ++j)
      #pragma unroll
      for (int k = 0; k < 4; ++k) {
        float v = acc[j][k] + breg[j];
        mx[j] = fmaxf(mx[j], v);
        mn[j] = fminf(mn[j], v);
        sm[j] += v;
        sq[j] = fmaf(v, v, sq[j]);
      }
  }
  #pragma unroll
  for (int j = 0; j < 8; ++j)
    for (int off = 8; off; off >>= 1) {
      mx[j] = fmaxf(mx[j], __shfl_down(mx[j], off, 16));
      mn[j] = fminf(mn[j], __shfl_down(mn[j], off, 16));
      sm[j] += __shfl_down(sm[j], off, 16);
      sq[j] += __shfl_down(sq[j], off, 16);
    }
  if (tn == 0) {
    #pragma unroll
    for (int j = 0; j < 8; ++j) {
      int o = o0 + to * 8 + j;
      mxb[b * 1024 + o] = mx[j];
      mnb[b * 1024 + o] = mn[j];
      atomicAdd(&sum3[o], sm[j]);
      atomicAdd(&sq3[o], sq[j]);
    }
  }
}

// pooled[b,c] = a3*(a3>=0 ? max : min) + s3  (maxpool commuted through BN affine)
__global__ __launch_bounds__(256) void k_pooled(const float* __restrict__ a3,
    const float* __restrict__ s3, const float* __restrict__ mxb,
    const float* __restrict__ mnb, float* __restrict__ pool)
{
  int idx4 = blockIdx.x * 256 + threadIdx.x;   // 8192 f4, grid 32
  int c4 = idx4 & 255;
  float4 a = ((const float4*)a3)[c4];
  float4 s = ((const float4*)s3)[c4];
  float4 mx = ((const float4*)mxb)[idx4];
  float4 mn = ((const float4*)mnb)[idx4];
  float4 r;
  r.x = fmaf(a.x, (a.x >= 0.f ? mx.x : mn.x), s.x);
  r.y = fmaf(a.y, (a.y >= 0.f ? mx.y : mn.y), s.y);
  r.z = fmaf(a.z, (a.z >= 0.f ? mx.z : mn.z), s.z);
  r.w = fmaf(a.w, (a.w >= 0.f ? mx.w : mn.w), s.w);
  ((float4*)pool)[idx4] = r;
}

// FC layer: outRaw[b, f] = bias[f] + sum_k W[f,k]*T(in[b,k]), T = relu(aIn*x+sIn) or id.
// Block = (64-f tile, 8-b group); per-f batch partial sums atomically accumulated.
__global__ __launch_bounds__(256) void k_fc(const float* __restrict__ in,
    const float* __restrict__ W, const float* __restrict__ bias,
    const float* __restrict__ aIn, const float* __restrict__ sIn,
    float* __restrict__ outRaw, float* __restrict__ sumF, float* __restrict__ sqF,
    int K, int Fout, int k4shift)
{
  __shared__ float ins[8 * 1024];
  __shared__ float red[2][4][64];
  int t = threadIdx.x;
  int f0 = blockIdx.x * 64;
  int b0 = blockIdx.y * 8;
  int K4 = K >> 2;
  for (int idx = t; idx < 8 * K4; idx += 256) {
    int bl = idx >> k4shift;
    int k4 = idx & (K4 - 1);
    float4 v = *(const float4*)(in + (size_t)(b0 + bl) * K + k4 * 4);
    if (aIn) {
      float4 a = ((const float4*)aIn)[k4];
      float4 s = ((const float4*)sIn)[k4];
      v.x = fmaxf(fmaf(a.x, v.x, s.x), 0.f);
      v.y = fmaxf(fmaf(a.y, v.y, s.y), 0.f);
      v.z = fmaxf(fmaf(a.z, v.z, s.z), 0.f);
      v.w = fmaxf(fmaf(a.w, v.w, s.w), 0.f);
    }
    *(float4*)&ins[bl * K + k4 * 4] = v;
  }
  __syncthreads();
  int f = t & 63, bg = t >> 6;
  const float* wr = W + (size_t)(f0 + f) * K;
  const float* iA = &ins[(bg * 2) * K];
  const float* iB = &ins[(bg * 2 + 1) * K];
  float acc0 = bias[f0 + f], acc1 = acc0;
  for (int k4 = 0; k4 < K4; ++k4) {
    float4 w = *(const float4*)&wr[k4 * 4];
    float4 a = *(const float4*)&iA[k4 * 4];
    float4 c = *(const float4*)&iB[k4 * 4];
    acc0 = fmaf(w.x, a.x, acc0); acc0 = fmaf(w.y, a.y, acc0);
    acc0 = fmaf(w.z, a.z, acc0); acc0 = fmaf(w.w, a.w, acc0);
    acc1 = fmaf(w.x, c.x, acc1); acc1 = fmaf(w.y, c.y, acc1);
    acc1 = fmaf(w.z, c.z, acc1); acc1 = fmaf(w.w, c.w, acc1);
  }
  outRaw[(size_t)(b0 + bg * 2) * Fout + f0 + f] = acc0;
  outRaw[(size_t)(b0 + bg * 2 + 1) * Fout + f0 + f] = acc1;
  red[0][bg][f] = acc0 + acc1;
  red[1][bg][f] = fmaf(acc0, acc0, acc1 * acc1);
  __syncthreads();
  if (t < 64) {
    float s = red[0][0][t] + red[0][1][t] + red[0][2][t] + red[0][3][t];
    float q = red[1][0][t] + red[1][1][t] + red[1][2][t] + red[1][3][t];
    atomicAdd(&sumF[f0 + t], s);
    atomicAdd(&sqF[f0 + t], q);
  }
}

// Head: p = relu(BN(f2)) @ wp.T + bp; then SO(3) projection per batch via Horn's
// quaternion (dominant eigvec of 4x4 N by 16 shifted matrix squarings); emit [B,4,4].
__global__ __launch_bounds__(384) void k_head(const float* __restrict__ f2r,
    const float* __restrict__ aF2, const float* __restrict__ sF2,
    const float* __restrict__ wp, const float* __restrict__ bp,
    float* __restrict__ out)
{
  __shared__ float pS[32 * 12];
  int t = threadIdx.x;
  {
    int b = t / 12, j = t % 12;
    const float* w = wp + j * 256;
    const float* fr = f2r + b * 256;
    float acc = bp[j];
    for (int c = 0; c < 256; ++c) {
      float h = fmaxf(fmaf(aF2[c], fr[c], sF2[c]), 0.f);
      acc = fmaf(w[c], h, acc);
    }
    pS[t] = acc;
  }
  __syncthreads();
  if (t < 32) {
    const float* p = &pS[t * 12];
    float m00=p[0],m01=p[1],m02=p[2],m10=p[3],m11=p[4],m12=p[5],m20=p[6],m21=p[7],m22=p[8];
    float P[4][4];
    P[0][0]=m00+m11+m22; P[0][1]=m21-m12;     P[0][2]=m02-m20;     P[0][3]=m10-m01;
    P[1][1]=m00-m11-m22; P[1][2]=m01+m10;     P[1][3]=m02+m20;
    P[2][2]=m11-m00-m22; P[2][3]=m12+m21;
    P[3][3]=m22-m00-m11;
    P[1][0]=P[0][1]; P[2][0]=P[0][2]; P[3][0]=P[0][3];
    P[2][1]=P[1][2]; P[3][1]=P[1][3]; P[3][2]=P[2][3];
    float fn = sqrtf(m00*m00+m01*m01+m02*m02+m10*m10+m11*m11+m12*m12+m20*m20+m21*m21+m22*m22);
    float inv = 1.f / (2.f * fn + 1e-30f);
    #pragma unroll
    for (int i = 0; i < 4; ++i)
      #pragma unroll
      for (int j = 0; j < 4; ++j) P[i][j] *= inv;
    P[0][0] += 1.f; P[1][1] += 1.f; P[2][2] += 1.f; P[3][3] += 1.f;
    for (int it = 0; it < 16; ++it) {
      float Q[4][4];
      #pragma unroll
      for (int i = 0; i < 4; ++i)
        #pragma unroll
        for (int j = 0; j < 4; ++j)
          Q[i][j] = P[i][0]*P[0][j] + P[i][1]*P[1][j] + P[i][2]*P[2][j] + P[i][3]*P[3][j];
      float mxa = 0.f;
      #pragma unroll
      for (int i = 0; i < 4; ++i)
        #pragma unroll
        for (int j = 0; j < 4; ++j) mxa = fmaxf(mxa, fabsf(Q[i][j]));
      float r = 1.f / mxa;
      #pragma unroll
      for (int i = 0; i < 4; ++i)
        #pragma unroll
        for (int j = 0; j < 4; ++j) P[i][j] = Q[i][j] * r;
    }
    float bestn = -1.f; int bj = 0;
    #pragma unroll
    for (int j = 0; j < 4; ++j) {
      float nn = P[0][j]*P[0][j] + P[1][j]*P[1][j] + P[2][j]*P[2][j] + P[3][j]*P[3][j];
      if (nn > bestn) { bestn = nn; bj = j; }
    }
    float qw = P[0][bj], qx = P[1][bj], qy = P[2][bj], qz = P[3][bj];
    float qn = rsqrtf(qw*qw + qx*qx + qy*qy + qz*qz);
    qw *= qn; qx *= qn; qy *= qn; qz *= qn;
    float* ob = out + t * 16;
    ob[0]  = 1.f - 2.f*(qy*qy + qz*qz);
    ob[1]  = 2.f*(qx*qy - qw*qz);
    ob[2]  = 2.f*(qx*qz + qw*qy);
    ob[3]  = p[9];
    ob[4]  = 2.f*(qx*qy + qw*qz);
    ob[5]  = 1.f - 2.f*(qx*qx + qz*qz);
    ob[6]  = 2.f*(qy*qz - qw*qx);
    ob[7]  = p[10];
    ob[8]  = 2.f*(qx*qz - qw*qy);
    ob[9]  = 2.f*(qy*qz + qw*qx);
    ob[10] = 1.f - 2.f*(qx*qx + qy*qy);
    ob[11] = p[11];
    ob[12] = 0.f; ob[13] = 0.f; ob[14] = 0.f; ob[15] = 1.f;
  }
}

extern "C" void kernel_launch(void* const* d_in, const int* in_sizes, int n_in,
                              void* d_out, int out_size, void* d_ws, size_t ws_size,
                              hipStream_t stream)
{
  (void)in_sizes; (void)n_in; (void)out_size;
  if (ws_size < (size_t)WS_FLOATS * sizeof(float)) return;  // needs ~51.4 MB scratch
  const float* x   = (const float*)d_in[0];
  const float* w1  = (const float*)d_in[1];
  const float* b1  = (const float*)d_in[2];
  const float* g1  = (const float*)d_in[3];
  const float* be1 = (const float*)d_in[4];
  const float* w2  = (const float*)d_in[5];
  const float* b2  = (const float*)d_in[6];
  const float* g2  = (const float*)d_in[7];
  const float* be2 = (const float*)d_in[8];
  const float* w3  = (const float*)d_in[9];
  const float* b3  = (const float*)d_in[10];
  const float* g3  = (const float*)d_in[11];
  const float* be3 = (const float*)d_in[12];
  const float* wf1 = (const float*)d_in[13];
  const float* bf1 = (const float*)d_in[14];
  const float* gf1 = (const float*)d_in[15];
  const float* bef1= (const float*)d_in[16];
  const float* wf2 = (const float*)d_in[17];
  const float* bf2 = (const float*)d_in[18];
  const float* gf2 = (const float*)d_in[19];
  const float* bef2= (const float*)d_in[20];
  const float* wp  = (const float*)d_in[21];
  const float* bp  = (const float*)d_in[22];
  float* ws  = (float*)d_ws;
  float* out = (float*)d_out;

  hipMemsetAsync((void*)(ws + OFF_Z), 0, ZN * sizeof(float), stream);
  k_conv1<<<4096, 256, 0, stream>>>(x, w1, b1, ws + OFF_Y1, ws + OFF_SUM1, ws + OFF_SQ1);
  k_finalize<<<1, 64, 0, stream>>>(ws + OFF_SUM1, ws + OFF_SQ1, g1, be1,
                                   ws + OFF_A1, ws + OFF_S1, 64, 1.f / 65536.f);
  k_conv2<<<2048, 256, 0, stream>>>(ws + OFF_Y1, w2, b2, ws + OFF_A1, ws + OFF_S1,
                                    ws + OFF_Y2, ws + OFF_SUM2, ws + OFF_SQ2);
  k_finalize<<<1, 128, 0, stream>>>(ws + OFF_SUM2, ws + OFF_SQ2, g2, be2,
                                    ws + OFF_A2, ws + OFF_S2, 128, 1.f / 65536.f);
  k_tw3<<<512, 256, 0, stream>>>(w3, ws + OFF_W3T);
  k_conv3<<<256, 256, 0, stream>>>(ws + OFF_Y2, ws + OFF_W3T, b3, ws + OFF_A2, ws + OFF_S2,
                                   ws + OFF_MX, ws + OFF_MN, ws + OFF_SUM3, ws + OFF_SQ3);
  k_finalize<<<4, 256, 0, stream>>>(ws + OFF_SUM3, ws + OFF_SQ3, g3, be3,
                                    ws + OFF_A3, ws + OFF_S3, 1024, 1.f / 65536.f);
  k_pooled<<<32, 256, 0, stream>>>(ws + OFF_A3, ws + OFF_S3, ws + OFF_MX, ws + OFF_MN,
                                   ws + OFF_POOL);
  k_fc<<<dim3(8, 4), 256, 0, stream>>>(ws + OFF_POOL, wf1, bf1, nullptr, nullptr,
                                       ws + OFF_F1R, ws + OFF_SUMF1, ws + OFF_SQF1,
                                       1024, 512, 8);
  k_finalize<<<2, 256, 0, stream>>>(ws + OFF_SUMF1, ws + OFF_SQF1, gf1, bef1,
                                    ws + OFF_AF1, ws + OFF_SF1, 512, 1.f / 32.f);
  k_fc<<<dim3(4, 4), 256, 0, stream>>>(ws + OFF_F1R, wf2, bf2, ws + OFF_AF1, ws + OFF_SF1,
                                       ws + OFF_F2R, ws + OFF_SUMF2, ws + OFF_SQF2,
                                       512, 256, 7);
  k_finalize<<<1, 256, 0, stream>>>(ws + OFF_SUMF2, ws + OFF_SQF2, gf2, bef2,
                                    ws + OFF_AF2, ws + OFF_SF2, 256, 1.f / 32.f);
  k_head<<<1, 384, 0, stream>>>(ws + OFF_F2R, ws + OFF_AF2, ws + OFF_SF2, wp, bp, out);
}

// Round 3
// 361.272 us; speedup vs baseline: 1.9303x; 1.9303x over previous
//
#include <hip/hip_runtime.h>

// PointNetRot9d. Round 3: conv3 MFMA fragments switched bf16 -> fp16.
//  - r2's bf16 version was computationally correct but absmax 8.9e-2 > 4.25e-2:
//    operand quantization (2^-9 rel) through BN3->FC->Horn projection.
//  - fp16 = 11 mantissa bits (2^-12 rel), 8x better; same MFMA shape/rate/layout
//    (v_mfma_f32_16x16x32_f16), fp32 accumulation. Range safe: h2 in [0,~6],
//    |w3| <= ~0.5.
//  - Structure identical to r2: MFMA-native swizzled LDS ([cb][row'][8],
//    row'=(row+cb)&mask), A-frags cached in regs, grid 512, 2 blocks/CU,
//    XCD-swizzled blockIdx, exact fp32 BN3 stats from accumulators.

#define NPT 2048
#define C1 64
#define C2 128
#define EPSV 1e-5f

typedef __attribute__((ext_vector_type(8))) _Float16 half8;
typedef __attribute__((ext_vector_type(4))) float floatx4;

// ---- workspace layout (float offsets) ----
#define OFF_Y1    0               // 32*64*2048   = 4194304
#define OFF_Y2    4194304         // 32*128*2048  = 8388608
#define OFF_Z     12582912        // zeroed stats region start
#define ZN        3968
#define OFF_SUM1  (OFF_Z)
#define OFF_SQ1   (OFF_Z+64)
#define OFF_SUM2  (OFF_Z+128)
#define OFF_SQ2   (OFF_Z+256)
#define OFF_SUM3  (OFF_Z+384)
#define OFF_SQ3   (OFF_Z+1408)
#define OFF_SUMF1 (OFF_Z+2432)
#define OFF_SQF1  (OFF_Z+2944)
#define OFF_SUMF2 (OFF_Z+3456)
#define OFF_SQF2  (OFF_Z+3712)
#define OFF_A1    (OFF_Z+3968)
#define OFF_S1    (OFF_A1+64)
#define OFF_A2    (OFF_A1+128)
#define OFF_S2    (OFF_A1+256)
#define OFF_A3    (OFF_A1+384)
#define OFF_S3    (OFF_A1+1408)
#define OFF_AF1   (OFF_A1+2432)
#define OFF_SF1   (OFF_AF1+512)
#define OFF_AF2   (OFF_AF1+1024)
#define OFF_SF2   (OFF_AF1+1280)
#define OFF_MX    (OFF_AF1+1536)      // 2 ns-slots * 32*1024 = 65536
#define OFF_MN    (OFF_MX+65536)      // 65536
#define OFF_POOL  (OFF_MX+131072)     // 32768
#define OFF_F1R   (OFF_POOL+32768)    // 16384
#define OFF_F2R   (OFF_F1R+16384)     // 8192
#define OFF_W3H   (OFF_F2R+8192)      // 131072 ushort = 65536 float slots
#define WS_FLOATS (OFF_W3H+65536)     // 12,844,800 floats = 51.4 MB

static __device__ inline unsigned short f16r(float f) {
  _Float16 h = (_Float16)f;            // v_cvt_f16_f32, RNE
  return __builtin_bit_cast(unsigned short, h);
}

// conv1: y1[b,o,n] = sum_d w1[o,d]*x[b,d,n] + b1[o]; per-channel sum/sumsq.
__global__ __launch_bounds__(256) void k_conv1(const float* __restrict__ x,
    const float* __restrict__ w1, const float* __restrict__ b1,
    float* __restrict__ y1, float* __restrict__ sum1, float* __restrict__ sq1)
{
  int idx4 = blockIdx.x * 256 + threadIdx.x;     // f4 index into [32][64][2048]
  int n4 = idx4 & 511;
  int o  = (idx4 >> 9) & 63;
  int b  = idx4 >> 15;
  const float4* xr = (const float4*)(x + (size_t)b * 3 * NPT);
  float4 x0 = xr[n4], x1 = xr[512 + n4], x2 = xr[1024 + n4];
  float wa = w1[o*3], wb = w1[o*3+1], wc = w1[o*3+2], bb = b1[o];
  float4 v;
  v.x = fmaf(wa, x0.x, fmaf(wb, x1.x, fmaf(wc, x2.x, bb)));
  v.y = fmaf(wa, x0.y, fmaf(wb, x1.y, fmaf(wc, x2.y, bb)));
  v.z = fmaf(wa, x0.z, fmaf(wb, x1.z, fmaf(wc, x2.z, bb)));
  v.w = fmaf(wa, x0.w, fmaf(wb, x1.w, fmaf(wc, x2.w, bb)));
  ((float4*)y1)[idx4] = v;
  float s = v.x + v.y + v.z + v.w;
  float q = v.x*v.x + v.y*v.y + v.z*v.z + v.w*v.w;
  for (int off = 32; off; off >>= 1) { s += __shfl_down(s, off); q += __shfl_down(q, off); }
  __shared__ float red[8];
  int lane = threadIdx.x & 63, wv = threadIdx.x >> 6;
  if (!lane) { red[wv] = s; red[4 + wv] = q; }
  __syncthreads();
  if (!threadIdx.x) {
    atomicAdd(&sum1[o], red[0] + red[1] + red[2] + red[3]);
    atomicAdd(&sq1[o],  red[4] + red[5] + red[6] + red[7]);
  }
}

// Fold BN into per-channel affine: a = g*rsqrt(var+eps), s = be - a*mean.
__global__ void k_finalize(const float* __restrict__ sum, const float* __restrict__ sq,
    const float* __restrict__ g, const float* __restrict__ be,
    float* __restrict__ a, float* __restrict__ s, int C, float invc)
{
  int c = blockIdx.x * blockDim.x + threadIdx.x;
  if (c >= C) return;
  float m = sum[c] * invc;
  float v = fmaf(-m, m, sq[c] * invc);
  float ia = g[c] * rsqrtf(v + EPSV);
  a[c] = ia;
  s[c] = fmaf(-ia, m, be[c]);
}

// conv2: y2[b,o,n] = sum_c w2[o,c]*relu(a1[c]*y1[b,c,n]+s1[c]) + b2[o]; stats2.
__global__ __launch_bounds__(256) void k_conv2(const float* __restrict__ y1,
    const float* __restrict__ w2, const float* __restrict__ b2,
    const float* __restrict__ a1, const float* __restrict__ s1,
    float* __restrict__ y2, float* __restrict__ sum2, float* __restrict__ sq2)
{
  __shared__ float h1s[32 * 256];
  __shared__ float w2s[64 * 20];
  int t = threadIdx.x;
  int bi = blockIdx.x;
  int nt = bi & 7, ot = (bi >> 3) & 7, b = bi >> 6;
  int n0 = nt * 256, o0 = ot * 16;
  for (int i = 0; i < 4; ++i) {
    int idx = t + i * 256;
    int oj = idx >> 6, c = idx & 63;
    w2s[c * 20 + oj] = w2[(o0 + oj) * 64 + c];
  }
  int to = t >> 6, tn = t & 63;
  float acc[4][4];
  #pragma unroll
  for (int j = 0; j < 4; ++j)
    #pragma unroll
    for (int k = 0; k < 4; ++k) acc[j][k] = 0.f;
  for (int kc = 0; kc < 2; ++kc) {
    __syncthreads();
    for (int i = 0; i < 8; ++i) {
      int idx = t + i * 256;
      int cl = idx >> 6, n4 = idx & 63;
      int c = kc * 32 + cl;
      float4 v = *(const float4*)(y1 + (size_t)b * C1 * NPT + (size_t)c * NPT + n0 + n4 * 4);
      float a = a1[c], sf = s1[c];
      v.x = fmaxf(fmaf(a, v.x, sf), 0.f);
      v.y = fmaxf(fmaf(a, v.y, sf), 0.f);
      v.z = fmaxf(fmaf(a, v.z, sf), 0.f);
      v.w = fmaxf(fmaf(a, v.w, sf), 0.f);
      *(float4*)&h1s[cl * 256 + n4 * 4] = v;
    }
    __syncthreads();
    #pragma unroll 8
    for (int cl = 0; cl < 32; ++cl) {
      float4 hv = *(const float4*)&h1s[cl * 256 + tn * 4];
      float4 wv = *(const float4*)&w2s[(kc * 32 + cl) * 20 + to * 4];
      float hr[4] = {hv.x, hv.y, hv.z, hv.w};
      float wr[4] = {wv.x, wv.y, wv.z, wv.w};
      #pragma unroll
      for (int j = 0; j < 4; ++j)
        #pragma unroll
        for (int k = 0; k < 4; ++k) acc[j][k] = fmaf(wr[j], hr[k], acc[j][k]);
    }
  }
  #pragma unroll
  for (int j = 0; j < 4; ++j) {
    int o = o0 + to * 4 + j;
    float bb = b2[o];
    float4 v;
    v.x = acc[j][0] + bb; v.y = acc[j][1] + bb; v.z = acc[j][2] + bb; v.w = acc[j][3] + bb;
    *(float4*)(y2 + (size_t)b * C2 * NPT + (size_t)o * NPT + n0 + tn * 4) = v;
    float s = v.x + v.y + v.z + v.w;
    float q = v.x*v.x + v.y*v.y + v.z*v.z + v.w*v.w;
    for (int off = 32; off; off >>= 1) { s += __shfl_down(s, off); q += __shfl_down(q, off); }
    if (tn == 0) { atomicAdd(&sum2[o], s); atomicAdd(&sq2[o], q); }
  }
}

// One-time cvt w3 [1024][128] f32 -> fp16 (same layout; rows are MFMA A-rows).
__global__ __launch_bounds__(256) void k_w3h(const float* __restrict__ w3,
                                             unsigned short* __restrict__ w3h)
{
  int idx4 = blockIdx.x * 256 + threadIdx.x;   // 32768 f4, grid 128
  float4 v = ((const float4*)w3)[idx4];
  ushort4 o;
  o.x = f16r(v.x); o.y = f16r(v.y); o.z = f16r(v.z); o.w = f16r(v.w);
  ((ushort4*)w3h)[idx4] = o;
}

// conv3 via fp16 MFMA: block = (b, 128-o tile, n-half); 16 chunks of 64 n.
// LDS: w3s[cb][o'][8], h2s[cb][n'][8], row'=(row+cb)&mask swizzle (conflict-free).
// A-frags cached in regs; per-(b,o) max/min + per-o sum/sq exact in fp32.
__global__ __launch_bounds__(256, 2) void k_conv3(const float* __restrict__ y2,
    const unsigned short* __restrict__ w3h, const float* __restrict__ b3,
    const float* __restrict__ a2, const float* __restrict__ s2,
    float* __restrict__ mxb, float* __restrict__ mnb,
    float* __restrict__ sum3, float* __restrict__ sq3)
{
  __shared__ unsigned short w3s[16 * 128 * 8];  // 32 KB
  __shared__ unsigned short h2s[16 * 64 * 8];   // 16 KB
  __shared__ float sred[2][128][4];             // 4 KB
  int t = threadIdx.x;
  int bi = blockIdx.x;                 // bi = ot*64 + b*2 + ns (XCD-local b,ns)
  int ot_blk = bi >> 6;
  int b  = (bi >> 1) & 31;
  int ns = bi & 1;
  int o0 = ot_blk * 128;
  int n_base = ns * 1024;
  int w = t >> 6, lane = t & 63;
  int ow = w & 1, nw = w >> 1;
  int quad = lane >> 4, l15 = lane & 15;

  // ---- stage w3 o-tile: [cb][o'][8] with o' = (o+cb)&127 ----
  for (int i = 0; i < 8; ++i) {
    int idx = i * 256 + t;             // 2048 = 128 o x 16 cb
    int o = idx >> 4, cb = idx & 15;
    uint4 v = *(const uint4*)(w3h + (size_t)(o0 + o) * 128 + cb * 8);
    int op = (o + cb) & 127;
    *(uint4*)&w3s[(cb * 128 + op) * 8] = v;
  }
  __syncthreads();

  // ---- cache A-frags: af[ot][s], o = ow*64 + ot*16 + l15, k-block = s*4+quad ----
  half8 af[4][4];
  #pragma unroll
  for (int ti = 0; ti < 4; ++ti)
    #pragma unroll
    for (int s = 0; s < 4; ++s) {
      int cb = s * 4 + quad;
      int o = ow * 64 + ti * 16 + l15;
      int op = (o + cb) & 127;
      af[ti][s] = *(const half8*)&w3s[(cb * 128 + op) * 8];
    }

  // ---- bias + running stats regs ----
  float breg[4][4], mx[4][4], mn[4][4], sm[4][4], sq[4][4];
  #pragma unroll
  for (int ti = 0; ti < 4; ++ti)
    #pragma unroll
    for (int r = 0; r < 4; ++r) {
      breg[ti][r] = b3[o0 + ow * 64 + ti * 16 + quad * 4 + r];
      mx[ti][r] = -3.4e38f; mn[ti][r] = 3.4e38f; sm[ti][r] = 0.f; sq[ti][r] = 0.f;
    }

  // staging thread mapping: cg = t>>4 (8 c), ng = t&15 (4 n); BN2 coeffs fixed per thread
  int cg = t >> 4, ng = t & 15;
  int c0 = cg * 8, nn = ng * 4;
  float av[8], sv[8];
  #pragma unroll
  for (int i = 0; i < 8; ++i) { av[i] = a2[c0 + i]; sv[i] = s2[c0 + i]; }

  for (int nc = 0; nc < 16; ++nc) {
    int n0 = n_base + nc * 64;
    __syncthreads();
    // ---- stage h2 chunk: relu(a2*y2+s2) -> fp16, [cb][n'][8], n'=(n+cb)&63 ----
    {
      float4 m0, m1, m2, m3, m4, m5, m6, m7;
      const float* yb = y2 + (size_t)b * C2 * NPT + n0 + nn;
      m0 = *(const float4*)(yb + (size_t)(c0 + 0) * NPT);
      m1 = *(const float4*)(yb + (size_t)(c0 + 1) * NPT);
      m2 = *(const float4*)(yb + (size_t)(c0 + 2) * NPT);
      m3 = *(const float4*)(yb + (size_t)(c0 + 3) * NPT);
      m4 = *(const float4*)(yb + (size_t)(c0 + 4) * NPT);
      m5 = *(const float4*)(yb + (size_t)(c0 + 5) * NPT);
      m6 = *(const float4*)(yb + (size_t)(c0 + 6) * NPT);
      m7 = *(const float4*)(yb + (size_t)(c0 + 7) * NPT);
      #define BN4(mm, i) \
        mm.x = fmaxf(fmaf(av[i], mm.x, sv[i]), 0.f); \
        mm.y = fmaxf(fmaf(av[i], mm.y, sv[i]), 0.f); \
        mm.z = fmaxf(fmaf(av[i], mm.z, sv[i]), 0.f); \
        mm.w = fmaxf(fmaf(av[i], mm.w, sv[i]), 0.f);
      BN4(m0,0) BN4(m1,1) BN4(m2,2) BN4(m3,3) BN4(m4,4) BN4(m5,5) BN4(m6,6) BN4(m7,7)
      #undef BN4
      #define ST_J(j, comp) { \
        uint4 pk; \
        pk.x = (unsigned)f16r(m0.comp) | ((unsigned)f16r(m1.comp) << 16); \
        pk.y = (unsigned)f16r(m2.comp) | ((unsigned)f16r(m3.comp) << 16); \
        pk.z = (unsigned)f16r(m4.comp) | ((unsigned)f16r(m5.comp) << 16); \
        pk.w = (unsigned)f16r(m6.comp) | ((unsigned)f16r(m7.comp) << 16); \
        int np = ((nn + j) + cg) & 63; \
        *(uint4*)&h2s[(cg * 64 + np) * 8] = pk; }
      ST_J(0, x) ST_J(1, y) ST_J(2, z) ST_J(3, w)
      #undef ST_J
    }
    __syncthreads();

    // ---- MFMA: acc[ot][nt] over 4 k-steps ----
    floatx4 acc[4][2];
    #pragma unroll
    for (int ti = 0; ti < 4; ++ti)
      #pragma unroll
      for (int ntile = 0; ntile < 2; ++ntile)
        acc[ti][ntile] = (floatx4){0.f, 0.f, 0.f, 0.f};
    #pragma unroll
    for (int s = 0; s < 4; ++s) {
      int cb = s * 4 + quad;
      half8 bf[2];
      #pragma unroll
      for (int ntile = 0; ntile < 2; ++ntile) {
        int n = nw * 32 + ntile * 16 + l15;
        int np = (n + cb) & 63;
        bf[ntile] = *(const half8*)&h2s[(cb * 64 + np) * 8];
      }
      #pragma unroll
      for (int ti = 0; ti < 4; ++ti) {
        acc[ti][0] = __builtin_amdgcn_mfma_f32_16x16x32_f16(af[ti][s], bf[0], acc[ti][0], 0, 0, 0);
        acc[ti][1] = __builtin_amdgcn_mfma_f32_16x16x32_f16(af[ti][s], bf[1], acc[ti][1], 0, 0, 0);
      }
    }
    // ---- stats: val = acc + b3; max/min/sum/sq per o ----
    #pragma unroll
    for (int ti = 0; ti < 4; ++ti)
      #pragma unroll
      for (int ntile = 0; ntile < 2; ++ntile)
        #pragma unroll
        for (int r = 0; r < 4; ++r) {
          float v = acc[ti][ntile][r] + breg[ti][r];
          mx[ti][r] = fmaxf(mx[ti][r], v);
          mn[ti][r] = fminf(mn[ti][r], v);
          sm[ti][r] += v;
          sq[ti][r] = fmaf(v, v, sq[ti][r]);
        }
  }

  // ---- reduce stats over the 16 n-lanes, then across nw via LDS ----
  #pragma unroll
  for (int ti = 0; ti < 4; ++ti)
    #pragma unroll
    for (int r = 0; r < 4; ++r) {
      #pragma unroll
      for (int m = 1; m < 16; m <<= 1) {
        mx[ti][r] = fmaxf(mx[ti][r], __shfl_xor(mx[ti][r], m, 16));
        mn[ti][r] = fminf(mn[ti][r], __shfl_xor(mn[ti][r], m, 16));
        sm[ti][r] += __shfl_xor(sm[ti][r], m, 16);
        sq[ti][r] += __shfl_xor(sq[ti][r], m, 16);
      }
    }
  if (l15 == 0) {
    #pragma unroll
    for (int ti = 0; ti < 4; ++ti)
      #pragma unroll
      for (int r = 0; r < 4; ++r) {
        int oloc = ow * 64 + ti * 16 + quad * 4 + r;
        sred[nw][oloc][0] = mx[ti][r];
        sred[nw][oloc][1] = mn[ti][r];
        sred[nw][oloc][2] = sm[ti][r];
        sred[nw][oloc][3] = sq[ti][r];
      }
  }
  __syncthreads();
  if (t < 128) {
    int o = o0 + t;
    float fmx = fmaxf(sred[0][t][0], sred[1][t][0]);
    float fmn = fminf(sred[0][t][1], sred[1][t][1]);
    float fsm = sred[0][t][2] + sred[1][t][2];
    float fsq = sred[0][t][3] + sred[1][t][3];
    mxb[ns * 32768 + b * 1024 + o] = fmx;
    mnb[ns * 32768 + b * 1024 + o] = fmn;
    atomicAdd(&sum3[o], fsm);
    atomicAdd(&sq3[o], fsq);
  }
}

// pooled[b,c] = a3*(a3>=0 ? max : min) + s3, combining the 2 n-half slots.
__global__ __launch_bounds__(256) void k_pooled(const float* __restrict__ a3,
    const float* __restrict__ s3, const float* __restrict__ mxb,
    const float* __restrict__ mnb, float* __restrict__ pool)
{
  int idx4 = blockIdx.x * 256 + threadIdx.x;   // 8192 f4, grid 32
  int c4 = idx4 & 255;
  float4 a = ((const float4*)a3)[c4];
  float4 s = ((const float4*)s3)[c4];
  float4 mx0 = ((const float4*)mxb)[idx4];
  float4 mx1 = ((const float4*)mxb)[idx4 + 8192];
  float4 mn0 = ((const float4*)mnb)[idx4];
  float4 mn1 = ((const float4*)mnb)[idx4 + 8192];
  float4 mx, mn;
  mx.x = fmaxf(mx0.x, mx1.x); mx.y = fmaxf(mx0.y, mx1.y);
  mx.z = fmaxf(mx0.z, mx1.z); mx.w = fmaxf(mx0.w, mx1.w);
  mn.x = fminf(mn0.x, mn1.x); mn.y = fminf(mn0.y, mn1.y);
  mn.z = fminf(mn0.z, mn1.z); mn.w = fminf(mn0.w, mn1.w);
  float4 r;
  r.x = fmaf(a.x, (a.x >= 0.f ? mx.x : mn.x), s.x);
  r.y = fmaf(a.y, (a.y >= 0.f ? mx.y : mn.y), s.y);
  r.z = fmaf(a.z, (a.z >= 0.f ? mx.z : mn.z), s.z);
  r.w = fmaf(a.w, (a.w >= 0.f ? mx.w : mn.w), s.w);
  ((float4*)pool)[idx4] = r;
}

// FC layer: outRaw[b,f] = bias[f] + sum_k W[f,k]*T(in[b,k]); batch stats.
__global__ __launch_bounds__(256) void k_fc(const float* __restrict__ in,
    const float* __restrict__ W, const float* __restrict__ bias,
    const float* __restrict__ aIn, const float* __restrict__ sIn,
    float* __restrict__ outRaw, float* __restrict__ sumF, float* __restrict__ sqF,
    int K, int Fout, int k4shift)
{
  __shared__ float ins[8 * 1024];
  __shared__ float red[2][4][64];
  int t = threadIdx.x;
  int f0 = blockIdx.x * 64;
  int b0 = blockIdx.y * 8;
  int K4 = K >> 2;
  for (int idx = t; idx < 8 * K4; idx += 256) {
    int bl = idx >> k4shift;
    int k4 = idx & (K4 - 1);
    float4 v = *(const float4*)(in + (size_t)(b0 + bl) * K + k4 * 4);
    if (aIn) {
      float4 a = ((const float4*)aIn)[k4];
      float4 s = ((const float4*)sIn)[k4];
      v.x = fmaxf(fmaf(a.x, v.x, s.x), 0.f);
      v.y = fmaxf(fmaf(a.y, v.y, s.y), 0.f);
      v.z = fmaxf(fmaf(a.z, v.z, s.z), 0.f);
      v.w = fmaxf(fmaf(a.w, v.w, s.w), 0.f);
    }
    *(float4*)&ins[bl * K + k4 * 4] = v;
  }
  __syncthreads();
  int f = t & 63, bg = t >> 6;
  const float* wr = W + (size_t)(f0 + f) * K;
  const float* iA = &ins[(bg * 2) * K];
  const float* iB = &ins[(bg * 2 + 1) * K];
  float acc0 = bias[f0 + f], acc1 = acc0;
  for (int k4 = 0; k4 < K4; ++k4) {
    float4 w = *(const float4*)&wr[k4 * 4];
    float4 a = *(const float4*)&iA[k4 * 4];
    float4 c = *(const float4*)&iB[k4 * 4];
    acc0 = fmaf(w.x, a.x, acc0); acc0 = fmaf(w.y, a.y, acc0);
    acc0 = fmaf(w.z, a.z, acc0); acc0 = fmaf(w.w, a.w, acc0);
    acc1 = fmaf(w.x, c.x, acc1); acc1 = fmaf(w.y, c.y, acc1);
    acc1 = fmaf(w.z, c.z, acc1); acc1 = fmaf(w.w, c.w, acc1);
  }
  outRaw[(size_t)(b0 + bg * 2) * Fout + f0 + f] = acc0;
  outRaw[(size_t)(b0 + bg * 2 + 1) * Fout + f0 + f] = acc1;
  red[0][bg][f] = acc0 + acc1;
  red[1][bg][f] = fmaf(acc0, acc0, acc1 * acc1);
  __syncthreads();
  if (t < 64) {
    float s = red[0][0][t] + red[0][1][t] + red[0][2][t] + red[0][3][t];
    float q = red[1][0][t] + red[1][1][t] + red[1][2][t] + red[1][3][t];
    atomicAdd(&sumF[f0 + t], s);
    atomicAdd(&sqF[f0 + t], q);
  }
}

// Head: p = relu(BN(f2)) @ wp.T + bp; Horn-quaternion SO(3) projection -> [B,4,4].
__global__ __launch_bounds__(384) void k_head(const float* __restrict__ f2r,
    const float* __restrict__ aF2, const float* __restrict__ sF2,
    const float* __restrict__ wp, const float* __restrict__ bp,
    float* __restrict__ out)
{
  __shared__ float pS[32 * 12];
  int t = threadIdx.x;
  {
    int b = t / 12, j = t % 12;
    const float* w = wp + j * 256;
    const float* fr = f2r + b * 256;
    float acc = bp[j];
    for (int c = 0; c < 256; ++c) {
      float h = fmaxf(fmaf(aF2[c], fr[c], sF2[c]), 0.f);
      acc = fmaf(w[c], h, acc);
    }
    pS[t] = acc;
  }
  __syncthreads();
  if (t < 32) {
    const float* p = &pS[t * 12];
    float m00=p[0],m01=p[1],m02=p[2],m10=p[3],m11=p[4],m12=p[5],m20=p[6],m21=p[7],m22=p[8];
    float P[4][4];
    P[0][0]=m00+m11+m22; P[0][1]=m21-m12;     P[0][2]=m02-m20;     P[0][3]=m10-m01;
    P[1][1]=m00-m11-m22; P[1][2]=m01+m10;     P[1][3]=m02+m20;
    P[2][2]=m11-m00-m22; P[2][3]=m12+m21;
    P[3][3]=m22-m00-m11;
    P[1][0]=P[0][1]; P[2][0]=P[0][2]; P[3][0]=P[0][3];
    P[2][1]=P[1][2]; P[3][1]=P[1][3]; P[3][2]=P[2][3];
    float fn = sqrtf(m00*m00+m01*m01+m02*m02+m10*m10+m11*m11+m12*m12+m20*m20+m21*m21+m22*m22);
    float inv = 1.f / (2.f * fn + 1e-30f);
    #pragma unroll
    for (int i = 0; i < 4; ++i)
      #pragma unroll
      for (int j = 0; j < 4; ++j) P[i][j] *= inv;
    P[0][0] += 1.f; P[1][1] += 1.f; P[2][2] += 1.f; P[3][3] += 1.f;
    for (int it = 0; it < 16; ++it) {
      float Q[4][4];
      #pragma unroll
      for (int i = 0; i < 4; ++i)
        #pragma unroll
        for (int j = 0; j < 4; ++j)
          Q[i][j] = P[i][0]*P[0][j] + P[i][1]*P[1][j] + P[i][2]*P[2][j] + P[i][3]*P[3][j];
      float mxa = 0.f;
      #pragma unroll
      for (int i = 0; i < 4; ++i)
        #pragma unroll
        for (int j = 0; j < 4; ++j) mxa = fmaxf(mxa, fabsf(Q[i][j]));
      float r = 1.f / mxa;
      #pragma unroll
      for (int i = 0; i < 4; ++i)
        #pragma unroll
        for (int j = 0; j < 4; ++j) P[i][j] = Q[i][j] * r;
    }
    float bestn = -1.f; int bj = 0;
    #pragma unroll
    for (int j = 0; j < 4; ++j) {
      float nn = P[0][j]*P[0][j] + P[1][j]*P[1][j] + P[2][j]*P[2][j] + P[3][j]*P[3][j];
      if (nn > bestn) { bestn = nn; bj = j; }
    }
    float qw = P[0][bj], qx = P[1][bj], qy = P[2][bj], qz = P[3][bj];
    float qn = rsqrtf(qw*qw + qx*qx + qy*qy + qz*qz);
    qw *= qn; qx *= qn; qy *= qn; qz *= qn;
    float* ob = out + t * 16;
    ob[0]  = 1.f - 2.f*(qy*qy + qz*qz);
    ob[1]  = 2.f*(qx*qy - qw*qz);
    ob[2]  = 2.f*(qx*qz + qw*qy);
    ob[3]  = p[9];
    ob[4]  = 2.f*(qx*qy + qw*qz);
    ob[5]  = 1.f - 2.f*(qx*qx + qz*qz);
    ob[6]  = 2.f*(qy*qz - qw*qx);
    ob[7]  = p[10];
    ob[8]  = 2.f*(qx*qz - qw*qy);
    ob[9]  = 2.f*(qy*qz + qw*qx);
    ob[10] = 1.f - 2.f*(qx*qx + qy*qy);
    ob[11] = p[11];
    ob[12] = 0.f; ob[13] = 0.f; ob[14] = 0.f; ob[15] = 1.f;
  }
}

extern "C" void kernel_launch(void* const* d_in, const int* in_sizes, int n_in,
                              void* d_out, int out_size, void* d_ws, size_t ws_size,
                              hipStream_t stream)
{
  (void)in_sizes; (void)n_in; (void)out_size;
  if (ws_size < (size_t)WS_FLOATS * sizeof(float)) return;  // needs ~51.4 MB scratch
  const float* x   = (const float*)d_in[0];
  const float* w1  = (const float*)d_in[1];
  const float* b1  = (const float*)d_in[2];
  const float* g1  = (const float*)d_in[3];
  const float* be1 = (const float*)d_in[4];
  const float* w2  = (const float*)d_in[5];
  const float* b2  = (const float*)d_in[6];
  const float* g2  = (const float*)d_in[7];
  const float* be2 = (const float*)d_in[8];
  const float* w3  = (const float*)d_in[9];
  const float* b3  = (const float*)d_in[10];
  const float* g3  = (const float*)d_in[11];
  const float* be3 = (const float*)d_in[12];
  const float* wf1 = (const float*)d_in[13];
  const float* bf1 = (const float*)d_in[14];
  const float* gf1 = (const float*)d_in[15];
  const float* bef1= (const float*)d_in[16];
  const float* wf2 = (const float*)d_in[17];
  const float* bf2 = (const float*)d_in[18];
  const float* gf2 = (const float*)d_in[19];
  const float* bef2= (const float*)d_in[20];
  const float* wp  = (const float*)d_in[21];
  const float* bp  = (const float*)d_in[22];
  float* ws  = (float*)d_ws;
  float* out = (float*)d_out;

  hipMemsetAsync((void*)(ws + OFF_Z), 0, ZN * sizeof(float), stream);
  k_conv1<<<4096, 256, 0, stream>>>(x, w1, b1, ws + OFF_Y1, ws + OFF_SUM1, ws + OFF_SQ1);
  k_finalize<<<1, 64, 0, stream>>>(ws + OFF_SUM1, ws + OFF_SQ1, g1, be1,
                                   ws + OFF_A1, ws + OFF_S1, 64, 1.f / 65536.f);
  k_w3h<<<128, 256, 0, stream>>>(w3, (unsigned short*)(ws + OFF_W3H));
  k_conv2<<<2048, 256, 0, stream>>>(ws + OFF_Y1, w2, b2, ws + OFF_A1, ws + OFF_S1,
                                    ws + OFF_Y2, ws + OFF_SUM2, ws + OFF_SQ2);
  k_finalize<<<1, 128, 0, stream>>>(ws + OFF_SUM2, ws + OFF_SQ2, g2, be2,
                                    ws + OFF_A2, ws + OFF_S2, 128, 1.f / 65536.f);
  k_conv3<<<512, 256, 0, stream>>>(ws + OFF_Y2, (const unsigned short*)(ws + OFF_W3H), b3,
                                   ws + OFF_A2, ws + OFF_S2,
                                   ws + OFF_MX, ws + OFF_MN, ws + OFF_SUM3, ws + OFF_SQ3);
  k_finalize<<<4, 256, 0, stream>>>(ws + OFF_SUM3, ws + OFF_SQ3, g3, be3,
                                    ws + OFF_A3, ws + OFF_S3, 1024, 1.f / 65536.f);
  k_pooled<<<32, 256, 0, stream>>>(ws + OFF_A3, ws + OFF_S3, ws + OFF_MX, ws + OFF_MN,
                                   ws + OFF_POOL);
  k_fc<<<dim3(8, 4), 256, 0, stream>>>(ws + OFF_POOL, wf1, bf1, nullptr, nullptr,
                                       ws + OFF_F1R, ws + OFF_SUMF1, ws + OFF_SQF1,
                                       1024, 512, 8);
  k_finalize<<<2, 256, 0, stream>>>(ws + OFF_SUMF1, ws + OFF_SQF1, gf1, bef1,
                                    ws + OFF_AF1, ws + OFF_SF1, 512, 1.f / 32.f);
  k_fc<<<dim3(4, 4), 256, 0, stream>>>(ws + OFF_F1R, wf2, bf2, ws + OFF_AF1, ws + OFF_SF1,
                                       ws + OFF_F2R, ws + OFF_SUMF2, ws + OFF_SQF2,
                                       512, 256, 7);
  k_finalize<<<1, 256, 0, stream>>>(ws + OFF_SUMF2, ws + OFF_SQF2, gf2, bef2,
                                    ws + OFF_AF2, ws + OFF_SF2, 256, 1.f / 32.f);
  k_head<<<1, 384, 0, stream>>>(ws + OFF_F2R, ws + OFF_AF2, ws + OFF_SF2, wp, bp, out);
}

// Round 4
// 270.084 us; speedup vs baseline: 2.5820x; 1.3376x over previous
//
#include <hip/hip_runtime.h>

// PointNetRot9d. Round 4:
//  - conv2 rewritten as fp16 MFMA (was fp32 tile kernel: 108 us, VALUBusy 12%,
//    occupancy-capped, latency-bound). New: block = (b, 128-n slice) x all 128 o;
//    y1 read exactly once, w2 staged once; K=64 = 2 MFMA k-steps. Same
//    swizzled-LDS fragment machinery as the verified conv3.
//  - all 5 k_finalize launches removed: consumers derive BN affine (a,s) inline
//    from sum/sq/g/be (LDS precompute at block start). w3h+w2h merged into k_cvt.
//    15 -> 10 launches.
//  - conv3 unchanged except inline BN2 derivation.

#define NPT 2048
#define C1 64
#define C2 128
#define EPSV 1e-5f

typedef __attribute__((ext_vector_type(8))) _Float16 half8;
typedef __attribute__((ext_vector_type(4))) float floatx4;

// ---- workspace layout (float offsets) ----
#define OFF_Y1    0               // 32*64*2048   = 4194304
#define OFF_Y2    4194304         // 32*128*2048  = 8388608
#define OFF_Z     12582912        // zeroed stats region start
#define ZN        3968
#define OFF_SUM1  (OFF_Z)
#define OFF_SQ1   (OFF_Z+64)
#define OFF_SUM2  (OFF_Z+128)
#define OFF_SQ2   (OFF_Z+256)
#define OFF_SUM3  (OFF_Z+384)
#define OFF_SQ3   (OFF_Z+1408)
#define OFF_SUMF1 (OFF_Z+2432)
#define OFF_SQF1  (OFF_Z+2944)
#define OFF_SUMF2 (OFF_Z+3456)
#define OFF_SQF2  (OFF_Z+3712)
#define OFF_MX    (OFF_Z+3968)        // 2 ns-slots * 32*1024 = 65536
#define OFF_MN    (OFF_MX+65536)      // 65536
#define OFF_POOL  (OFF_MX+131072)     // 32768
#define OFF_F1R   (OFF_POOL+32768)    // 16384
#define OFF_F2R   (OFF_F1R+16384)     // 8192
#define OFF_W3H   (OFF_F2R+8192)      // 131072 shorts = 65536 float slots
#define OFF_W2H   (OFF_W3H+65536)     // 8192 shorts = 4096 float slots
#define WS_FLOATS (OFF_W2H+4096)      // ~51.4 MB

static __device__ inline unsigned short f16r(float f) {
  _Float16 h = (_Float16)f;            // v_cvt_f16_f32, RNE
  return __builtin_bit_cast(unsigned short, h);
}

// conv1: y1[b,o,n] = sum_d w1[o,d]*x[b,d,n] + b1[o]; per-channel sum/sumsq.
__global__ __launch_bounds__(256) void k_conv1(const float* __restrict__ x,
    const float* __restrict__ w1, const float* __restrict__ b1,
    float* __restrict__ y1, float* __restrict__ sum1, float* __restrict__ sq1)
{
  int idx4 = blockIdx.x * 256 + threadIdx.x;     // f4 index into [32][64][2048]
  int n4 = idx4 & 511;
  int o  = (idx4 >> 9) & 63;
  int b  = idx4 >> 15;
  const float4* xr = (const float4*)(x + (size_t)b * 3 * NPT);
  float4 x0 = xr[n4], x1 = xr[512 + n4], x2 = xr[1024 + n4];
  float wa = w1[o*3], wb = w1[o*3+1], wc = w1[o*3+2], bb = b1[o];
  float4 v;
  v.x = fmaf(wa, x0.x, fmaf(wb, x1.x, fmaf(wc, x2.x, bb)));
  v.y = fmaf(wa, x0.y, fmaf(wb, x1.y, fmaf(wc, x2.y, bb)));
  v.z = fmaf(wa, x0.z, fmaf(wb, x1.z, fmaf(wc, x2.z, bb)));
  v.w = fmaf(wa, x0.w, fmaf(wb, x1.w, fmaf(wc, x2.w, bb)));
  ((float4*)y1)[idx4] = v;
  float s = v.x + v.y + v.z + v.w;
  float q = v.x*v.x + v.y*v.y + v.z*v.z + v.w*v.w;
  for (int off = 32; off; off >>= 1) { s += __shfl_down(s, off); q += __shfl_down(q, off); }
  __shared__ float red[8];
  int lane = threadIdx.x & 63, wv = threadIdx.x >> 6;
  if (!lane) { red[wv] = s; red[4 + wv] = q; }
  __syncthreads();
  if (!threadIdx.x) {
    atomicAdd(&sum1[o], red[0] + red[1] + red[2] + red[3]);
    atomicAdd(&sq1[o],  red[4] + red[5] + red[6] + red[7]);
  }
}

// One-time cvt: w3 [1024][128] and w2 [128][64] f32 -> fp16 (same layouts).
__global__ __launch_bounds__(256) void k_cvt(const float* __restrict__ w3,
    const float* __restrict__ w2, unsigned short* __restrict__ w3h,
    unsigned short* __restrict__ w2h)
{
  int idx4 = blockIdx.x * 256 + threadIdx.x;   // 34816 f4, grid 136
  const float4* src; ushort4* dst; int k;
  if (idx4 < 32768) { src = (const float4*)w3; dst = (ushort4*)w3h; k = idx4; }
  else               { src = (const float4*)w2; dst = (ushort4*)w2h; k = idx4 - 32768; }
  float4 v = src[k];
  ushort4 o;
  o.x = f16r(v.x); o.y = f16r(v.y); o.z = f16r(v.z); o.w = f16r(v.w);
  dst[k] = o;
}

// conv2 via fp16 MFMA: block = (b, 128-n slice), all 128 o. K=64 = 2 k-steps.
// LDS: w2s[cb][o'][8], h1s[cb][n'][8], row'=(row+cb)&127 swizzle.
// BN1 affine derived inline from sum1/sq1; y2 fp32 out + BN2 stats.
__global__ __launch_bounds__(256, 2) void k_conv2(const float* __restrict__ y1,
    const unsigned short* __restrict__ w2h, const float* __restrict__ b2,
    const float* __restrict__ sum1, const float* __restrict__ sq1,
    const float* __restrict__ g1, const float* __restrict__ be1,
    float* __restrict__ y2, float* __restrict__ sum2, float* __restrict__ sq2)
{
  __shared__ unsigned short w2s[8 * 128 * 8];   // 16 KB
  __shared__ unsigned short h1s[8 * 128 * 8];   // 16 KB
  __shared__ float bn1[64][2];
  __shared__ float sred[2][128][2];
  int t = threadIdx.x;
  int bi = blockIdx.x;
  int b = bi >> 4, ns = bi & 15;
  int n0 = ns * 128;
  int w = t >> 6, lane = t & 63;
  int ow = w & 1, nw = w >> 1;
  int quad = lane >> 4, l15 = lane & 15;

  if (t < 64) {
    float m = sum1[t] * (1.f / 65536.f);
    float v = fmaf(-m, m, sq1[t] * (1.f / 65536.f));
    float ia = g1[t] * rsqrtf(v + EPSV);
    bn1[t][0] = ia; bn1[t][1] = fmaf(-ia, m, be1[t]);
  }
  // ---- stage w2: [cb][o'][8], o' = (o+cb)&127 ----
  for (int i = 0; i < 4; ++i) {
    int idx = i * 256 + t;             // 1024 = 128 o x 8 cb
    int o = idx >> 3, cb = idx & 7;
    uint4 v = *(const uint4*)(w2h + o * 64 + cb * 8);
    int op = (o + cb) & 127;
    *(uint4*)&w2s[(cb * 128 + op) * 8] = v;
  }
  __syncthreads();

  // ---- A-frags: o = ow*64 + ti*16 + l15, cb = s*4 + quad ----
  half8 af[4][2];
  #pragma unroll
  for (int ti = 0; ti < 4; ++ti)
    #pragma unroll
    for (int s = 0; s < 2; ++s) {
      int cb = s * 4 + quad;
      int o = ow * 64 + ti * 16 + l15;
      int op = (o + cb) & 127;
      af[ti][s] = *(const half8*)&w2s[(cb * 128 + op) * 8];
    }
  float breg[4][4];
  #pragma unroll
  for (int ti = 0; ti < 4; ++ti)
    #pragma unroll
    for (int r = 0; r < 4; ++r)
      breg[ti][r] = b2[ow * 64 + ti * 16 + quad * 4 + r];

  // ---- stage h1: relu(bn1(y1)) -> fp16, [cb][n'][8], n' = (n+cg)&127 ----
  {
    int cg = t >> 5, ng = t & 31;
    int c0 = cg * 8, nn = ng * 4;
    float av[8], sv[8];
    #pragma unroll
    for (int i = 0; i < 8; ++i) { av[i] = bn1[c0 + i][0]; sv[i] = bn1[c0 + i][1]; }
    float4 m0, m1, m2, m3, m4, m5, m6, m7;
    const float* yb = y1 + (size_t)b * C1 * NPT + n0 + nn;
    m0 = *(const float4*)(yb + (size_t)(c0 + 0) * NPT);
    m1 = *(const float4*)(yb + (size_t)(c0 + 1) * NPT);
    m2 = *(const float4*)(yb + (size_t)(c0 + 2) * NPT);
    m3 = *(const float4*)(yb + (size_t)(c0 + 3) * NPT);
    m4 = *(const float4*)(yb + (size_t)(c0 + 4) * NPT);
    m5 = *(const float4*)(yb + (size_t)(c0 + 5) * NPT);
    m6 = *(const float4*)(yb + (size_t)(c0 + 6) * NPT);
    m7 = *(const float4*)(yb + (size_t)(c0 + 7) * NPT);
    #define BN4(mm, i) \
      mm.x = fmaxf(fmaf(av[i], mm.x, sv[i]), 0.f); \
      mm.y = fmaxf(fmaf(av[i], mm.y, sv[i]), 0.f); \
      mm.z = fmaxf(fmaf(av[i], mm.z, sv[i]), 0.f); \
      mm.w = fmaxf(fmaf(av[i], mm.w, sv[i]), 0.f);
    BN4(m0,0) BN4(m1,1) BN4(m2,2) BN4(m3,3) BN4(m4,4) BN4(m5,5) BN4(m6,6) BN4(m7,7)
    #undef BN4
    #define ST_J(j, comp) { \
      uint4 pk; \
      pk.x = (unsigned)f16r(m0.comp) | ((unsigned)f16r(m1.comp) << 16); \
      pk.y = (unsigned)f16r(m2.comp) | ((unsigned)f16r(m3.comp) << 16); \
      pk.z = (unsigned)f16r(m4.comp) | ((unsigned)f16r(m5.comp) << 16); \
      pk.w = (unsigned)f16r(m6.comp) | ((unsigned)f16r(m7.comp) << 16); \
      int np = ((nn + j) + cg) & 127; \
      *(uint4*)&h1s[(cg * 128 + np) * 8] = pk; }
    ST_J(0, x) ST_J(1, y) ST_J(2, z) ST_J(3, w)
    #undef ST_J
  }
  __syncthreads();

  // ---- MFMA: acc[ti][nt] over 2 k-steps ----
  floatx4 acc[4][4];
  #pragma unroll
  for (int ti = 0; ti < 4; ++ti)
    #pragma unroll
    for (int nt = 0; nt < 4; ++nt) acc[ti][nt] = (floatx4){0.f, 0.f, 0.f, 0.f};
  #pragma unroll
  for (int s = 0; s < 2; ++s) {
    int cb = s * 4 + quad;
    half8 bf[4];
    #pragma unroll
    for (int nt = 0; nt < 4; ++nt) {
      int n = nw * 64 + nt * 16 + l15;
      int np = (n + cb) & 127;
      bf[nt] = *(const half8*)&h1s[(cb * 128 + np) * 8];
    }
    #pragma unroll
    for (int ti = 0; ti < 4; ++ti)
      #pragma unroll
      for (int nt = 0; nt < 4; ++nt)
        acc[ti][nt] = __builtin_amdgcn_mfma_f32_16x16x32_f16(af[ti][s], bf[nt], acc[ti][nt], 0, 0, 0);
  }

  // ---- epilogue: y2 = acc + b2; BN2 stats ----
  float sm[4][4], sq[4][4];
  #pragma unroll
  for (int ti = 0; ti < 4; ++ti)
    #pragma unroll
    for (int r = 0; r < 4; ++r) { sm[ti][r] = 0.f; sq[ti][r] = 0.f; }
  #pragma unroll
  for (int ti = 0; ti < 4; ++ti) {
    int o = ow * 64 + ti * 16 + quad * 4;
    #pragma unroll
    for (int nt = 0; nt < 4; ++nt) {
      int n = n0 + nw * 64 + nt * 16 + l15;
      #pragma unroll
      for (int r = 0; r < 4; ++r) {
        float val = acc[ti][nt][r] + breg[ti][r];
        y2[((size_t)b * C2 + (o + r)) * NPT + n] = val;
        sm[ti][r] += val;
        sq[ti][r] = fmaf(val, val, sq[ti][r]);
      }
    }
  }
  #pragma unroll
  for (int ti = 0; ti < 4; ++ti)
    #pragma unroll
    for (int r = 0; r < 4; ++r) {
      #pragma unroll
      for (int m = 1; m < 16; m <<= 1) {
        sm[ti][r] += __shfl_xor(sm[ti][r], m, 16);
        sq[ti][r] += __shfl_xor(sq[ti][r], m, 16);
      }
    }
  if (l15 == 0) {
    #pragma unroll
    for (int ti = 0; ti < 4; ++ti)
      #pragma unroll
      for (int r = 0; r < 4; ++r) {
        int oloc = ow * 64 + ti * 16 + quad * 4 + r;
        sred[nw][oloc][0] = sm[ti][r];
        sred[nw][oloc][1] = sq[ti][r];
      }
  }
  __syncthreads();
  if (t < 128) {
    atomicAdd(&sum2[t], sred[0][t][0] + sred[1][t][0]);
    atomicAdd(&sq2[t],  sred[0][t][1] + sred[1][t][1]);
  }
}

// conv3 via fp16 MFMA: block = (b, 128-o tile, n-half); 16 chunks of 64 n.
// BN2 affine derived inline from sum2/sq2. y3 never materialized.
__global__ __launch_bounds__(256, 2) void k_conv3(const float* __restrict__ y2,
    const unsigned short* __restrict__ w3h, const float* __restrict__ b3,
    const float* __restrict__ sum2, const float* __restrict__ sq2,
    const float* __restrict__ g2, const float* __restrict__ be2,
    float* __restrict__ mxb, float* __restrict__ mnb,
    float* __restrict__ sum3, float* __restrict__ sq3)
{
  __shared__ unsigned short w3s[16 * 128 * 8];  // 32 KB
  __shared__ unsigned short h2s[16 * 64 * 8];   // 16 KB
  __shared__ float sred[2][128][4];             // 4 KB
  __shared__ float bn2[128][2];                 // 1 KB
  int t = threadIdx.x;
  int bi = blockIdx.x;                 // bi = ot*64 + b*2 + ns
  int ot_blk = bi >> 6;
  int b  = (bi >> 1) & 31;
  int ns = bi & 1;
  int o0 = ot_blk * 128;
  int n_base = ns * 1024;
  int w = t >> 6, lane = t & 63;
  int ow = w & 1, nw = w >> 1;
  int quad = lane >> 4, l15 = lane & 15;

  if (t < 128) {
    float m = sum2[t] * (1.f / 65536.f);
    float v = fmaf(-m, m, sq2[t] * (1.f / 65536.f));
    float ia = g2[t] * rsqrtf(v + EPSV);
    bn2[t][0] = ia; bn2[t][1] = fmaf(-ia, m, be2[t]);
  }
  // ---- stage w3 o-tile: [cb][o'][8] with o' = (o+cb)&127 ----
  for (int i = 0; i < 8; ++i) {
    int idx = i * 256 + t;             // 2048 = 128 o x 16 cb
    int o = idx >> 4, cb = idx & 15;
    uint4 v = *(const uint4*)(w3h + (size_t)(o0 + o) * 128 + cb * 8);
    int op = (o + cb) & 127;
    *(uint4*)&w3s[(cb * 128 + op) * 8] = v;
  }
  __syncthreads();

  // ---- cache A-frags ----
  half8 af[4][4];
  #pragma unroll
  for (int ti = 0; ti < 4; ++ti)
    #pragma unroll
    for (int s = 0; s < 4; ++s) {
      int cb = s * 4 + quad;
      int o = ow * 64 + ti * 16 + l15;
      int op = (o + cb) & 127;
      af[ti][s] = *(const half8*)&w3s[(cb * 128 + op) * 8];
    }

  float breg[4][4], mx[4][4], mn[4][4], sm[4][4], sq[4][4];
  #pragma unroll
  for (int ti = 0; ti < 4; ++ti)
    #pragma unroll
    for (int r = 0; r < 4; ++r) {
      breg[ti][r] = b3[o0 + ow * 64 + ti * 16 + quad * 4 + r];
      mx[ti][r] = -3.4e38f; mn[ti][r] = 3.4e38f; sm[ti][r] = 0.f; sq[ti][r] = 0.f;
    }

  int cg = t >> 4, ng = t & 15;
  int c0 = cg * 8, nn = ng * 4;
  float av[8], sv[8];
  #pragma unroll
  for (int i = 0; i < 8; ++i) { av[i] = bn2[c0 + i][0]; sv[i] = bn2[c0 + i][1]; }

  for (int nc = 0; nc < 16; ++nc) {
    int n0 = n_base + nc * 64;
    __syncthreads();
    {
      float4 m0, m1, m2, m3, m4, m5, m6, m7;
      const float* yb = y2 + (size_t)b * C2 * NPT + n0 + nn;
      m0 = *(const float4*)(yb + (size_t)(c0 + 0) * NPT);
      m1 = *(const float4*)(yb + (size_t)(c0 + 1) * NPT);
      m2 = *(const float4*)(yb + (size_t)(c0 + 2) * NPT);
      m3 = *(const float4*)(yb + (size_t)(c0 + 3) * NPT);
      m4 = *(const float4*)(yb + (size_t)(c0 + 4) * NPT);
      m5 = *(const float4*)(yb + (size_t)(c0 + 5) * NPT);
      m6 = *(const float4*)(yb + (size_t)(c0 + 6) * NPT);
      m7 = *(const float4*)(yb + (size_t)(c0 + 7) * NPT);
      #define BN4(mm, i) \
        mm.x = fmaxf(fmaf(av[i], mm.x, sv[i]), 0.f); \
        mm.y = fmaxf(fmaf(av[i], mm.y, sv[i]), 0.f); \
        mm.z = fmaxf(fmaf(av[i], mm.z, sv[i]), 0.f); \
        mm.w = fmaxf(fmaf(av[i], mm.w, sv[i]), 0.f);
      BN4(m0,0) BN4(m1,1) BN4(m2,2) BN4(m3,3) BN4(m4,4) BN4(m5,5) BN4(m6,6) BN4(m7,7)
      #undef BN4
      #define ST_J(j, comp) { \
        uint4 pk; \
        pk.x = (unsigned)f16r(m0.comp) | ((unsigned)f16r(m1.comp) << 16); \
        pk.y = (unsigned)f16r(m2.comp) | ((unsigned)f16r(m3.comp) << 16); \
        pk.z = (unsigned)f16r(m4.comp) | ((unsigned)f16r(m5.comp) << 16); \
        pk.w = (unsigned)f16r(m6.comp) | ((unsigned)f16r(m7.comp) << 16); \
        int np = ((nn + j) + cg) & 63; \
        *(uint4*)&h2s[(cg * 64 + np) * 8] = pk; }
      ST_J(0, x) ST_J(1, y) ST_J(2, z) ST_J(3, w)
      #undef ST_J
    }
    __syncthreads();

    floatx4 acc[4][2];
    #pragma unroll
    for (int ti = 0; ti < 4; ++ti)
      #pragma unroll
      for (int nt = 0; nt < 2; ++nt) acc[ti][nt] = (floatx4){0.f, 0.f, 0.f, 0.f};
    #pragma unroll
    for (int s = 0; s < 4; ++s) {
      int cb = s * 4 + quad;
      half8 bf[2];
      #pragma unroll
      for (int nt = 0; nt < 2; ++nt) {
        int n = nw * 32 + nt * 16 + l15;
        int np = (n + cb) & 63;
        bf[nt] = *(const half8*)&h2s[(cb * 64 + np) * 8];
      }
      #pragma unroll
      for (int ti = 0; ti < 4; ++ti) {
        acc[ti][0] = __builtin_amdgcn_mfma_f32_16x16x32_f16(af[ti][s], bf[0], acc[ti][0], 0, 0, 0);
        acc[ti][1] = __builtin_amdgcn_mfma_f32_16x16x32_f16(af[ti][s], bf[1], acc[ti][1], 0, 0, 0);
      }
    }
    #pragma unroll
    for (int ti = 0; ti < 4; ++ti)
      #pragma unroll
      for (int nt = 0; nt < 2; ++nt)
        #pragma unroll
        for (int r = 0; r < 4; ++r) {
          float v = acc[ti][nt][r] + breg[ti][r];
          mx[ti][r] = fmaxf(mx[ti][r], v);
          mn[ti][r] = fminf(mn[ti][r], v);
          sm[ti][r] += v;
          sq[ti][r] = fmaf(v, v, sq[ti][r]);
        }
  }

  #pragma unroll
  for (int ti = 0; ti < 4; ++ti)
    #pragma unroll
    for (int r = 0; r < 4; ++r) {
      #pragma unroll
      for (int m = 1; m < 16; m <<= 1) {
        mx[ti][r] = fmaxf(mx[ti][r], __shfl_xor(mx[ti][r], m, 16));
        mn[ti][r] = fminf(mn[ti][r], __shfl_xor(mn[ti][r], m, 16));
        sm[ti][r] += __shfl_xor(sm[ti][r], m, 16);
        sq[ti][r] += __shfl_xor(sq[ti][r], m, 16);
      }
    }
  if (l15 == 0) {
    #pragma unroll
    for (int ti = 0; ti < 4; ++ti)
      #pragma unroll
      for (int r = 0; r < 4; ++r) {
        int oloc = ow * 64 + ti * 16 + quad * 4 + r;
        sred[nw][oloc][0] = mx[ti][r];
        sred[nw][oloc][1] = mn[ti][r];
        sred[nw][oloc][2] = sm[ti][r];
        sred[nw][oloc][3] = sq[ti][r];
      }
  }
  __syncthreads();
  if (t < 128) {
    int o = o0 + t;
    mxb[ns * 32768 + b * 1024 + o] = fmaxf(sred[0][t][0], sred[1][t][0]);
    mnb[ns * 32768 + b * 1024 + o] = fminf(sred[0][t][1], sred[1][t][1]);
    atomicAdd(&sum3[o], sred[0][t][2] + sred[1][t][2]);
    atomicAdd(&sq3[o],  sred[0][t][3] + sred[1][t][3]);
  }
}

// pooled[b,c] = a3*(a3>=0 ? max : min) + s3; BN3 affine derived inline.
__global__ __launch_bounds__(256) void k_pooled(const float* __restrict__ sum3,
    const float* __restrict__ sq3, const float* __restrict__ g3,
    const float* __restrict__ be3, const float* __restrict__ mxb,
    const float* __restrict__ mnb, float* __restrict__ pool)
{
  int idx4 = blockIdx.x * 256 + threadIdx.x;   // 8192 f4, grid 32
  int c4 = idx4 & 255;
  float4 S = ((const float4*)sum3)[c4];
  float4 Q = ((const float4*)sq3)[c4];
  float4 G = ((const float4*)g3)[c4];
  float4 Be = ((const float4*)be3)[c4];
  float4 a, s;
  const float inv = 1.f / 65536.f;
  #define MK(c) { float m = S.c * inv; float v = fmaf(-m, m, Q.c * inv); \
                  a.c = G.c * rsqrtf(v + EPSV); s.c = fmaf(-a.c, m, Be.c); }
  MK(x) MK(y) MK(z) MK(w)
  #undef MK
  float4 mx0 = ((const float4*)mxb)[idx4];
  float4 mx1 = ((const float4*)mxb)[idx4 + 8192];
  float4 mn0 = ((const float4*)mnb)[idx4];
  float4 mn1 = ((const float4*)mnb)[idx4 + 8192];
  float4 mx, mn;
  mx.x = fmaxf(mx0.x, mx1.x); mx.y = fmaxf(mx0.y, mx1.y);
  mx.z = fmaxf(mx0.z, mx1.z); mx.w = fmaxf(mx0.w, mx1.w);
  mn.x = fminf(mn0.x, mn1.x); mn.y = fminf(mn0.y, mn1.y);
  mn.z = fminf(mn0.z, mn1.z); mn.w = fminf(mn0.w, mn1.w);
  float4 r;
  r.x = fmaf(a.x, (a.x >= 0.f ? mx.x : mn.x), s.x);
  r.y = fmaf(a.y, (a.y >= 0.f ? mx.y : mn.y), s.y);
  r.z = fmaf(a.z, (a.z >= 0.f ? mx.z : mn.z), s.z);
  r.w = fmaf(a.w, (a.w >= 0.f ? mx.w : mn.w), s.w);
  ((float4*)pool)[idx4] = r;
}

// FC layer: outRaw[b,f] = bias[f] + sum_k W[f,k]*T(in[b,k]); batch stats.
// T = relu(BN(x)) with BN affine derived inline from sumIn/sqIn (or identity).
__global__ __launch_bounds__(256) void k_fc(const float* __restrict__ in,
    const float* __restrict__ W, const float* __restrict__ bias,
    const float* __restrict__ sumIn, const float* __restrict__ sqIn,
    const float* __restrict__ gIn, const float* __restrict__ beIn,
    float* __restrict__ outRaw, float* __restrict__ sumF, float* __restrict__ sqF,
    int K, int Fout, int k4shift)
{
  __shared__ float ins[8 * 1024];
  __shared__ float red[2][4][64];
  int t = threadIdx.x;
  int f0 = blockIdx.x * 64;
  int b0 = blockIdx.y * 8;
  int K4 = K >> 2;
  const float invb = 1.f / 32.f;
  for (int idx = t; idx < 8 * K4; idx += 256) {
    int bl = idx >> k4shift;
    int k4 = idx & (K4 - 1);
    float4 v = *(const float4*)(in + (size_t)(b0 + bl) * K + k4 * 4);
    if (sumIn) {
      float4 S = ((const float4*)sumIn)[k4];
      float4 Q = ((const float4*)sqIn)[k4];
      float4 G = ((const float4*)gIn)[k4];
      float4 Be = ((const float4*)beIn)[k4];
      #define TRF(c) { float m = S.c * invb; float vv = fmaf(-m, m, Q.c * invb); \
                       float a = G.c * rsqrtf(vv + EPSV); \
                       v.c = fmaxf(fmaf(a, v.c, fmaf(-a, m, Be.c)), 0.f); }
      TRF(x) TRF(y) TRF(z) TRF(w)
      #undef TRF
    }
    *(float4*)&ins[bl * K + k4 * 4] = v;
  }
  __syncthreads();
  int f = t & 63, bg = t >> 6;
  const float* wr = W + (size_t)(f0 + f) * K;
  const float* iA = &ins[(bg * 2) * K];
  const float* iB = &ins[(bg * 2 + 1) * K];
  float acc0 = bias[f0 + f], acc1 = acc0;
  for (int k4 = 0; k4 < K4; ++k4) {
    float4 w = *(const float4*)&wr[k4 * 4];
    float4 a = *(const float4*)&iA[k4 * 4];
    float4 c = *(const float4*)&iB[k4 * 4];
    acc0 = fmaf(w.x, a.x, acc0); acc0 = fmaf(w.y, a.y, acc0);
    acc0 = fmaf(w.z, a.z, acc0); acc0 = fmaf(w.w, a.w, acc0);
    acc1 = fmaf(w.x, c.x, acc1); acc1 = fmaf(w.y, c.y, acc1);
    acc1 = fmaf(w.z, c.z, acc1); acc1 = fmaf(w.w, c.w, acc1);
  }
  outRaw[(size_t)(b0 + bg * 2) * Fout + f0 + f] = acc0;
  outRaw[(size_t)(b0 + bg * 2 + 1) * Fout + f0 + f] = acc1;
  red[0][bg][f] = acc0 + acc1;
  red[1][bg][f] = fmaf(acc0, acc0, acc1 * acc1);
  __syncthreads();
  if (t < 64) {
    float s = red[0][0][t] + red[0][1][t] + red[0][2][t] + red[0][3][t];
    float q = red[1][0][t] + red[1][1][t] + red[1][2][t] + red[1][3][t];
    atomicAdd(&sumF[f0 + t], s);
    atomicAdd(&sqF[f0 + t], q);
  }
}

// Head: p = relu(BN(f2)) @ wp.T + bp; Horn-quaternion SO(3) projection -> [B,4,4].
// BN-F2 affine derived inline into LDS.
__global__ __launch_bounds__(384) void k_head(const float* __restrict__ f2r,
    const float* __restrict__ sumF2, const float* __restrict__ sqF2,
    const float* __restrict__ gf2, const float* __restrict__ bef2,
    const float* __restrict__ wp, const float* __restrict__ bp,
    float* __restrict__ out)
{
  __shared__ float pS[32 * 12];
  __shared__ float bnf[256][2];
  int t = threadIdx.x;
  if (t < 256) {
    float m = sumF2[t] * (1.f / 32.f);
    float v = fmaf(-m, m, sqF2[t] * (1.f / 32.f));
    float a = gf2[t] * rsqrtf(v + EPSV);
    bnf[t][0] = a; bnf[t][1] = fmaf(-a, m, bef2[t]);
  }
  __syncthreads();
  {
    int b = t / 12, j = t % 12;
    const float* w = wp + j * 256;
    const float* fr = f2r + b * 256;
    float acc = bp[j];
    for (int c = 0; c < 256; ++c) {
      float h = fmaxf(fmaf(bnf[c][0], fr[c], bnf[c][1]), 0.f);
      acc = fmaf(w[c], h, acc);
    }
    pS[t] = acc;
  }
  __syncthreads();
  if (t < 32) {
    const float* p = &pS[t * 12];
    float m00=p[0],m01=p[1],m02=p[2],m10=p[3],m11=p[4],m12=p[5],m20=p[6],m21=p[7],m22=p[8];
    float P[4][4];
    P[0][0]=m00+m11+m22; P[0][1]=m21-m12;     P[0][2]=m02-m20;     P[0][3]=m10-m01;
    P[1][1]=m00-m11-m22; P[1][2]=m01+m10;     P[1][3]=m02+m20;
    P[2][2]=m11-m00-m22; P[2][3]=m12+m21;
    P[3][3]=m22-m00-m11;
    P[1][0]=P[0][1]; P[2][0]=P[0][2]; P[3][0]=P[0][3];
    P[2][1]=P[1][2]; P[3][1]=P[1][3]; P[3][2]=P[2][3];
    float fn = sqrtf(m00*m00+m01*m01+m02*m02+m10*m10+m11*m11+m12*m12+m20*m20+m21*m21+m22*m22);
    float inv = 1.f / (2.f * fn + 1e-30f);
    #pragma unroll
    for (int i = 0; i < 4; ++i)
      #pragma unroll
      for (int j = 0; j < 4; ++j) P[i][j] *= inv;
    P[0][0] += 1.f; P[1][1] += 1.f; P[2][2] += 1.f; P[3][3] += 1.f;
    for (int it = 0; it < 16; ++it) {
      float Q[4][4];
      #pragma unroll
      for (int i = 0; i < 4; ++i)
        #pragma unroll
        for (int j = 0; j < 4; ++j)
          Q[i][j] = P[i][0]*P[0][j] + P[i][1]*P[1][j] + P[i][2]*P[2][j] + P[i][3]*P[3][j];
      float mxa = 0.f;
      #pragma unroll
      for (int i = 0; i < 4; ++i)
        #pragma unroll
        for (int j = 0; j < 4; ++j) mxa = fmaxf(mxa, fabsf(Q[i][j]));
      float r = 1.f / mxa;
      #pragma unroll
      for (int i = 0; i < 4; ++i)
        #pragma unroll
        for (int j = 0; j < 4; ++j) P[i][j] = Q[i][j] * r;
    }
    float bestn = -1.f; int bj = 0;
    #pragma unroll
    for (int j = 0; j < 4; ++j) {
      float nn = P[0][j]*P[0][j] + P[1][j]*P[1][j] + P[2][j]*P[2][j] + P[3][j]*P[3][j];
      if (nn > bestn) { bestn = nn; bj = j; }
    }
    float qw = P[0][bj], qx = P[1][bj], qy = P[2][bj], qz = P[3][bj];
    float qn = rsqrtf(qw*qw + qx*qx + qy*qy + qz*qz);
    qw *= qn; qx *= qn; qy *= qn; qz *= qn;
    float* ob = out + t * 16;
    ob[0]  = 1.f - 2.f*(qy*qy + qz*qz);
    ob[1]  = 2.f*(qx*qy - qw*qz);
    ob[2]  = 2.f*(qx*qz + qw*qy);
    ob[3]  = p[9];
    ob[4]  = 2.f*(qx*qy + qw*qz);
    ob[5]  = 1.f - 2.f*(qx*qx + qz*qz);
    ob[6]  = 2.f*(qy*qz - qw*qx);
    ob[7]  = p[10];
    ob[8]  = 2.f*(qx*qz - qw*qy);
    ob[9]  = 2.f*(qy*qz + qw*qx);
    ob[10] = 1.f - 2.f*(qx*qx + qy*qy);
    ob[11] = p[11];
    ob[12] = 0.f; ob[13] = 0.f; ob[14] = 0.f; ob[15] = 1.f;
  }
}

extern "C" void kernel_launch(void* const* d_in, const int* in_sizes, int n_in,
                              void* d_out, int out_size, void* d_ws, size_t ws_size,
                              hipStream_t stream)
{
  (void)in_sizes; (void)n_in; (void)out_size;
  if (ws_size < (size_t)WS_FLOATS * sizeof(float)) return;
  const float* x   = (const float*)d_in[0];
  const float* w1  = (const float*)d_in[1];
  const float* b1  = (const float*)d_in[2];
  const float* g1  = (const float*)d_in[3];
  const float* be1 = (const float*)d_in[4];
  const float* w2  = (const float*)d_in[5];
  const float* b2  = (const float*)d_in[6];
  const float* g2  = (const float*)d_in[7];
  const float* be2 = (const float*)d_in[8];
  const float* w3  = (const float*)d_in[9];
  const float* b3  = (const float*)d_in[10];
  const float* g3  = (const float*)d_in[11];
  const float* be3 = (const float*)d_in[12];
  const float* wf1 = (const float*)d_in[13];
  const float* bf1 = (const float*)d_in[14];
  const float* gf1 = (const float*)d_in[15];
  const float* bef1= (const float*)d_in[16];
  const float* wf2 = (const float*)d_in[17];
  const float* bf2 = (const float*)d_in[18];
  const float* gf2 = (const float*)d_in[19];
  const float* bef2= (const float*)d_in[20];
  const float* wp  = (const float*)d_in[21];
  const float* bp  = (const float*)d_in[22];
  float* ws  = (float*)d_ws;
  float* out = (float*)d_out;

  hipMemsetAsync((void*)(ws + OFF_Z), 0, ZN * sizeof(float), stream);
  k_cvt<<<136, 256, 0, stream>>>(w3, w2, (unsigned short*)(ws + OFF_W3H),
                                 (unsigned short*)(ws + OFF_W2H));
  k_conv1<<<4096, 256, 0, stream>>>(x, w1, b1, ws + OFF_Y1, ws + OFF_SUM1, ws + OFF_SQ1);
  k_conv2<<<512, 256, 0, stream>>>(ws + OFF_Y1, (const unsigned short*)(ws + OFF_W2H), b2,
                                   ws + OFF_SUM1, ws + OFF_SQ1, g1, be1,
                                   ws + OFF_Y2, ws + OFF_SUM2, ws + OFF_SQ2);
  k_conv3<<<512, 256, 0, stream>>>(ws + OFF_Y2, (const unsigned short*)(ws + OFF_W3H), b3,
                                   ws + OFF_SUM2, ws + OFF_SQ2, g2, be2,
                                   ws + OFF_MX, ws + OFF_MN, ws + OFF_SUM3, ws + OFF_SQ3);
  k_pooled<<<32, 256, 0, stream>>>(ws + OFF_SUM3, ws + OFF_SQ3, g3, be3,
                                   ws + OFF_MX, ws + OFF_MN, ws + OFF_POOL);
  k_fc<<<dim3(8, 4), 256, 0, stream>>>(ws + OFF_POOL, wf1, bf1,
                                       nullptr, nullptr, nullptr, nullptr,
                                       ws + OFF_F1R, ws + OFF_SUMF1, ws + OFF_SQF1,
                                       1024, 512, 8);
  k_fc<<<dim3(4, 4), 256, 0, stream>>>(ws + OFF_F1R, wf2, bf2,
                                       ws + OFF_SUMF1, ws + OFF_SQF1, gf1, bef1,
                                       ws + OFF_F2R, ws + OFF_SUMF2, ws + OFF_SQF2,
                                       512, 256, 7);
  k_head<<<1, 384, 0, stream>>>(ws + OFF_F2R, ws + OFF_SUMF2, ws + OFF_SQF2, gf2, bef2,
                                wp, bp, out);
}

// Round 5
// 254.378 us; speedup vs baseline: 2.7414x; 1.0617x over previous
//
#include <hip/hip_runtime.h>

// PointNetRot9d. Round 5:
//  - k_fc was 45 us with 1% VALUBusy: runtime-K loop => no unroll => serialized
//    vmcnt(0) chains on 32 blocks. New k_fc1/k_fc2: compile-time unrolled
//    K-chunks, K-split across blocks, atomicAdd into zeroed f1r/f2r; stats
//    derived inline by the consumer from the raw matrix.
//  - conv3 had 4.3M LDS bank conflicts: ST_J staging writes hit 2 granules per
//    16-lane phase (8-way). New swizzle np = n ^ (((n>>3)^cb)&7): 2-way (free)
//    for writes AND reads (verified by bank arithmetic for both conv2/conv3).
//  - y1/y2 stored fp16 (consumers decode + apply BN from exact fp32 stats):
//    halves conv3's 256 MB y2 L2 re-read and conv1/conv2 I/O.
//  - conv2/conv3 grids -> 1024 blocks (finer n-split; conv3 ns=4 slots).

#define NPT 2048
#define C1 64
#define C2 128
#define EPSV 1e-5f

typedef __attribute__((ext_vector_type(8))) _Float16 half8;
typedef __attribute__((ext_vector_type(4))) float floatx4;

// ---- workspace layout (float-slot offsets) ----
#define OFF_Y1H   0               // 32*64*2048 halves = 2097152 slots
#define OFF_Y2H   2097152         // 32*128*2048 halves = 4194304 slots
#define OFF_Z     6291456         // zeroed region start
#define OFF_SUM1  (OFF_Z)
#define OFF_SQ1   (OFF_Z+64)
#define OFF_SUM2  (OFF_Z+128)
#define OFF_SQ2   (OFF_Z+256)
#define OFF_SUM3  (OFF_Z+384)
#define OFF_SQ3   (OFF_Z+1408)
#define OFF_F1R   (OFF_Z+2432)    // 32*512 = 16384
#define OFF_F2R   (OFF_Z+18816)   // 32*256 = 8192
#define ZN        27008
#define OFF_MX    (OFF_Z+27008)   // 4 ns-slots * 32*1024 = 131072
#define OFF_MN    (OFF_MX+131072)
#define OFF_POOL  (OFF_MN+131072) // 32768
#define OFF_W3H   (OFF_POOL+32768)// 131072 halves = 65536 slots
#define OFF_W2H   (OFF_W3H+65536) // 8192 halves = 4096 slots
#define WS_FLOATS (OFF_W2H+4096)  // 6,683,008 floats = 26.7 MB

static __device__ inline unsigned short f16r(float f) {
  _Float16 h = (_Float16)f;
  return __builtin_bit_cast(unsigned short, h);
}
static __device__ inline float h2f(unsigned short u) {
  return (float)__builtin_bit_cast(_Float16, u);
}
// staging swizzle: bijection on n (per cb); spreads LDS granules within every
// 16-lane phase for both b128 writes and reads (2-way = free, m136).
static __device__ inline int SW(int n, int cb) { return n ^ (((n >> 3) ^ cb) & 7); }

// conv1: y1h[b,o,n] = fp16(sum_d w1[o,d]*x[b,d,n] + b1[o]); exact fp32 stats.
__global__ __launch_bounds__(256) void k_conv1(const float* __restrict__ x,
    const float* __restrict__ w1, const float* __restrict__ b1,
    unsigned short* __restrict__ y1h, float* __restrict__ sum1, float* __restrict__ sq1)
{
  int idx4 = blockIdx.x * 256 + threadIdx.x;     // f4 index into [32][64][512]
  int n4 = idx4 & 511;
  int o  = (idx4 >> 9) & 63;
  int b  = idx4 >> 15;
  const float4* xr = (const float4*)(x + (size_t)b * 3 * NPT);
  float4 x0 = xr[n4], x1 = xr[512 + n4], x2 = xr[1024 + n4];
  float wa = w1[o*3], wb = w1[o*3+1], wc = w1[o*3+2], bb = b1[o];
  float4 v;
  v.x = fmaf(wa, x0.x, fmaf(wb, x1.x, fmaf(wc, x2.x, bb)));
  v.y = fmaf(wa, x0.y, fmaf(wb, x1.y, fmaf(wc, x2.y, bb)));
  v.z = fmaf(wa, x0.z, fmaf(wb, x1.z, fmaf(wc, x2.z, bb)));
  v.w = fmaf(wa, x0.w, fmaf(wb, x1.w, fmaf(wc, x2.w, bb)));
  ushort4 p;
  p.x = f16r(v.x); p.y = f16r(v.y); p.z = f16r(v.z); p.w = f16r(v.w);
  ((ushort4*)y1h)[idx4] = p;
  float s = v.x + v.y + v.z + v.w;
  float q = v.x*v.x + v.y*v.y + v.z*v.z + v.w*v.w;
  for (int off = 32; off; off >>= 1) { s += __shfl_down(s, off); q += __shfl_down(q, off); }
  __shared__ float red[8];
  int lane = threadIdx.x & 63, wv = threadIdx.x >> 6;
  if (!lane) { red[wv] = s; red[4 + wv] = q; }
  __syncthreads();
  if (!threadIdx.x) {
    atomicAdd(&sum1[o], red[0] + red[1] + red[2] + red[3]);
    atomicAdd(&sq1[o],  red[4] + red[5] + red[6] + red[7]);
  }
}

// One-time cvt: w3 [1024][128] and w2 [128][64] f32 -> fp16.
__global__ __launch_bounds__(256) void k_cvt(const float* __restrict__ w3,
    const float* __restrict__ w2, unsigned short* __restrict__ w3h,
    unsigned short* __restrict__ w2h)
{
  int idx4 = blockIdx.x * 256 + threadIdx.x;   // 34816 f4, grid 136
  const float4* src; ushort4* dst; int k;
  if (idx4 < 32768) { src = (const float4*)w3; dst = (ushort4*)w3h; k = idx4; }
  else               { src = (const float4*)w2; dst = (ushort4*)w2h; k = idx4 - 32768; }
  float4 v = src[k];
  ushort4 o;
  o.x = f16r(v.x); o.y = f16r(v.y); o.z = f16r(v.z); o.w = f16r(v.w);
  dst[k] = o;
}

// conv2 MFMA: block = (b, 64-n slice) x all 128 o. K=64 = 2 k-steps.
__global__ __launch_bounds__(256, 2) void k_conv2(const unsigned short* __restrict__ y1h,
    const unsigned short* __restrict__ w2h, const float* __restrict__ b2,
    const float* __restrict__ sum1, const float* __restrict__ sq1,
    const float* __restrict__ g1, const float* __restrict__ be1,
    unsigned short* __restrict__ y2h, float* __restrict__ sum2, float* __restrict__ sq2)
{
  __shared__ unsigned short w2s[8 * 128 * 8];   // 16 KB
  __shared__ unsigned short h1s[8 * 64 * 8];    // 8 KB
  __shared__ float bn1[64][2];
  __shared__ float sred[2][128][2];
  int t = threadIdx.x;
  int bi = blockIdx.x;                 // 1024 = 32 b x 32 ns
  int b = bi >> 5, ns = bi & 31;
  int n0 = ns * 64;
  int w = t >> 6, lane = t & 63;
  int ow = w & 1, nw = w >> 1;
  int quad = lane >> 4, l15 = lane & 15;

  if (t < 64) {
    float m = sum1[t] * (1.f / 65536.f);
    float v = fmaf(-m, m, sq1[t] * (1.f / 65536.f));
    float ia = g1[t] * rsqrtf(v + EPSV);
    bn1[t][0] = ia; bn1[t][1] = fmaf(-ia, m, be1[t]);
  }
  // stage w2: [cb][o'][8], o' = (o+cb)&127
  for (int i = 0; i < 4; ++i) {
    int idx = i * 256 + t;             // 1024 = 128 o x 8 cb
    int o = idx >> 3, cb = idx & 7;
    uint4 v = *(const uint4*)(w2h + o * 64 + cb * 8);
    int op = (o + cb) & 127;
    *(uint4*)&w2s[(cb * 128 + op) * 8] = v;
  }
  __syncthreads();

  half8 af[4][2];
  #pragma unroll
  for (int ti = 0; ti < 4; ++ti)
    #pragma unroll
    for (int s = 0; s < 2; ++s) {
      int cb = s * 4 + quad;
      int o = ow * 64 + ti * 16 + l15;
      int op = (o + cb) & 127;
      af[ti][s] = *(const half8*)&w2s[(cb * 128 + op) * 8];
    }
  float breg[4][4];
  #pragma unroll
  for (int ti = 0; ti < 4; ++ti)
    #pragma unroll
    for (int r = 0; r < 4; ++r)
      breg[ti][r] = b2[ow * 64 + ti * 16 + quad * 4 + r];

  // stage h1 = fp16(relu(bn1(y1h))): [cb][n'][8], n' = SW(n, cg)
  {
    int cg = t >> 5, ng = t & 31;      // 8 c-groups x 32 n-pairs
    int c0 = cg * 8, nn = ng * 2;
    float av[8], sv[8];
    #pragma unroll
    for (int i = 0; i < 8; ++i) { av[i] = bn1[c0 + i][0]; sv[i] = bn1[c0 + i][1]; }
    const unsigned short* yb = y1h + (size_t)(b * C1 + c0) * NPT + n0 + nn;
    float v0[8], v1[8];
    #pragma unroll
    for (int i = 0; i < 8; ++i) {
      unsigned u = *(const unsigned*)(yb + (size_t)i * NPT);
      v0[i] = fmaxf(fmaf(av[i], h2f((unsigned short)(u & 0xffffu)), sv[i]), 0.f);
      v1[i] = fmaxf(fmaf(av[i], h2f((unsigned short)(u >> 16)), sv[i]), 0.f);
    }
    uint4 pk;
    pk.x = (unsigned)f16r(v0[0]) | ((unsigned)f16r(v0[1]) << 16);
    pk.y = (unsigned)f16r(v0[2]) | ((unsigned)f16r(v0[3]) << 16);
    pk.z = (unsigned)f16r(v0[4]) | ((unsigned)f16r(v0[5]) << 16);
    pk.w = (unsigned)f16r(v0[6]) | ((unsigned)f16r(v0[7]) << 16);
    *(uint4*)&h1s[(cg * 64 + SW(nn, cg)) * 8] = pk;
    pk.x = (unsigned)f16r(v1[0]) | ((unsigned)f16r(v1[1]) << 16);
    pk.y = (unsigned)f16r(v1[2]) | ((unsigned)f16r(v1[3]) << 16);
    pk.z = (unsigned)f16r(v1[4]) | ((unsigned)f16r(v1[5]) << 16);
    pk.w = (unsigned)f16r(v1[6]) | ((unsigned)f16r(v1[7]) << 16);
    *(uint4*)&h1s[(cg * 64 + SW(nn + 1, cg)) * 8] = pk;
  }
  __syncthreads();

  floatx4 acc[4][2];
  #pragma unroll
  for (int ti = 0; ti < 4; ++ti)
    #pragma unroll
    for (int nt = 0; nt < 2; ++nt) acc[ti][nt] = (floatx4){0.f, 0.f, 0.f, 0.f};
  #pragma unroll
  for (int s = 0; s < 2; ++s) {
    int cb = s * 4 + quad;
    half8 bf[2];
    #pragma unroll
    for (int nt = 0; nt < 2; ++nt) {
      int n = nw * 32 + nt * 16 + l15;
      bf[nt] = *(const half8*)&h1s[(cb * 64 + SW(n, cb)) * 8];
    }
    #pragma unroll
    for (int ti = 0; ti < 4; ++ti) {
      acc[ti][0] = __builtin_amdgcn_mfma_f32_16x16x32_f16(af[ti][s], bf[0], acc[ti][0], 0, 0, 0);
      acc[ti][1] = __builtin_amdgcn_mfma_f32_16x16x32_f16(af[ti][s], bf[1], acc[ti][1], 0, 0, 0);
    }
  }

  // epilogue: y2h = fp16(acc + b2); exact fp32 BN2 stats
  float sm[4][4], sq[4][4];
  #pragma unroll
  for (int ti = 0; ti < 4; ++ti)
    #pragma unroll
    for (int r = 0; r < 4; ++r) { sm[ti][r] = 0.f; sq[ti][r] = 0.f; }
  #pragma unroll
  for (int ti = 0; ti < 4; ++ti) {
    int o = ow * 64 + ti * 16 + quad * 4;
    #pragma unroll
    for (int nt = 0; nt < 2; ++nt) {
      int n = n0 + nw * 32 + nt * 16 + l15;
      #pragma unroll
      for (int r = 0; r < 4; ++r) {
        float val = acc[ti][nt][r] + breg[ti][r];
        y2h[(size_t)(b * C2 + o + r) * NPT + n] = f16r(val);
        sm[ti][r] += val;
        sq[ti][r] = fmaf(val, val, sq[ti][r]);
      }
    }
  }
  #pragma unroll
  for (int ti = 0; ti < 4; ++ti)
    #pragma unroll
    for (int r = 0; r < 4; ++r) {
      #pragma unroll
      for (int m = 1; m < 16; m <<= 1) {
        sm[ti][r] += __shfl_xor(sm[ti][r], m, 16);
        sq[ti][r] += __shfl_xor(sq[ti][r], m, 16);
      }
    }
  if (l15 == 0) {
    #pragma unroll
    for (int ti = 0; ti < 4; ++ti)
      #pragma unroll
      for (int r = 0; r < 4; ++r) {
        int oloc = ow * 64 + ti * 16 + quad * 4 + r;
        sred[nw][oloc][0] = sm[ti][r];
        sred[nw][oloc][1] = sq[ti][r];
      }
  }
  __syncthreads();
  if (t < 128) {
    atomicAdd(&sum2[t], sred[0][t][0] + sred[1][t][0]);
    atomicAdd(&sq2[t],  sred[0][t][1] + sred[1][t][1]);
  }
}

// conv3 MFMA: block = (b, 128-o tile, n-quarter); 8 chunks of 64 n.
__global__ __launch_bounds__(256, 2) void k_conv3(const unsigned short* __restrict__ y2h,
    const unsigned short* __restrict__ w3h, const float* __restrict__ b3,
    const float* __restrict__ sum2, const float* __restrict__ sq2,
    const float* __restrict__ g2, const float* __restrict__ be2,
    float* __restrict__ mxb, float* __restrict__ mnb,
    float* __restrict__ sum3, float* __restrict__ sq3)
{
  __shared__ unsigned short w3s[16 * 128 * 8];  // 32 KB
  __shared__ unsigned short h2s[16 * 64 * 8];   // 16 KB
  __shared__ float sred[2][128][4];             // 4 KB
  __shared__ float bn2[128][2];                 // 1 KB
  int t = threadIdx.x;
  int bi = blockIdx.x;                 // 1024 = 8 ot x 32 b x 4 ns
  int ot_blk = bi >> 7;
  int b  = (bi >> 2) & 31;
  int ns = bi & 3;
  int o0 = ot_blk * 128;
  int n_base = ns * 512;
  int w = t >> 6, lane = t & 63;
  int ow = w & 1, nw = w >> 1;
  int quad = lane >> 4, l15 = lane & 15;

  if (t < 128) {
    float m = sum2[t] * (1.f / 65536.f);
    float v = fmaf(-m, m, sq2[t] * (1.f / 65536.f));
    float ia = g2[t] * rsqrtf(v + EPSV);
    bn2[t][0] = ia; bn2[t][1] = fmaf(-ia, m, be2[t]);
  }
  // stage w3 o-tile: [cb][o'][8], o' = (o+cb)&127 (2-way verified)
  for (int i = 0; i < 8; ++i) {
    int idx = i * 256 + t;             // 2048 = 128 o x 16 cb
    int o = idx >> 4, cb = idx & 15;
    uint4 v = *(const uint4*)(w3h + (size_t)(o0 + o) * 128 + cb * 8);
    int op = (o + cb) & 127;
    *(uint4*)&w3s[(cb * 128 + op) * 8] = v;
  }
  __syncthreads();

  half8 af[4][4];
  #pragma unroll
  for (int ti = 0; ti < 4; ++ti)
    #pragma unroll
    for (int s = 0; s < 4; ++s) {
      int cb = s * 4 + quad;
      int o = ow * 64 + ti * 16 + l15;
      int op = (o + cb) & 127;
      af[ti][s] = *(const half8*)&w3s[(cb * 128 + op) * 8];
    }

  float breg[4][4], mx[4][4], mn[4][4], sm[4][4], sq[4][4];
  #pragma unroll
  for (int ti = 0; ti < 4; ++ti)
    #pragma unroll
    for (int r = 0; r < 4; ++r) {
      breg[ti][r] = b3[o0 + ow * 64 + ti * 16 + quad * 4 + r];
      mx[ti][r] = -3.4e38f; mn[ti][r] = 3.4e38f; sm[ti][r] = 0.f; sq[ti][r] = 0.f;
    }

  int cg = t >> 4, ng = t & 15;
  int c0 = cg * 8, nn = ng * 4;
  float av[8], sv[8];
  #pragma unroll
  for (int i = 0; i < 8; ++i) { av[i] = bn2[c0 + i][0]; sv[i] = bn2[c0 + i][1]; }

  for (int nc = 0; nc < 8; ++nc) {
    int n0 = n_base + nc * 64;
    __syncthreads();
    // stage h2 = fp16(relu(bn2(y2h))): [cb][n'][8], n' = SW(n, cg)
    {
      float4 m[8];
      const unsigned short* yb = y2h + (size_t)(b * C2 + c0) * NPT + n0 + nn;
      #pragma unroll
      for (int i = 0; i < 8; ++i) {
        ushort4 u = *(const ushort4*)(yb + (size_t)i * NPT);
        m[i].x = fmaxf(fmaf(av[i], h2f(u.x), sv[i]), 0.f);
        m[i].y = fmaxf(fmaf(av[i], h2f(u.y), sv[i]), 0.f);
        m[i].z = fmaxf(fmaf(av[i], h2f(u.z), sv[i]), 0.f);
        m[i].w = fmaxf(fmaf(av[i], h2f(u.w), sv[i]), 0.f);
      }
      #define ST_J(j, comp) { \
        uint4 pk; \
        pk.x = (unsigned)f16r(m[0].comp) | ((unsigned)f16r(m[1].comp) << 16); \
        pk.y = (unsigned)f16r(m[2].comp) | ((unsigned)f16r(m[3].comp) << 16); \
        pk.z = (unsigned)f16r(m[4].comp) | ((unsigned)f16r(m[5].comp) << 16); \
        pk.w = (unsigned)f16r(m[6].comp) | ((unsigned)f16r(m[7].comp) << 16); \
        *(uint4*)&h2s[(cg * 64 + SW(nn + j, cg)) * 8] = pk; }
      ST_J(0, x) ST_J(1, y) ST_J(2, z) ST_J(3, w)
      #undef ST_J
    }
    __syncthreads();

    floatx4 acc[4][2];
    #pragma unroll
    for (int ti = 0; ti < 4; ++ti)
      #pragma unroll
      for (int nt = 0; nt < 2; ++nt) acc[ti][nt] = (floatx4){0.f, 0.f, 0.f, 0.f};
    #pragma unroll
    for (int s = 0; s < 4; ++s) {
      int cb = s * 4 + quad;
      half8 bf[2];
      #pragma unroll
      for (int nt = 0; nt < 2; ++nt) {
        int n = nw * 32 + nt * 16 + l15;
        bf[nt] = *(const half8*)&h2s[(cb * 64 + SW(n, cb)) * 8];
      }
      #pragma unroll
      for (int ti = 0; ti < 4; ++ti) {
        acc[ti][0] = __builtin_amdgcn_mfma_f32_16x16x32_f16(af[ti][s], bf[0], acc[ti][0], 0, 0, 0);
        acc[ti][1] = __builtin_amdgcn_mfma_f32_16x16x32_f16(af[ti][s], bf[1], acc[ti][1], 0, 0, 0);
      }
    }
    #pragma unroll
    for (int ti = 0; ti < 4; ++ti)
      #pragma unroll
      for (int nt = 0; nt < 2; ++nt)
        #pragma unroll
        for (int r = 0; r < 4; ++r) {
          float v = acc[ti][nt][r] + breg[ti][r];
          mx[ti][r] = fmaxf(mx[ti][r], v);
          mn[ti][r] = fminf(mn[ti][r], v);
          sm[ti][r] += v;
          sq[ti][r] = fmaf(v, v, sq[ti][r]);
        }
  }

  #pragma unroll
  for (int ti = 0; ti < 4; ++ti)
    #pragma unroll
    for (int r = 0; r < 4; ++r) {
      #pragma unroll
      for (int m = 1; m < 16; m <<= 1) {
        mx[ti][r] = fmaxf(mx[ti][r], __shfl_xor(mx[ti][r], m, 16));
        mn[ti][r] = fminf(mn[ti][r], __shfl_xor(mn[ti][r], m, 16));
        sm[ti][r] += __shfl_xor(sm[ti][r], m, 16);
        sq[ti][r] += __shfl_xor(sq[ti][r], m, 16);
      }
    }
  if (l15 == 0) {
    #pragma unroll
    for (int ti = 0; ti < 4; ++ti)
      #pragma unroll
      for (int r = 0; r < 4; ++r) {
        int oloc = ow * 64 + ti * 16 + quad * 4 + r;
        sred[nw][oloc][0] = mx[ti][r];
        sred[nw][oloc][1] = mn[ti][r];
        sred[nw][oloc][2] = sm[ti][r];
        sred[nw][oloc][3] = sq[ti][r];
      }
  }
  __syncthreads();
  if (t < 128) {
    int o = o0 + t;
    mxb[ns * 32768 + b * 1024 + o] = fmaxf(sred[0][t][0], sred[1][t][0]);
    mnb[ns * 32768 + b * 1024 + o] = fminf(sred[0][t][1], sred[1][t][1]);
    atomicAdd(&sum3[o], sred[0][t][2] + sred[1][t][2]);
    atomicAdd(&sq3[o],  sred[0][t][3] + sred[1][t][3]);
  }
}

// pooled[b,c] = a3*(a3>=0 ? max : min) + s3 over 4 ns-slots; BN3 inline.
__global__ __launch_bounds__(256) void k_pooled(const float* __restrict__ sum3,
    const float* __restrict__ sq3, const float* __restrict__ g3,
    const float* __restrict__ be3, const float* __restrict__ mxb,
    const float* __restrict__ mnb, float* __restrict__ pool)
{
  int idx4 = blockIdx.x * 256 + threadIdx.x;   // 8192 f4, grid 32
  int c4 = idx4 & 255;
  float4 S = ((const float4*)sum3)[c4];
  float4 Q = ((const float4*)sq3)[c4];
  float4 G = ((const float4*)g3)[c4];
  float4 Be = ((const float4*)be3)[c4];
  float4 a, s;
  const float inv = 1.f / 65536.f;
  #define MK(c) { float m = S.c * inv; float v = fmaf(-m, m, Q.c * inv); \
                  a.c = G.c * rsqrtf(v + EPSV); s.c = fmaf(-a.c, m, Be.c); }
  MK(x) MK(y) MK(z) MK(w)
  #undef MK
  float4 mx = ((const float4*)mxb)[idx4];
  float4 mn = ((const float4*)mnb)[idx4];
  #pragma unroll
  for (int sl = 1; sl < 4; ++sl) {
    float4 mxs = ((const float4*)mxb)[idx4 + sl * 8192];
    float4 mns = ((const float4*)mnb)[idx4 + sl * 8192];
    mx.x = fmaxf(mx.x, mxs.x); mx.y = fmaxf(mx.y, mxs.y);
    mx.z = fmaxf(mx.z, mxs.z); mx.w = fmaxf(mx.w, mxs.w);
    mn.x = fminf(mn.x, mns.x); mn.y = fminf(mn.y, mns.y);
    mn.z = fminf(mn.z, mns.z); mn.w = fminf(mn.w, mns.w);
  }
  float4 r;
  r.x = fmaf(a.x, (a.x >= 0.f ? mx.x : mn.x), s.x);
  r.y = fmaf(a.y, (a.y >= 0.f ? mx.y : mn.y), s.y);
  r.z = fmaf(a.z, (a.z >= 0.f ? mx.z : mn.z), s.z);
  r.w = fmaf(a.w, (a.w >= 0.f ? mx.w : mn.w), s.w);
  ((float4*)pool)[idx4] = r;
}

// FC1: f1r[b,f] += bias(kc==0) + sum_{k in chunk} wf1[f,k]*pool[b,k].
// grid (16 f-tiles of 32, 8 k-chunks of 128); fully unrolled K-chunk.
__global__ __launch_bounds__(256) void k_fc1(const float* __restrict__ pool,
    const float* __restrict__ wf1, const float* __restrict__ bf1,
    float* __restrict__ f1r)
{
  __shared__ float ins[32 * 128];   // 16 KB
  int t = threadIdx.x;
  int f0 = blockIdx.x * 32;
  int k0 = blockIdx.y * 128;
  #pragma unroll
  for (int i = 0; i < 4; ++i) {
    int idx = i * 256 + t;          // 1024 f4 = 32 b x 32 k4
    int b = idx >> 5, k4 = idx & 31;
    *(float4*)&ins[b * 128 + k4 * 4] = *(const float4*)(pool + (size_t)b * 1024 + k0 + k4 * 4);
  }
  __syncthreads();
  int f = t & 31, bq = t >> 5;      // 32 f x 8 b-quads
  int bl = bq * 4;
  const float4* wr = (const float4*)(wf1 + (size_t)(f0 + f) * 1024 + k0);
  float acc0 = 0.f, acc1 = 0.f, acc2 = 0.f, acc3 = 0.f;
  #pragma unroll
  for (int k4 = 0; k4 < 32; ++k4) {
    float4 wv = wr[k4];
    float4 i0 = *(const float4*)&ins[(bl + 0) * 128 + k4 * 4];
    float4 i1 = *(const float4*)&ins[(bl + 1) * 128 + k4 * 4];
    float4 i2 = *(const float4*)&ins[(bl + 2) * 128 + k4 * 4];
    float4 i3 = *(const float4*)&ins[(bl + 3) * 128 + k4 * 4];
    acc0 = fmaf(wv.x, i0.x, fmaf(wv.y, i0.y, fmaf(wv.z, i0.z, fmaf(wv.w, i0.w, acc0))));
    acc1 = fmaf(wv.x, i1.x, fmaf(wv.y, i1.y, fmaf(wv.z, i1.z, fmaf(wv.w, i1.w, acc1))));
    acc2 = fmaf(wv.x, i2.x, fmaf(wv.y, i2.y, fmaf(wv.z, i2.z, fmaf(wv.w, i2.w, acc2))));
    acc3 = fmaf(wv.x, i3.x, fmaf(wv.y, i3.y, fmaf(wv.z, i3.z, fmaf(wv.w, i3.w, acc3))));
  }
  float bs = (blockIdx.y == 0) ? bf1[f0 + f] : 0.f;
  atomicAdd(&f1r[(size_t)(bl + 0) * 512 + f0 + f], acc0 + bs);
  atomicAdd(&f1r[(size_t)(bl + 1) * 512 + f0 + f], acc1 + bs);
  atomicAdd(&f1r[(size_t)(bl + 2) * 512 + f0 + f], acc2 + bs);
  atomicAdd(&f1r[(size_t)(bl + 3) * 512 + f0 + f], acc3 + bs);
}

// FC2: BN1d stats over batch computed inline from f1r k-columns; then
// f2r[b,f] += bias(kc==0) + sum_k wf2[f,k]*relu(BN(f1r[b,k])).
// grid (8 f-tiles of 32, 8 k-chunks of 64).
__global__ __launch_bounds__(256) void k_fc2(const float* __restrict__ f1r,
    const float* __restrict__ wf2, const float* __restrict__ bf2,
    const float* __restrict__ gf1, const float* __restrict__ bef1,
    float* __restrict__ f2r)
{
  __shared__ float ins[32 * 64];    // 8 KB
  __shared__ float bnA[64], bnS[64];
  int t = threadIdx.x;
  int f0 = blockIdx.x * 32;
  int k0 = blockIdx.y * 64;
  #pragma unroll
  for (int i = 0; i < 2; ++i) {
    int idx = i * 256 + t;          // 512 f4 = 32 b x 16 k4
    int b = idx >> 4, k4 = idx & 15;
    *(float4*)&ins[b * 64 + k4 * 4] = *(const float4*)(f1r + (size_t)b * 512 + k0 + k4 * 4);
  }
  __syncthreads();
  if (t < 64) {
    float s = 0.f, q = 0.f;
    #pragma unroll
    for (int b = 0; b < 32; ++b) {
      float x = ins[b * 64 + t];
      s += x; q = fmaf(x, x, q);
    }
    float m = s * (1.f / 32.f);
    float v = fmaf(-m, m, q * (1.f / 32.f));
    float a = gf1[k0 + t] * rsqrtf(v + EPSV);
    bnA[t] = a; bnS[t] = fmaf(-a, m, bef1[k0 + t]);
  }
  __syncthreads();
  #pragma unroll
  for (int i = 0; i < 2; ++i) {
    int idx = i * 256 + t;
    int b = idx >> 4, k4 = idx & 15;
    float4 v = *(const float4*)&ins[b * 64 + k4 * 4];
    v.x = fmaxf(fmaf(bnA[k4*4+0], v.x, bnS[k4*4+0]), 0.f);
    v.y = fmaxf(fmaf(bnA[k4*4+1], v.y, bnS[k4*4+1]), 0.f);
    v.z = fmaxf(fmaf(bnA[k4*4+2], v.z, bnS[k4*4+2]), 0.f);
    v.w = fmaxf(fmaf(bnA[k4*4+3], v.w, bnS[k4*4+3]), 0.f);
    *(float4*)&ins[b * 64 + k4 * 4] = v;
  }
  __syncthreads();
  int f = t & 31, bq = t >> 5;
  int bl = bq * 4;
  const float4* wr = (const float4*)(wf2 + (size_t)(f0 + f) * 512 + k0);
  float acc0 = 0.f, acc1 = 0.f, acc2 = 0.f, acc3 = 0.f;
  #pragma unroll
  for (int k4 = 0; k4 < 16; ++k4) {
    float4 wv = wr[k4];
    float4 i0 = *(const float4*)&ins[(bl + 0) * 64 + k4 * 4];
    float4 i1 = *(const float4*)&ins[(bl + 1) * 64 + k4 * 4];
    float4 i2 = *(const float4*)&ins[(bl + 2) * 64 + k4 * 4];
    float4 i3 = *(const float4*)&ins[(bl + 3) * 64 + k4 * 4];
    acc0 = fmaf(wv.x, i0.x, fmaf(wv.y, i0.y, fmaf(wv.z, i0.z, fmaf(wv.w, i0.w, acc0))));
    acc1 = fmaf(wv.x, i1.x, fmaf(wv.y, i1.y, fmaf(wv.z, i1.z, fmaf(wv.w, i1.w, acc1))));
    acc2 = fmaf(wv.x, i2.x, fmaf(wv.y, i2.y, fmaf(wv.z, i2.z, fmaf(wv.w, i2.w, acc2))));
    acc3 = fmaf(wv.x, i3.x, fmaf(wv.y, i3.y, fmaf(wv.z, i3.z, fmaf(wv.w, i3.w, acc3))));
  }
  float bs = (blockIdx.y == 0) ? bf2[f0 + f] : 0.f;
  atomicAdd(&f2r[(size_t)(bl + 0) * 256 + f0 + f], acc0 + bs);
  atomicAdd(&f2r[(size_t)(bl + 1) * 256 + f0 + f], acc1 + bs);
  atomicAdd(&f2r[(size_t)(bl + 2) * 256 + f0 + f], acc2 + bs);
  atomicAdd(&f2r[(size_t)(bl + 3) * 256 + f0 + f], acc3 + bs);
}

// Head: BN-F2 stats inline; p = relu(BN(f2r)) @ wp.T + bp; Horn SO(3) -> [B,4,4].
__global__ __launch_bounds__(384) void k_head(const float* __restrict__ f2r,
    const float* __restrict__ gf2, const float* __restrict__ bef2,
    const float* __restrict__ wp, const float* __restrict__ bp,
    float* __restrict__ out)
{
  __shared__ float pS[32 * 12];
  __shared__ float bnf[256][2];
  int t = threadIdx.x;
  if (t < 256) {
    float s = 0.f, q = 0.f;
    #pragma unroll
    for (int b = 0; b < 32; ++b) {
      float x = f2r[b * 256 + t];
      s += x; q = fmaf(x, x, q);
    }
    float m = s * (1.f / 32.f);
    float v = fmaf(-m, m, q * (1.f / 32.f));
    float a = gf2[t] * rsqrtf(v + EPSV);
    bnf[t][0] = a; bnf[t][1] = fmaf(-a, m, bef2[t]);
  }
  __syncthreads();
  {
    int b = t / 12, j = t % 12;
    const float* w = wp + j * 256;
    const float* fr = f2r + b * 256;
    float acc = bp[j];
    #pragma unroll 8
    for (int c = 0; c < 256; ++c) {
      float h = fmaxf(fmaf(bnf[c][0], fr[c], bnf[c][1]), 0.f);
      acc = fmaf(w[c], h, acc);
    }
    pS[t] = acc;
  }
  __syncthreads();
  if (t < 32) {
    const float* p = &pS[t * 12];
    float m00=p[0],m01=p[1],m02=p[2],m10=p[3],m11=p[4],m12=p[5],m20=p[6],m21=p[7],m22=p[8];
    float P[4][4];
    P[0][0]=m00+m11+m22; P[0][1]=m21-m12;     P[0][2]=m02-m20;     P[0][3]=m10-m01;
    P[1][1]=m00-m11-m22; P[1][2]=m01+m10;     P[1][3]=m02+m20;
    P[2][2]=m11-m00-m22; P[2][3]=m12+m21;
    P[3][3]=m22-m00-m11;
    P[1][0]=P[0][1]; P[2][0]=P[0][2]; P[3][0]=P[0][3];
    P[2][1]=P[1][2]; P[3][1]=P[1][3]; P[3][2]=P[2][3];
    float fn = sqrtf(m00*m00+m01*m01+m02*m02+m10*m10+m11*m11+m12*m12+m20*m20+m21*m21+m22*m22);
    float inv = 1.f / (2.f * fn + 1e-30f);
    #pragma unroll
    for (int i = 0; i < 4; ++i)
      #pragma unroll
      for (int j = 0; j < 4; ++j) P[i][j] *= inv;
    P[0][0] += 1.f; P[1][1] += 1.f; P[2][2] += 1.f; P[3][3] += 1.f;
    for (int it = 0; it < 16; ++it) {
      float Q[4][4];
      #pragma unroll
      for (int i = 0; i < 4; ++i)
        #pragma unroll
        for (int j = 0; j < 4; ++j)
          Q[i][j] = P[i][0]*P[0][j] + P[i][1]*P[1][j] + P[i][2]*P[2][j] + P[i][3]*P[3][j];
      float mxa = 0.f;
      #pragma unroll
      for (int i = 0; i < 4; ++i)
        #pragma unroll
        for (int j = 0; j < 4; ++j) mxa = fmaxf(mxa, fabsf(Q[i][j]));
      float r = 1.f / mxa;
      #pragma unroll
      for (int i = 0; i < 4; ++i)
        #pragma unroll
        for (int j = 0; j < 4; ++j) P[i][j] = Q[i][j] * r;
    }
    float bestn = -1.f; int bj = 0;
    #pragma unroll
    for (int j = 0; j < 4; ++j) {
      float nn = P[0][j]*P[0][j] + P[1][j]*P[1][j] + P[2][j]*P[2][j] + P[3][j]*P[3][j];
      if (nn > bestn) { bestn = nn; bj = j; }
    }
    float qw = P[0][bj], qx = P[1][bj], qy = P[2][bj], qz = P[3][bj];
    float qn = rsqrtf(qw*qw + qx*qx + qy*qy + qz*qz);
    qw *= qn; qx *= qn; qy *= qn; qz *= qn;
    float* ob = out + t * 16;
    ob[0]  = 1.f - 2.f*(qy*qy + qz*qz);
    ob[1]  = 2.f*(qx*qy - qw*qz);
    ob[2]  = 2.f*(qx*qz + qw*qy);
    ob[3]  = p[9];
    ob[4]  = 2.f*(qx*qy + qw*qz);
    ob[5]  = 1.f - 2.f*(qx*qx + qz*qz);
    ob[6]  = 2.f*(qy*qz - qw*qx);
    ob[7]  = p[10];
    ob[8]  = 2.f*(qx*qz - qw*qy);
    ob[9]  = 2.f*(qy*qz + qw*qx);
    ob[10] = 1.f - 2.f*(qx*qx + qy*qy);
    ob[11] = p[11];
    ob[12] = 0.f; ob[13] = 0.f; ob[14] = 0.f; ob[15] = 1.f;
  }
}

extern "C" void kernel_launch(void* const* d_in, const int* in_sizes, int n_in,
                              void* d_out, int out_size, void* d_ws, size_t ws_size,
                              hipStream_t stream)
{
  (void)in_sizes; (void)n_in; (void)out_size;
  if (ws_size < (size_t)WS_FLOATS * sizeof(float)) return;
  const float* x   = (const float*)d_in[0];
  const float* w1  = (const float*)d_in[1];
  const float* b1  = (const float*)d_in[2];
  const float* g1  = (const float*)d_in[3];
  const float* be1 = (const float*)d_in[4];
  const float* w2  = (const float*)d_in[5];
  const float* b2  = (const float*)d_in[6];
  const float* g2  = (const float*)d_in[7];
  const float* be2 = (const float*)d_in[8];
  const float* w3  = (const float*)d_in[9];
  const float* b3  = (const float*)d_in[10];
  const float* g3  = (const float*)d_in[11];
  const float* be3 = (const float*)d_in[12];
  const float* wf1 = (const float*)d_in[13];
  const float* bf1 = (const float*)d_in[14];
  const float* gf1 = (const float*)d_in[15];
  const float* bef1= (const float*)d_in[16];
  const float* wf2 = (const float*)d_in[17];
  const float* bf2 = (const float*)d_in[18];
  const float* gf2 = (const float*)d_in[19];
  const float* bef2= (const float*)d_in[20];
  const float* wp  = (const float*)d_in[21];
  const float* bp  = (const float*)d_in[22];
  float* ws  = (float*)d_ws;
  float* out = (float*)d_out;
  unsigned short* y1h = (unsigned short*)(ws + OFF_Y1H);
  unsigned short* y2h = (unsigned short*)(ws + OFF_Y2H);
  unsigned short* w3h = (unsigned short*)(ws + OFF_W3H);
  unsigned short* w2h = (unsigned short*)(ws + OFF_W2H);

  hipMemsetAsync((void*)(ws + OFF_Z), 0, ZN * sizeof(float), stream);
  k_cvt<<<136, 256, 0, stream>>>(w3, w2, w3h, w2h);
  k_conv1<<<4096, 256, 0, stream>>>(x, w1, b1, y1h, ws + OFF_SUM1, ws + OFF_SQ1);
  k_conv2<<<1024, 256, 0, stream>>>(y1h, w2h, b2, ws + OFF_SUM1, ws + OFF_SQ1, g1, be1,
                                    y2h, ws + OFF_SUM2, ws + OFF_SQ2);
  k_conv3<<<1024, 256, 0, stream>>>(y2h, w3h, b3, ws + OFF_SUM2, ws + OFF_SQ2, g2, be2,
                                    ws + OFF_MX, ws + OFF_MN, ws + OFF_SUM3, ws + OFF_SQ3);
  k_pooled<<<32, 256, 0, stream>>>(ws + OFF_SUM3, ws + OFF_SQ3, g3, be3,
                                   ws + OFF_MX, ws + OFF_MN, ws + OFF_POOL);
  k_fc1<<<dim3(16, 8), 256, 0, stream>>>(ws + OFF_POOL, wf1, bf1, ws + OFF_F1R);
  k_fc2<<<dim3(8, 8), 256, 0, stream>>>(ws + OFF_F1R, wf2, bf2, gf1, bef1, ws + OFF_F2R);
  k_head<<<1, 384, 0, stream>>>(ws + OFF_F2R, gf2, bef2, wp, bp, out);
}

// Round 7
// 221.426 us; speedup vs baseline: 3.1494x; 1.1488x over previous
//
#include <hip/hip_runtime.h>

// PointNetRot9d. Round 7: r6 logic + FIXED workspace layout.
//  - r6 failed (absmax 2.53) because OFF_H2T was placed inside y2h's range:
//    y2h is 32*128*2048 halves = 4,194,304 FLOAT SLOTS (comment said 2M).
//    h2t/y2h/stats/weights all aliased. This round only corrects the map:
//      H1T [0, 2097152) | Y2H [2097152, 6291456) | H2T [6291456, 10485760)
//      stats/outputs/weights after; 43.0 MB total.
//  - Kernel logic unchanged from r6: closed-form BN1 from x moments; h1/h2
//    stored fp16 post-BN-relu TRANSPOSED [b][n][c] so conv2/conv3 staging is
//    pure uint4 copies into SW-swizzled LDS; fc1/fc2 unroll capped at 4.

#define NPT 2048
#define C1 64
#define C2 128
#define EPSV 1e-5f

typedef __attribute__((ext_vector_type(8))) _Float16 half8;
typedef __attribute__((ext_vector_type(4))) float floatx4;

// ---- workspace layout (float-slot offsets) ----
#define OFF_H1T   0               // 32*2048*64 halves  = 2097152 slots
#define OFF_Y2H   2097152         // 32*128*2048 halves = 4194304 slots
#define OFF_H2T   6291456         // 32*2048*128 halves = 4194304 slots
#define OFF_Z     10485760        // zeroed region start
#define OFF_XS    (OFF_Z)         // 16: Sx[3], Sxx diag[3], Sxx off[3]
#define OFF_SUM2  (OFF_Z+16)
#define OFF_SQ2   (OFF_Z+144)
#define OFF_SUM3  (OFF_Z+272)
#define OFF_SQ3   (OFF_Z+1296)
#define OFF_F1R   (OFF_Z+2320)    // 32*512
#define OFF_F2R   (OFF_Z+18704)   // 32*256
#define ZN        26896
#define OFF_MX    (OFF_Z+26896)   // 2 ns-slots * 32*1024
#define OFF_MN    (OFF_MX+65536)
#define OFF_POOL  (OFF_MN+65536)  // 32768
#define OFF_W3H   (OFF_POOL+32768)// 131072 halves = 65536 slots
#define OFF_W2H   (OFF_W3H+65536) // 8192 halves = 4096 slots
#define WS_FLOATS (OFF_W2H+4096)  // 10,746,128 floats = 43.0 MB

static __device__ inline unsigned short f16r(float f) {
  _Float16 h = (_Float16)f;
  return __builtin_bit_cast(unsigned short, h);
}
static __device__ inline float h2f(unsigned short u) {
  return (float)__builtin_bit_cast(_Float16, u);
}
// LDS staging swizzle (bijection on n per cb): conflict-free b128 write+read.
static __device__ inline int SW(int n, int cb) { return n ^ (((n >> 3) ^ cb) & 7); }

// x moments: Sx[d], Sxx[d,d'] over all (b,n). 9 atomics/block.
__global__ __launch_bounds__(256) void k_xstat(const float* __restrict__ x,
                                               float* __restrict__ xs)
{
  int idx4 = blockIdx.x * 256 + threadIdx.x;   // 16384 f4 = [32 b][512 n4]
  int n4 = idx4 & 511, b = idx4 >> 9;
  const float4* xr = (const float4*)(x + (size_t)b * 3 * NPT);
  float4 x0 = xr[n4], x1 = xr[512 + n4], x2 = xr[1024 + n4];
  float v[9];
  v[0] = x0.x + x0.y + x0.z + x0.w;
  v[1] = x1.x + x1.y + x1.z + x1.w;
  v[2] = x2.x + x2.y + x2.z + x2.w;
  v[3] = x0.x*x0.x + x0.y*x0.y + x0.z*x0.z + x0.w*x0.w;
  v[4] = x1.x*x1.x + x1.y*x1.y + x1.z*x1.z + x1.w*x1.w;
  v[5] = x2.x*x2.x + x2.y*x2.y + x2.z*x2.z + x2.w*x2.w;
  v[6] = x0.x*x1.x + x0.y*x1.y + x0.z*x1.z + x0.w*x1.w;
  v[7] = x0.x*x2.x + x0.y*x2.y + x0.z*x2.z + x0.w*x2.w;
  v[8] = x1.x*x2.x + x1.y*x2.y + x1.z*x2.z + x1.w*x2.w;
  #pragma unroll
  for (int k = 0; k < 9; ++k)
    for (int off = 32; off; off >>= 1) v[k] += __shfl_down(v[k], off);
  __shared__ float red[4][9];
  int lane = threadIdx.x & 63, wv = threadIdx.x >> 6;
  if (!lane)
    #pragma unroll
    for (int k = 0; k < 9; ++k) red[wv][k] = v[k];
  __syncthreads();
  if (threadIdx.x < 9)
    atomicAdd(&xs[threadIdx.x], red[0][threadIdx.x] + red[1][threadIdx.x] +
                                red[2][threadIdx.x] + red[3][threadIdx.x]);
}

// One-time cvt: w3 [1024][128] and w2 [128][64] f32 -> fp16.
__global__ __launch_bounds__(256) void k_cvt(const float* __restrict__ w3,
    const float* __restrict__ w2, unsigned short* __restrict__ w3h,
    unsigned short* __restrict__ w2h)
{
  int idx4 = blockIdx.x * 256 + threadIdx.x;   // 34816 f4, grid 136
  const float4* src; ushort4* dst; int k;
  if (idx4 < 32768) { src = (const float4*)w3; dst = (ushort4*)w3h; k = idx4; }
  else               { src = (const float4*)w2; dst = (ushort4*)w2h; k = idx4 - 32768; }
  float4 v = src[k];
  ushort4 o;
  o.x = f16r(v.x); o.y = f16r(v.y); o.z = f16r(v.z); o.w = f16r(v.w);
  dst[k] = o;
}

// conv1 + BN1(closed form from xs) + relu -> h1t[b][n][64c] fp16.
__global__ __launch_bounds__(256) void k_conv1(const float* __restrict__ x,
    const float* __restrict__ w1, const float* __restrict__ b1,
    const float* __restrict__ g1, const float* __restrict__ be1,
    const float* __restrict__ xs, unsigned short* __restrict__ h1t)
{
  __shared__ float wc[64][4];
  int t = threadIdx.x;
  int bi = blockIdx.x;            // 256 = 32 b x 8 nt
  int b = bi >> 3, nt = bi & 7;
  if (t < 64) {
    float w0 = w1[t*3], w1_ = w1[t*3+1], w2_ = w1[t*3+2], bb = b1[t];
    const float invN = 1.f / 65536.f;
    float wsx = (w0*xs[0] + w1_*xs[1] + w2_*xs[2]) * invN;   // E[w.x]
    float mean = wsx + bb;
    float Ey2 = (w0*w0*xs[3] + w1_*w1_*xs[4] + w2_*w2_*xs[5]
               + 2.f*(w0*w1_*xs[6] + w0*w2_*xs[7] + w1_*w2_*xs[8])) * invN
               + 2.f*bb*wsx + bb*bb;
    float var = Ey2 - mean*mean;
    float a = g1[t] * rsqrtf(var + EPSV);
    wc[t][0] = a*w0; wc[t][1] = a*w1_; wc[t][2] = a*w2_;
    wc[t][3] = be1[t] + a*(bb - mean);
  }
  __syncthreads();
  int n = nt * 256 + t;
  const float* xb = x + (size_t)b * 3 * NPT + n;
  float x0 = xb[0], x1 = xb[NPT], x2 = xb[2*NPT];
  unsigned short* orow = h1t + ((size_t)b * NPT + n) * C1;
  #pragma unroll
  for (int i = 0; i < 8; ++i) {
    uint4 pk;
    unsigned* pd = (unsigned*)&pk;
    #pragma unroll
    for (int j = 0; j < 4; ++j) {
      int o = i*8 + j*2;
      float h0 = fmaxf(fmaf(wc[o][0], x0, fmaf(wc[o][1], x1, fmaf(wc[o][2], x2, wc[o][3]))), 0.f);
      float h1 = fmaxf(fmaf(wc[o+1][0], x0, fmaf(wc[o+1][1], x1, fmaf(wc[o+1][2], x2, wc[o+1][3]))), 0.f);
      pd[j] = (unsigned)f16r(h0) | ((unsigned)f16r(h1) << 16);
    }
    *(uint4*)(orow + i * 8) = pk;
  }
}

// conv2 MFMA: block = (b, 64-n slice) x all 128 o. Staging = pure copies.
__global__ __launch_bounds__(256, 2) void k_conv2(const unsigned short* __restrict__ h1t,
    const unsigned short* __restrict__ w2h, const float* __restrict__ b2,
    unsigned short* __restrict__ y2h, float* __restrict__ sum2, float* __restrict__ sq2)
{
  __shared__ unsigned short w2s[8 * 128 * 8];   // 16 KB
  __shared__ unsigned short h1s[8 * 64 * 8];    // 8 KB
  __shared__ float sred[2][128][2];
  int t = threadIdx.x;
  int bi = blockIdx.x;                 // 1024 = 32 b x 32 ns
  int b = bi >> 5, ns = bi & 31;
  int n0 = ns * 64;
  int w = t >> 6, lane = t & 63;
  int ow = w & 1, nw = w >> 1;
  int quad = lane >> 4, l15 = lane & 15;

  // stage w2: [cb][o'][8], o' = (o+cb)&127
  for (int i = 0; i < 4; ++i) {
    int idx = i * 256 + t;             // 1024 = 128 o x 8 cb
    int o = idx >> 3, cb = idx & 7;
    uint4 v = *(const uint4*)(w2h + o * 64 + cb * 8);
    int op = (o + cb) & 127;
    *(uint4*)&w2s[(cb * 128 + op) * 8] = v;
  }
  // stage h1: pure copy from h1t[b][n][c], [cb][n'][8] with n' = SW(n,cb)
  {
    int n = t & 63, cp = t >> 6;       // cb pair {2cp, 2cp+1}
    const unsigned short* src = h1t + ((size_t)b * NPT + n0 + n) * C1 + cp * 16;
    uint4 v0 = *(const uint4*)(src);
    uint4 v1 = *(const uint4*)(src + 8);
    *(uint4*)&h1s[((2*cp)   * 64 + SW(n, 2*cp))   * 8] = v0;
    *(uint4*)&h1s[((2*cp+1) * 64 + SW(n, 2*cp+1)) * 8] = v1;
  }
  __syncthreads();

  half8 af[4][2];
  #pragma unroll
  for (int ti = 0; ti < 4; ++ti)
    #pragma unroll
    for (int s = 0; s < 2; ++s) {
      int cb = s * 4 + quad;
      int o = ow * 64 + ti * 16 + l15;
      int op = (o + cb) & 127;
      af[ti][s] = *(const half8*)&w2s[(cb * 128 + op) * 8];
    }
  float breg[4][4];
  #pragma unroll
  for (int ti = 0; ti < 4; ++ti)
    #pragma unroll
    for (int r = 0; r < 4; ++r)
      breg[ti][r] = b2[ow * 64 + ti * 16 + quad * 4 + r];

  floatx4 acc[4][2];
  #pragma unroll
  for (int ti = 0; ti < 4; ++ti)
    #pragma unroll
    for (int nt = 0; nt < 2; ++nt) acc[ti][nt] = (floatx4){0.f, 0.f, 0.f, 0.f};
  #pragma unroll
  for (int s = 0; s < 2; ++s) {
    int cb = s * 4 + quad;
    half8 bf[2];
    #pragma unroll
    for (int nt = 0; nt < 2; ++nt) {
      int n = nw * 32 + nt * 16 + l15;
      bf[nt] = *(const half8*)&h1s[(cb * 64 + SW(n, cb)) * 8];
    }
    #pragma unroll
    for (int ti = 0; ti < 4; ++ti) {
      acc[ti][0] = __builtin_amdgcn_mfma_f32_16x16x32_f16(af[ti][s], bf[0], acc[ti][0], 0, 0, 0);
      acc[ti][1] = __builtin_amdgcn_mfma_f32_16x16x32_f16(af[ti][s], bf[1], acc[ti][1], 0, 0, 0);
    }
  }

  // epilogue: y2h = fp16(acc + b2); exact fp32 BN2 stats
  float sm[4][4], sq[4][4];
  #pragma unroll
  for (int ti = 0; ti < 4; ++ti)
    #pragma unroll
    for (int r = 0; r < 4; ++r) { sm[ti][r] = 0.f; sq[ti][r] = 0.f; }
  #pragma unroll
  for (int ti = 0; ti < 4; ++ti) {
    int o = ow * 64 + ti * 16 + quad * 4;
    #pragma unroll
    for (int nt = 0; nt < 2; ++nt) {
      int n = n0 + nw * 32 + nt * 16 + l15;
      #pragma unroll
      for (int r = 0; r < 4; ++r) {
        float val = acc[ti][nt][r] + breg[ti][r];
        y2h[(size_t)(b * C2 + o + r) * NPT + n] = f16r(val);
        sm[ti][r] += val;
        sq[ti][r] = fmaf(val, val, sq[ti][r]);
      }
    }
  }
  #pragma unroll
  for (int ti = 0; ti < 4; ++ti)
    #pragma unroll
    for (int r = 0; r < 4; ++r) {
      #pragma unroll
      for (int m = 1; m < 16; m <<= 1) {
        sm[ti][r] += __shfl_xor(sm[ti][r], m, 16);
        sq[ti][r] += __shfl_xor(sq[ti][r], m, 16);
      }
    }
  if (l15 == 0) {
    #pragma unroll
    for (int ti = 0; ti < 4; ++ti)
      #pragma unroll
      for (int r = 0; r < 4; ++r) {
        int oloc = ow * 64 + ti * 16 + quad * 4 + r;
        sred[nw][oloc][0] = sm[ti][r];
        sred[nw][oloc][1] = sq[ti][r];
      }
  }
  __syncthreads();
  if (t < 128) {
    atomicAdd(&sum2[t], sred[0][t][0] + sred[1][t][0]);
    atomicAdd(&sq2[t],  sred[0][t][1] + sred[1][t][1]);
  }
}

// BN2+relu+transpose: y2h[b][c][n] -> h2t[b][n][128c] fp16 (fp32 BN math).
__global__ __launch_bounds__(256) void k_bnrelu2(const unsigned short* __restrict__ y2h,
    const float* __restrict__ sum2, const float* __restrict__ sq2,
    const float* __restrict__ g2, const float* __restrict__ be2,
    unsigned short* __restrict__ h2t)
{
  __shared__ float bn[128][2];
  int t = threadIdx.x;
  int bi = blockIdx.x;              // 1024 = 32 b x 32 nt (64-n tiles)
  int b = bi >> 5, nt = bi & 31;
  int n0 = nt * 64;
  if (t < 128) {
    float m = sum2[t] * (1.f / 65536.f);
    float v = fmaf(-m, m, sq2[t] * (1.f / 65536.f));
    float a = g2[t] * rsqrtf(v + EPSV);
    bn[t][0] = a; bn[t][1] = fmaf(-a, m, be2[t]);
  }
  __syncthreads();
  int coct = t & 15, ng = t >> 4;   // 8 c x 4 n per thread
  int c0 = coct * 8, n = n0 + ng * 4;
  float h[8][4];
  #pragma unroll
  for (int i = 0; i < 8; ++i) {
    ushort4 u = *(const ushort4*)(y2h + (size_t)(b * C2 + c0 + i) * NPT + n);
    float a = bn[c0 + i][0], s = bn[c0 + i][1];
    h[i][0] = fmaxf(fmaf(a, h2f(u.x), s), 0.f);
    h[i][1] = fmaxf(fmaf(a, h2f(u.y), s), 0.f);
    h[i][2] = fmaxf(fmaf(a, h2f(u.z), s), 0.f);
    h[i][3] = fmaxf(fmaf(a, h2f(u.w), s), 0.f);
  }
  #pragma unroll
  for (int j = 0; j < 4; ++j) {
    uint4 pk;
    pk.x = (unsigned)f16r(h[0][j]) | ((unsigned)f16r(h[1][j]) << 16);
    pk.y = (unsigned)f16r(h[2][j]) | ((unsigned)f16r(h[3][j]) << 16);
    pk.z = (unsigned)f16r(h[4][j]) | ((unsigned)f16r(h[5][j]) << 16);
    pk.w = (unsigned)f16r(h[6][j]) | ((unsigned)f16r(h[7][j]) << 16);
    *(uint4*)(h2t + ((size_t)b * NPT + n + j) * C2 + c0) = pk;
  }
}

// conv3 MFMA: block = (ot, b, n-half); 16 chunks of 64 n; staging = pure copy.
__global__ __launch_bounds__(256, 2) void k_conv3(const unsigned short* __restrict__ h2t,
    const unsigned short* __restrict__ w3h, const float* __restrict__ b3,
    float* __restrict__ mxb, float* __restrict__ mnb,
    float* __restrict__ sum3, float* __restrict__ sq3)
{
  __shared__ unsigned short w3s[16 * 128 * 8];  // 32 KB
  __shared__ unsigned short h2s[16 * 64 * 8];   // 16 KB
  __shared__ float sred[2][128][4];             // 4 KB
  int t = threadIdx.x;
  int bi = blockIdx.x;                 // 512: bi = ot*64 + b*2 + ns
  int ot_blk = bi >> 6;
  int b  = (bi >> 1) & 31;
  int ns = bi & 1;
  int o0 = ot_blk * 128;
  int n_base = ns * 1024;
  int w = t >> 6, lane = t & 63;
  int ow = w & 1, nw = w >> 1;
  int quad = lane >> 4, l15 = lane & 15;

  // stage w3 o-tile: [cb][o'][8], o' = (o+cb)&127
  for (int i = 0; i < 8; ++i) {
    int idx = i * 256 + t;             // 2048 = 128 o x 16 cb
    int o = idx >> 4, cb = idx & 15;
    uint4 v = *(const uint4*)(w3h + (size_t)(o0 + o) * 128 + cb * 8);
    int op = (o + cb) & 127;
    *(uint4*)&w3s[(cb * 128 + op) * 8] = v;
  }
  __syncthreads();

  half8 af[4][4];
  #pragma unroll
  for (int ti = 0; ti < 4; ++ti)
    #pragma unroll
    for (int s = 0; s < 4; ++s) {
      int cb = s * 4 + quad;
      int o = ow * 64 + ti * 16 + l15;
      int op = (o + cb) & 127;
      af[ti][s] = *(const half8*)&w3s[(cb * 128 + op) * 8];
    }

  float breg[4][4], mx[4][4], mn[4][4], sm[4][4], sq[4][4];
  #pragma unroll
  for (int ti = 0; ti < 4; ++ti)
    #pragma unroll
    for (int r = 0; r < 4; ++r) {
      breg[ti][r] = b3[o0 + ow * 64 + ti * 16 + quad * 4 + r];
      mx[ti][r] = -3.4e38f; mn[ti][r] = 3.4e38f; sm[ti][r] = 0.f; sq[ti][r] = 0.f;
    }

  int sn = t & 63, cq = t >> 6;        // staging map: 64 n x 4 cb-quads
  for (int nc = 0; nc < 16; ++nc) {
    int n0 = n_base + nc * 64;
    __syncthreads();
    // stage h2: 4 contiguous uint4 per thread -> swizzled LDS
    {
      const unsigned short* src = h2t + ((size_t)b * NPT + n0 + sn) * C2 + cq * 32;
      uint4 v0 = *(const uint4*)(src);
      uint4 v1 = *(const uint4*)(src + 8);
      uint4 v2 = *(const uint4*)(src + 16);
      uint4 v3 = *(const uint4*)(src + 24);
      int cb0 = cq * 4;
      *(uint4*)&h2s[((cb0 + 0) * 64 + SW(sn, cb0 + 0)) * 8] = v0;
      *(uint4*)&h2s[((cb0 + 1) * 64 + SW(sn, cb0 + 1)) * 8] = v1;
      *(uint4*)&h2s[((cb0 + 2) * 64 + SW(sn, cb0 + 2)) * 8] = v2;
      *(uint4*)&h2s[((cb0 + 3) * 64 + SW(sn, cb0 + 3)) * 8] = v3;
    }
    __syncthreads();

    floatx4 acc[4][2];
    #pragma unroll
    for (int ti = 0; ti < 4; ++ti)
      #pragma unroll
      for (int nt = 0; nt < 2; ++nt) acc[ti][nt] = (floatx4){0.f, 0.f, 0.f, 0.f};
    #pragma unroll
    for (int s = 0; s < 4; ++s) {
      int cb = s * 4 + quad;
      half8 bf[2];
      #pragma unroll
      for (int nt = 0; nt < 2; ++nt) {
        int n = nw * 32 + nt * 16 + l15;
        bf[nt] = *(const half8*)&h2s[(cb * 64 + SW(n, cb)) * 8];
      }
      #pragma unroll
      for (int ti = 0; ti < 4; ++ti) {
        acc[ti][0] = __builtin_amdgcn_mfma_f32_16x16x32_f16(af[ti][s], bf[0], acc[ti][0], 0, 0, 0);
        acc[ti][1] = __builtin_amdgcn_mfma_f32_16x16x32_f16(af[ti][s], bf[1], acc[ti][1], 0, 0, 0);
      }
    }
    #pragma unroll
    for (int ti = 0; ti < 4; ++ti)
      #pragma unroll
      for (int nt = 0; nt < 2; ++nt)
        #pragma unroll
        for (int r = 0; r < 4; ++r) {
          float v = acc[ti][nt][r] + breg[ti][r];
          mx[ti][r] = fmaxf(mx[ti][r], v);
          mn[ti][r] = fminf(mn[ti][r], v);
          sm[ti][r] += v;
          sq[ti][r] = fmaf(v, v, sq[ti][r]);
        }
  }

  #pragma unroll
  for (int ti = 0; ti < 4; ++ti)
    #pragma unroll
    for (int r = 0; r < 4; ++r) {
      #pragma unroll
      for (int m = 1; m < 16; m <<= 1) {
        mx[ti][r] = fmaxf(mx[ti][r], __shfl_xor(mx[ti][r], m, 16));
        mn[ti][r] = fminf(mn[ti][r], __shfl_xor(mn[ti][r], m, 16));
        sm[ti][r] += __shfl_xor(sm[ti][r], m, 16);
        sq[ti][r] += __shfl_xor(sq[ti][r], m, 16);
      }
    }
  if (l15 == 0) {
    #pragma unroll
    for (int ti = 0; ti < 4; ++ti)
      #pragma unroll
      for (int r = 0; r < 4; ++r) {
        int oloc = ow * 64 + ti * 16 + quad * 4 + r;
        sred[nw][oloc][0] = mx[ti][r];
        sred[nw][oloc][1] = mn[ti][r];
        sred[nw][oloc][2] = sm[ti][r];
        sred[nw][oloc][3] = sq[ti][r];
      }
  }
  __syncthreads();
  if (t < 128) {
    int o = o0 + t;
    mxb[ns * 32768 + b * 1024 + o] = fmaxf(sred[0][t][0], sred[1][t][0]);
    mnb[ns * 32768 + b * 1024 + o] = fminf(sred[0][t][1], sred[1][t][1]);
    atomicAdd(&sum3[o], sred[0][t][2] + sred[1][t][2]);
    atomicAdd(&sq3[o],  sred[0][t][3] + sred[1][t][3]);
  }
}

// pooled[b,c] = a3*(a3>=0 ? max : min) + s3 over 2 ns-slots; BN3 inline.
__global__ __launch_bounds__(256) void k_pooled(const float* __restrict__ sum3,
    const float* __restrict__ sq3, const float* __restrict__ g3,
    const float* __restrict__ be3, const float* __restrict__ mxb,
    const float* __restrict__ mnb, float* __restrict__ pool)
{
  int idx4 = blockIdx.x * 256 + threadIdx.x;   // 8192 f4, grid 32
  int c4 = idx4 & 255;
  float4 S = ((const float4*)sum3)[c4];
  float4 Q = ((const float4*)sq3)[c4];
  float4 G = ((const float4*)g3)[c4];
  float4 Be = ((const float4*)be3)[c4];
  float4 a, s;
  const float inv = 1.f / 65536.f;
  #define MK(c) { float m = S.c * inv; float v = fmaf(-m, m, Q.c * inv); \
                  a.c = G.c * rsqrtf(v + EPSV); s.c = fmaf(-a.c, m, Be.c); }
  MK(x) MK(y) MK(z) MK(w)
  #undef MK
  float4 mx = ((const float4*)mxb)[idx4];
  float4 mn = ((const float4*)mnb)[idx4];
  {
    float4 mxs = ((const float4*)mxb)[idx4 + 8192];
    float4 mns = ((const float4*)mnb)[idx4 + 8192];
    mx.x = fmaxf(mx.x, mxs.x); mx.y = fmaxf(mx.y, mxs.y);
    mx.z = fmaxf(mx.z, mxs.z); mx.w = fmaxf(mx.w, mxs.w);
    mn.x = fminf(mn.x, mns.x); mn.y = fminf(mn.y, mns.y);
    mn.z = fminf(mn.z, mns.z); mn.w = fminf(mn.w, mns.w);
  }
  float4 r;
  r.x = fmaf(a.x, (a.x >= 0.f ? mx.x : mn.x), s.x);
  r.y = fmaf(a.y, (a.y >= 0.f ? mx.y : mn.y), s.y);
  r.z = fmaf(a.z, (a.z >= 0.f ? mx.z : mn.z), s.z);
  r.w = fmaf(a.w, (a.w >= 0.f ? mx.w : mn.w), s.w);
  ((float4*)pool)[idx4] = r;
}

// FC1: f1r[b,f] += bias(kc0) + chunk dot. unroll capped at 4 (r5: 256 VGPR spill).
__global__ __launch_bounds__(256) void k_fc1(const float* __restrict__ pool,
    const float* __restrict__ wf1, const float* __restrict__ bf1,
    float* __restrict__ f1r)
{
  __shared__ float ins[32 * 128];   // 16 KB
  int t = threadIdx.x;
  int f0 = blockIdx.x * 32;
  int k0 = blockIdx.y * 128;
  #pragma unroll
  for (int i = 0; i < 4; ++i) {
    int idx = i * 256 + t;
    int b = idx >> 5, k4 = idx & 31;
    *(float4*)&ins[b * 128 + k4 * 4] = *(const float4*)(pool + (size_t)b * 1024 + k0 + k4 * 4);
  }
  __syncthreads();
  int f = t & 31, bq = t >> 5;
  int bl = bq * 4;
  const float4* wr = (const float4*)(wf1 + (size_t)(f0 + f) * 1024 + k0);
  float acc0 = 0.f, acc1 = 0.f, acc2 = 0.f, acc3 = 0.f;
  #pragma unroll 4
  for (int k4 = 0; k4 < 32; ++k4) {
    float4 wv = wr[k4];
    float4 i0 = *(const float4*)&ins[(bl + 0) * 128 + k4 * 4];
    float4 i1 = *(const float4*)&ins[(bl + 1) * 128 + k4 * 4];
    float4 i2 = *(const float4*)&ins[(bl + 2) * 128 + k4 * 4];
    float4 i3 = *(const float4*)&ins[(bl + 3) * 128 + k4 * 4];
    acc0 = fmaf(wv.x, i0.x, fmaf(wv.y, i0.y, fmaf(wv.z, i0.z, fmaf(wv.w, i0.w, acc0))));
    acc1 = fmaf(wv.x, i1.x, fmaf(wv.y, i1.y, fmaf(wv.z, i1.z, fmaf(wv.w, i1.w, acc1))));
    acc2 = fmaf(wv.x, i2.x, fmaf(wv.y, i2.y, fmaf(wv.z, i2.z, fmaf(wv.w, i2.w, acc2))));
    acc3 = fmaf(wv.x, i3.x, fmaf(wv.y, i3.y, fmaf(wv.z, i3.z, fmaf(wv.w, i3.w, acc3))));
  }
  float bs = (blockIdx.y == 0) ? bf1[f0 + f] : 0.f;
  atomicAdd(&f1r[(size_t)(bl + 0) * 512 + f0 + f], acc0 + bs);
  atomicAdd(&f1r[(size_t)(bl + 1) * 512 + f0 + f], acc1 + bs);
  atomicAdd(&f1r[(size_t)(bl + 2) * 512 + f0 + f], acc2 + bs);
  atomicAdd(&f1r[(size_t)(bl + 3) * 512 + f0 + f], acc3 + bs);
}

// FC2: BN1d(f1) stats inline per k-chunk; unroll capped at 4.
__global__ __launch_bounds__(256) void k_fc2(const float* __restrict__ f1r,
    const float* __restrict__ wf2, const float* __restrict__ bf2,
    const float* __restrict__ gf1, const float* __restrict__ bef1,
    float* __restrict__ f2r)
{
  __shared__ float ins[32 * 64];    // 8 KB
  __shared__ float bnA[64], bnS[64];
  int t = threadIdx.x;
  int f0 = blockIdx.x * 32;
  int k0 = blockIdx.y * 64;
  #pragma unroll
  for (int i = 0; i < 2; ++i) {
    int idx = i * 256 + t;
    int b = idx >> 4, k4 = idx & 15;
    *(float4*)&ins[b * 64 + k4 * 4] = *(const float4*)(f1r + (size_t)b * 512 + k0 + k4 * 4);
  }
  __syncthreads();
  if (t < 64) {
    float s = 0.f, q = 0.f;
    #pragma unroll
    for (int b = 0; b < 32; ++b) {
      float x = ins[b * 64 + t];
      s += x; q = fmaf(x, x, q);
    }
    float m = s * (1.f / 32.f);
    float v = fmaf(-m, m, q * (1.f / 32.f));
    float a = gf1[k0 + t] * rsqrtf(v + EPSV);
    bnA[t] = a; bnS[t] = fmaf(-a, m, bef1[k0 + t]);
  }
  __syncthreads();
  #pragma unroll
  for (int i = 0; i < 2; ++i) {
    int idx = i * 256 + t;
    int b = idx >> 4, k4 = idx & 15;
    float4 v = *(const float4*)&ins[b * 64 + k4 * 4];
    v.x = fmaxf(fmaf(bnA[k4*4+0], v.x, bnS[k4*4+0]), 0.f);
    v.y = fmaxf(fmaf(bnA[k4*4+1], v.y, bnS[k4*4+1]), 0.f);
    v.z = fmaxf(fmaf(bnA[k4*4+2], v.z, bnS[k4*4+2]), 0.f);
    v.w = fmaxf(fmaf(bnA[k4*4+3], v.w, bnS[k4*4+3]), 0.f);
    *(float4*)&ins[b * 64 + k4 * 4] = v;
  }
  __syncthreads();
  int f = t & 31, bq = t >> 5;
  int bl = bq * 4;
  const float4* wr = (const float4*)(wf2 + (size_t)(f0 + f) * 512 + k0);
  float acc0 = 0.f, acc1 = 0.f, acc2 = 0.f, acc3 = 0.f;
  #pragma unroll 4
  for (int k4 = 0; k4 < 16; ++k4) {
    float4 wv = wr[k4];
    float4 i0 = *(const float4*)&ins[(bl + 0) * 64 + k4 * 4];
    float4 i1 = *(const float4*)&ins[(bl + 1) * 64 + k4 * 4];
    float4 i2 = *(const float4*)&ins[(bl + 2) * 64 + k4 * 4];
    float4 i3 = *(const float4*)&ins[(bl + 3) * 64 + k4 * 4];
    acc0 = fmaf(wv.x, i0.x, fmaf(wv.y, i0.y, fmaf(wv.z, i0.z, fmaf(wv.w, i0.w, acc0))));
    acc1 = fmaf(wv.x, i1.x, fmaf(wv.y, i1.y, fmaf(wv.z, i1.z, fmaf(wv.w, i1.w, acc1))));
    acc2 = fmaf(wv.x, i2.x, fmaf(wv.y, i2.y, fmaf(wv.z, i2.z, fmaf(wv.w, i2.w, acc2))));
    acc3 = fmaf(wv.x, i3.x, fmaf(wv.y, i3.y, fmaf(wv.w, i3.w, fmaf(wv.z, i3.z, acc3))));
  }
  float bs = (blockIdx.y == 0) ? bf2[f0 + f] : 0.f;
  atomicAdd(&f2r[(size_t)(bl + 0) * 256 + f0 + f], acc0 + bs);
  atomicAdd(&f2r[(size_t)(bl + 1) * 256 + f0 + f], acc1 + bs);
  atomicAdd(&f2r[(size_t)(bl + 2) * 256 + f0 + f], acc2 + bs);
  atomicAdd(&f2r[(size_t)(bl + 3) * 256 + f0 + f], acc3 + bs);
}

// Head: BN-F2 stats inline; p = relu(BN(f2r)) @ wp.T + bp; Horn SO(3) -> [B,4,4].
__global__ __launch_bounds__(384) void k_head(const float* __restrict__ f2r,
    const float* __restrict__ gf2, const float* __restrict__ bef2,
    const float* __restrict__ wp, const float* __restrict__ bp,
    float* __restrict__ out)
{
  __shared__ float pS[32 * 12];
  __shared__ float bnf[256][2];
  int t = threadIdx.x;
  if (t < 256) {
    float s = 0.f, q = 0.f;
    #pragma unroll
    for (int b = 0; b < 32; ++b) {
      float x = f2r[b * 256 + t];
      s += x; q = fmaf(x, x, q);
    }
    float m = s * (1.f / 32.f);
    float v = fmaf(-m, m, q * (1.f / 32.f));
    float a = gf2[t] * rsqrtf(v + EPSV);
    bnf[t][0] = a; bnf[t][1] = fmaf(-a, m, bef2[t]);
  }
  __syncthreads();
  {
    int b = t / 12, j = t % 12;
    const float* w = wp + j * 256;
    const float* fr = f2r + b * 256;
    float acc = bp[j];
    #pragma unroll 8
    for (int c = 0; c < 256; ++c) {
      float h = fmaxf(fmaf(bnf[c][0], fr[c], bnf[c][1]), 0.f);
      acc = fmaf(w[c], h, acc);
    }
    pS[t] = acc;
  }
  __syncthreads();
  if (t < 32) {
    const float* p = &pS[t * 12];
    float m00=p[0],m01=p[1],m02=p[2],m10=p[3],m11=p[4],m12=p[5],m20=p[6],m21=p[7],m22=p[8];
    float P[4][4];
    P[0][0]=m00+m11+m22; P[0][1]=m21-m12;     P[0][2]=m02-m20;     P[0][3]=m10-m01;
    P[1][1]=m00-m11-m22; P[1][2]=m01+m10;     P[1][3]=m02+m20;
    P[2][2]=m11-m00-m22; P[2][3]=m12+m21;
    P[3][3]=m22-m00-m11;
    P[1][0]=P[0][1]; P[2][0]=P[0][2]; P[3][0]=P[0][3];
    P[2][1]=P[1][2]; P[3][1]=P[1][3]; P[3][2]=P[2][3];
    float fn = sqrtf(m00*m00+m01*m01+m02*m02+m10*m10+m11*m11+m12*m12+m20*m20+m21*m21+m22*m22);
    float inv = 1.f / (2.f * fn + 1e-30f);
    #pragma unroll
    for (int i = 0; i < 4; ++i)
      #pragma unroll
      for (int j = 0; j < 4; ++j) P[i][j] *= inv;
    P[0][0] += 1.f; P[1][1] += 1.f; P[2][2] += 1.f; P[3][3] += 1.f;
    for (int it = 0; it < 16; ++it) {
      float Q[4][4];
      #pragma unroll
      for (int i = 0; i < 4; ++i)
        #pragma unroll
        for (int j = 0; j < 4; ++j)
          Q[i][j] = P[i][0]*P[0][j] + P[i][1]*P[1][j] + P[i][2]*P[2][j] + P[i][3]*P[3][j];
      float mxa = 0.f;
      #pragma unroll
      for (int i = 0; i < 4; ++i)
        #pragma unroll
        for (int j = 0; j < 4; ++j) mxa = fmaxf(mxa, fabsf(Q[i][j]));
      float r = 1.f / mxa;
      #pragma unroll
      for (int i = 0; i < 4; ++i)
        #pragma unroll
        for (int j = 0; j < 4; ++j) P[i][j] = Q[i][j] * r;
    }
    float bestn = -1.f; int bj = 0;
    #pragma unroll
    for (int j = 0; j < 4; ++j) {
      float nn = P[0][j]*P[0][j] + P[1][j]*P[1][j] + P[2][j]*P[2][j] + P[3][j]*P[3][j];
      if (nn > bestn) { bestn = nn; bj = j; }
    }
    float qw = P[0][bj], qx = P[1][bj], qy = P[2][bj], qz = P[3][bj];
    float qn = rsqrtf(qw*qw + qx*qx + qy*qy + qz*qz);
    qw *= qn; qx *= qn; qy *= qn; qz *= qn;
    float* ob = out + t * 16;
    ob[0]  = 1.f - 2.f*(qy*qy + qz*qz);
    ob[1]  = 2.f*(qx*qy - qw*qz);
    ob[2]  = 2.f*(qx*qz + qw*qy);
    ob[3]  = p[9];
    ob[4]  = 2.f*(qx*qy + qw*qz);
    ob[5]  = 1.f - 2.f*(qx*qx + qz*qz);
    ob[6]  = 2.f*(qy*qz - qw*qx);
    ob[7]  = p[10];
    ob[8]  = 2.f*(qx*qz - qw*qy);
    ob[9]  = 2.f*(qy*qz + qw*qx);
    ob[10] = 1.f - 2.f*(qx*qx + qy*qy);
    ob[11] = p[11];
    ob[12] = 0.f; ob[13] = 0.f; ob[14] = 0.f; ob[15] = 1.f;
  }
}

extern "C" void kernel_launch(void* const* d_in, const int* in_sizes, int n_in,
                              void* d_out, int out_size, void* d_ws, size_t ws_size,
                              hipStream_t stream)
{
  (void)in_sizes; (void)n_in; (void)out_size;
  if (ws_size < (size_t)WS_FLOATS * sizeof(float)) return;
  const float* x   = (const float*)d_in[0];
  const float* w1  = (const float*)d_in[1];
  const float* b1  = (const float*)d_in[2];
  const float* g1  = (const float*)d_in[3];
  const float* be1 = (const float*)d_in[4];
  const float* w2  = (const float*)d_in[5];
  const float* b2  = (const float*)d_in[6];
  const float* g2  = (const float*)d_in[7];
  const float* be2 = (const float*)d_in[8];
  const float* w3  = (const float*)d_in[9];
  const float* b3  = (const float*)d_in[10];
  const float* g3  = (const float*)d_in[11];
  const float* be3 = (const float*)d_in[12];
  const float* wf1 = (const float*)d_in[13];
  const float* bf1 = (const float*)d_in[14];
  const float* gf1 = (const float*)d_in[15];
  const float* bef1= (const float*)d_in[16];
  const float* wf2 = (const float*)d_in[17];
  const float* bf2 = (const float*)d_in[18];
  const float* gf2 = (const float*)d_in[19];
  const float* bef2= (const float*)d_in[20];
  const float* wp  = (const float*)d_in[21];
  const float* bp  = (const float*)d_in[22];
  float* ws  = (float*)d_ws;
  float* out = (float*)d_out;
  unsigned short* h1t = (unsigned short*)(ws + OFF_H1T);
  unsigned short* y2h = (unsigned short*)(ws + OFF_Y2H);
  unsigned short* h2t = (unsigned short*)(ws + OFF_H2T);
  unsigned short* w3h = (unsigned short*)(ws + OFF_W3H);
  unsigned short* w2h = (unsigned short*)(ws + OFF_W2H);

  hipMemsetAsync((void*)(ws + OFF_Z), 0, ZN * sizeof(float), stream);
  k_cvt<<<136, 256, 0, stream>>>(w3, w2, w3h, w2h);
  k_xstat<<<64, 256, 0, stream>>>(x, ws + OFF_XS);
  k_conv1<<<256, 256, 0, stream>>>(x, w1, b1, g1, be1, ws + OFF_XS, h1t);
  k_conv2<<<1024, 256, 0, stream>>>(h1t, w2h, b2, y2h, ws + OFF_SUM2, ws + OFF_SQ2);
  k_bnrelu2<<<1024, 256, 0, stream>>>(y2h, ws + OFF_SUM2, ws + OFF_SQ2, g2, be2, h2t);
  k_conv3<<<512, 256, 0, stream>>>(h2t, w3h, b3, ws + OFF_MX, ws + OFF_MN,
                                   ws + OFF_SUM3, ws + OFF_SQ3);
  k_pooled<<<32, 256, 0, stream>>>(ws + OFF_SUM3, ws + OFF_SQ3, g3, be3,
                                   ws + OFF_MX, ws + OFF_MN, ws + OFF_POOL);
  k_fc1<<<dim3(16, 8), 256, 0, stream>>>(ws + OFF_POOL, wf1, bf1, ws + OFF_F1R);
  k_fc2<<<dim3(8, 8), 256, 0, stream>>>(ws + OFF_F1R, wf2, bf2, gf1, bef1, ws + OFF_F2R);
  k_head<<<1, 384, 0, stream>>>(ws + OFF_F2R, gf2, bef2, wp, bp, out);
}

// Round 8
// 211.119 us; speedup vs baseline: 3.3031x; 1.0488x over previous
//
#include <hip/hip_runtime.h>

// PointNetRot9d. Round 8: dispatch-count + invisible-cost reduction.
//  (r7 profile was blinded: top-5 all harness 268MB ws-poison fills @44us —
//   every app kernel is now <44us. Attack launch count + known inefficiencies.)
//  - conv1 FUSED into conv2 (k_conv12): staging computes h1=relu(BN1(w1·x))
//    straight from x (closed-form BN1 from x moments). h1t (8MB w + 8MB
//    strided r) and one launch removed. Same fp16 quantization point.
//  - y2 stored TRANSPOSED [b][n][c]: epilogue = 8B ushort4 stores (was 32x 2B
//    scattered); bnrelu2 becomes pure linear elementwise.
//  - k_cvt+k_xstat fused (k_prep, disjoint block ranges); k_pooled fused into
//    k_fc1 (pool slice derived inline from mxb/mnb/sum3/sq3).
//  - conv3 stats on RAW acc, bias folded at final reduction (max+b, sum+Nb,
//    sq+2b*sum+Nb^2): -20% hot-loop VALU, -16 VGPRs.
//  12 -> 8 dispatches.

#define NPT 2048
#define C1 64
#define C2 128
#define EPSV 1e-5f

typedef __attribute__((ext_vector_type(8))) _Float16 half8;
typedef __attribute__((ext_vector_type(4))) float floatx4;

// ---- workspace layout (float-slot offsets) ----
#define OFF_Y2T   0               // 32*2048*128 halves = 4194304 slots
#define OFF_H2T   4194304         // 32*2048*128 halves = 4194304 slots
#define OFF_Z     8388608         // zeroed region start
#define OFF_XS    (OFF_Z)         // 16: Sx[3], Sxx diag[3], Sxx off[3]
#define OFF_SUM2  (OFF_Z+16)
#define OFF_SQ2   (OFF_Z+144)
#define OFF_SUM3  (OFF_Z+272)
#define OFF_SQ3   (OFF_Z+1296)
#define OFF_F1R   (OFF_Z+2320)    // 32*512
#define OFF_F2R   (OFF_Z+18704)   // 32*256
#define ZN        26896
#define OFF_MX    (OFF_Z+26896)   // 2 ns-slots * 32*1024
#define OFF_MN    (OFF_MX+65536)
#define OFF_W3H   (OFF_MN+65536)  // 131072 halves = 65536 slots
#define OFF_W2H   (OFF_W3H+65536) // 8192 halves = 4096 slots
#define WS_FLOATS (OFF_W2H+4096)  // 8,550,160 floats = 34.2 MB

static __device__ inline unsigned short f16r(float f) {
  _Float16 h = (_Float16)f;
  return __builtin_bit_cast(unsigned short, h);
}
static __device__ inline float h2f(unsigned short u) {
  return (float)__builtin_bit_cast(_Float16, u);
}
// LDS staging swizzle (bijection on n per cb): conflict-free b128 write+read.
static __device__ inline int SW(int n, int cb) { return n ^ (((n >> 3) ^ cb) & 7); }

// k_prep: blocks [0,136) cvt w3/w2 -> fp16; blocks [136,200) x moments.
__global__ __launch_bounds__(256) void k_prep(const float* __restrict__ w3,
    const float* __restrict__ w2, unsigned short* __restrict__ w3h,
    unsigned short* __restrict__ w2h, const float* __restrict__ x,
    float* __restrict__ xs)
{
  int bi = blockIdx.x;
  int t = threadIdx.x;
  if (bi < 136) {
    int idx4 = bi * 256 + t;                   // 34816 f4
    const float4* src; ushort4* dst; int k;
    if (idx4 < 32768) { src = (const float4*)w3; dst = (ushort4*)w3h; k = idx4; }
    else               { src = (const float4*)w2; dst = (ushort4*)w2h; k = idx4 - 32768; }
    float4 v = src[k];
    ushort4 o;
    o.x = f16r(v.x); o.y = f16r(v.y); o.z = f16r(v.z); o.w = f16r(v.w);
    dst[k] = o;
    return;
  }
  int idx4 = (bi - 136) * 256 + t;             // 16384 f4 = [32 b][512 n4]
  int n4 = idx4 & 511, b = idx4 >> 9;
  const float4* xr = (const float4*)(x + (size_t)b * 3 * NPT);
  float4 x0 = xr[n4], x1 = xr[512 + n4], x2 = xr[1024 + n4];
  float v[9];
  v[0] = x0.x + x0.y + x0.z + x0.w;
  v[1] = x1.x + x1.y + x1.z + x1.w;
  v[2] = x2.x + x2.y + x2.z + x2.w;
  v[3] = x0.x*x0.x + x0.y*x0.y + x0.z*x0.z + x0.w*x0.w;
  v[4] = x1.x*x1.x + x1.y*x1.y + x1.z*x1.z + x1.w*x1.w;
  v[5] = x2.x*x2.x + x2.y*x2.y + x2.z*x2.z + x2.w*x2.w;
  v[6] = x0.x*x1.x + x0.y*x1.y + x0.z*x1.z + x0.w*x1.w;
  v[7] = x0.x*x2.x + x0.y*x2.y + x0.z*x2.z + x0.w*x2.w;
  v[8] = x1.x*x2.x + x1.y*x2.y + x1.z*x2.z + x1.w*x2.w;
  #pragma unroll
  for (int k = 0; k < 9; ++k)
    for (int off = 32; off; off >>= 1) v[k] += __shfl_down(v[k], off);
  __shared__ float red[4][9];
  int lane = t & 63, wv = t >> 6;
  if (!lane)
    #pragma unroll
    for (int k = 0; k < 9; ++k) red[wv][k] = v[k];
  __syncthreads();
  if (t < 9)
    atomicAdd(&xs[t], red[0][t] + red[1][t] + red[2][t] + red[3][t]);
}

// k_conv12: fused conv1(+BN1 closed form +relu, in-register) -> conv2 MFMA.
// Block = (b, 64-n slice) x all 128 o. y2t [b][n][128c] fp16 raw + BN2 stats.
__global__ __launch_bounds__(256, 4) void k_conv12(const float* __restrict__ x,
    const float* __restrict__ w1, const float* __restrict__ b1,
    const float* __restrict__ g1, const float* __restrict__ be1,
    const float* __restrict__ xs,
    const unsigned short* __restrict__ w2h, const float* __restrict__ b2,
    unsigned short* __restrict__ y2t, float* __restrict__ sum2, float* __restrict__ sq2)
{
  __shared__ unsigned short w2s[8 * 128 * 8];   // 16 KB
  __shared__ unsigned short h1s[8 * 64 * 8];    // 8 KB
  __shared__ float wc[64][4];
  __shared__ float sred[2][128][2];
  int t = threadIdx.x;
  int bi = blockIdx.x;                 // 1024 = 32 b x 32 ns
  int b = bi >> 5, ns = bi & 31;
  int n0 = ns * 64;
  int w = t >> 6, lane = t & 63;
  int ow = w & 1, nw = w >> 1;
  int quad = lane >> 4, l15 = lane & 15;

  // A: BN1 closed form -> folded conv1 coeffs
  if (t < 64) {
    float w0 = w1[t*3], w1_ = w1[t*3+1], w2_ = w1[t*3+2], bb = b1[t];
    const float invN = 1.f / 65536.f;
    float wsx = (w0*xs[0] + w1_*xs[1] + w2_*xs[2]) * invN;
    float mean = wsx + bb;
    float Ey2 = (w0*w0*xs[3] + w1_*w1_*xs[4] + w2_*w2_*xs[5]
               + 2.f*(w0*w1_*xs[6] + w0*w2_*xs[7] + w1_*w2_*xs[8])) * invN
               + 2.f*bb*wsx + bb*bb;
    float var = Ey2 - mean*mean;
    float a = g1[t] * rsqrtf(var + EPSV);
    wc[t][0] = a*w0; wc[t][1] = a*w1_; wc[t][2] = a*w2_;
    wc[t][3] = be1[t] + a*(bb - mean);
  }
  // B: stage w2 [cb][o'][8], o' = (o+cb)&127
  for (int i = 0; i < 4; ++i) {
    int idx = i * 256 + t;             // 1024 = 128 o x 8 cb
    int o = idx >> 3, cb = idx & 7;
    uint4 v = *(const uint4*)(w2h + o * 64 + cb * 8);
    int op = (o + cb) & 127;
    *(uint4*)&w2s[(cb * 128 + op) * 8] = v;
  }
  __syncthreads();                     // wc ready for C

  // C: compute h1 = relu(wc . x) for 8c x 2n per thread; pack to swizzled LDS
  {
    int cg = t >> 5, ng = t & 31;      // 8 c-groups x 32 n-pairs
    int c0 = cg * 8, nn = ng * 2;
    const float* xb = x + (size_t)b * 3 * NPT + n0 + nn;
    float2 xv0 = *(const float2*)(xb);
    float2 xv1 = *(const float2*)(xb + NPT);
    float2 xv2 = *(const float2*)(xb + 2 * NPT);
    uint4 p0, p1;
    unsigned* a0 = (unsigned*)&p0;
    unsigned* a1 = (unsigned*)&p1;
    #pragma unroll
    for (int j = 0; j < 4; ++j) {
      int c = c0 + j * 2;
      float hA0 = fmaxf(fmaf(wc[c][0], xv0.x, fmaf(wc[c][1], xv1.x, fmaf(wc[c][2], xv2.x, wc[c][3]))), 0.f);
      float hA1 = fmaxf(fmaf(wc[c][0], xv0.y, fmaf(wc[c][1], xv1.y, fmaf(wc[c][2], xv2.y, wc[c][3]))), 0.f);
      float hB0 = fmaxf(fmaf(wc[c+1][0], xv0.x, fmaf(wc[c+1][1], xv1.x, fmaf(wc[c+1][2], xv2.x, wc[c+1][3]))), 0.f);
      float hB1 = fmaxf(fmaf(wc[c+1][0], xv0.y, fmaf(wc[c+1][1], xv1.y, fmaf(wc[c+1][2], xv2.y, wc[c+1][3]))), 0.f);
      a0[j] = (unsigned)f16r(hA0) | ((unsigned)f16r(hB0) << 16);
      a1[j] = (unsigned)f16r(hA1) | ((unsigned)f16r(hB1) << 16);
    }
    *(uint4*)&h1s[(cg * 64 + SW(nn, cg)) * 8] = p0;
    *(uint4*)&h1s[(cg * 64 + SW(nn + 1, cg)) * 8] = p1;
  }
  __syncthreads();

  half8 af[4][2];
  #pragma unroll
  for (int ti = 0; ti < 4; ++ti)
    #pragma unroll
    for (int s = 0; s < 2; ++s) {
      int cb = s * 4 + quad;
      int o = ow * 64 + ti * 16 + l15;
      int op = (o + cb) & 127;
      af[ti][s] = *(const half8*)&w2s[(cb * 128 + op) * 8];
    }
  float breg[4][4];
  #pragma unroll
  for (int ti = 0; ti < 4; ++ti)
    #pragma unroll
    for (int r = 0; r < 4; ++r)
      breg[ti][r] = b2[ow * 64 + ti * 16 + quad * 4 + r];

  floatx4 acc[4][2];
  #pragma unroll
  for (int ti = 0; ti < 4; ++ti)
    #pragma unroll
    for (int nt = 0; nt < 2; ++nt) acc[ti][nt] = (floatx4){0.f, 0.f, 0.f, 0.f};
  #pragma unroll
  for (int s = 0; s < 2; ++s) {
    int cb = s * 4 + quad;
    half8 bf[2];
    #pragma unroll
    for (int nt = 0; nt < 2; ++nt) {
      int n = nw * 32 + nt * 16 + l15;
      bf[nt] = *(const half8*)&h1s[(cb * 64 + SW(n, cb)) * 8];
    }
    #pragma unroll
    for (int ti = 0; ti < 4; ++ti) {
      acc[ti][0] = __builtin_amdgcn_mfma_f32_16x16x32_f16(af[ti][s], bf[0], acc[ti][0], 0, 0, 0);
      acc[ti][1] = __builtin_amdgcn_mfma_f32_16x16x32_f16(af[ti][s], bf[1], acc[ti][1], 0, 0, 0);
    }
  }

  // epilogue: y2t[b][n][c] = fp16(acc + b2) via 8B stores; exact fp32 stats
  float sm[4][4], sq[4][4];
  #pragma unroll
  for (int ti = 0; ti < 4; ++ti)
    #pragma unroll
    for (int r = 0; r < 4; ++r) { sm[ti][r] = 0.f; sq[ti][r] = 0.f; }
  #pragma unroll
  for (int ti = 0; ti < 4; ++ti) {
    int o = ow * 64 + ti * 16 + quad * 4;
    #pragma unroll
    for (int nt = 0; nt < 2; ++nt) {
      int n = n0 + nw * 32 + nt * 16 + l15;
      float v0 = acc[ti][nt][0] + breg[ti][0];
      float v1 = acc[ti][nt][1] + breg[ti][1];
      float v2 = acc[ti][nt][2] + breg[ti][2];
      float v3 = acc[ti][nt][3] + breg[ti][3];
      ushort4 st;
      st.x = f16r(v0); st.y = f16r(v1); st.z = f16r(v2); st.w = f16r(v3);
      *(ushort4*)(y2t + ((size_t)b * NPT + n) * C2 + o) = st;
      sm[ti][0] += v0; sq[ti][0] = fmaf(v0, v0, sq[ti][0]);
      sm[ti][1] += v1; sq[ti][1] = fmaf(v1, v1, sq[ti][1]);
      sm[ti][2] += v2; sq[ti][2] = fmaf(v2, v2, sq[ti][2]);
      sm[ti][3] += v3; sq[ti][3] = fmaf(v3, v3, sq[ti][3]);
    }
  }
  #pragma unroll
  for (int ti = 0; ti < 4; ++ti)
    #pragma unroll
    for (int r = 0; r < 4; ++r) {
      #pragma unroll
      for (int m = 1; m < 16; m <<= 1) {
        sm[ti][r] += __shfl_xor(sm[ti][r], m, 16);
        sq[ti][r] += __shfl_xor(sq[ti][r], m, 16);
      }
    }
  if (l15 == 0) {
    #pragma unroll
    for (int ti = 0; ti < 4; ++ti)
      #pragma unroll
      for (int r = 0; r < 4; ++r) {
        int oloc = ow * 64 + ti * 16 + quad * 4 + r;
        sred[nw][oloc][0] = sm[ti][r];
        sred[nw][oloc][1] = sq[ti][r];
      }
  }
  __syncthreads();
  if (t < 128) {
    atomicAdd(&sum2[t], sred[0][t][0] + sred[1][t][0]);
    atomicAdd(&sq2[t],  sred[0][t][1] + sred[1][t][1]);
  }
}

// BN2+relu elementwise (linear, same layout): y2t -> h2t, fp32 BN math.
__global__ __launch_bounds__(256) void k_bnrelu2(const unsigned short* __restrict__ y2t,
    const float* __restrict__ sum2, const float* __restrict__ sq2,
    const float* __restrict__ g2, const float* __restrict__ be2,
    unsigned short* __restrict__ h2t)
{
  __shared__ float bn[128][2];
  int t = threadIdx.x;
  if (t < 128) {
    float m = sum2[t] * (1.f / 65536.f);
    float v = fmaf(-m, m, sq2[t] * (1.f / 65536.f));
    float a = g2[t] * rsqrtf(v + EPSV);
    bn[t][0] = a; bn[t][1] = fmaf(-a, m, be2[t]);
  }
  __syncthreads();
  size_t base = ((size_t)blockIdx.x * 256 + t) * 32;   // 32 halves/thread
  int c0 = (int)(base & 127);
  #pragma unroll
  for (int k = 0; k < 4; ++k) {
    ushort4 u0 = *(const ushort4*)(y2t + base + k * 8);
    ushort4 u1 = *(const ushort4*)(y2t + base + k * 8 + 4);
    int c = c0 + k * 8;
    float h0 = fmaxf(fmaf(bn[c+0][0], h2f(u0.x), bn[c+0][1]), 0.f);
    float h1 = fmaxf(fmaf(bn[c+1][0], h2f(u0.y), bn[c+1][1]), 0.f);
    float h2 = fmaxf(fmaf(bn[c+2][0], h2f(u0.z), bn[c+2][1]), 0.f);
    float h3 = fmaxf(fmaf(bn[c+3][0], h2f(u0.w), bn[c+3][1]), 0.f);
    float h4 = fmaxf(fmaf(bn[c+4][0], h2f(u1.x), bn[c+4][1]), 0.f);
    float h5 = fmaxf(fmaf(bn[c+5][0], h2f(u1.y), bn[c+5][1]), 0.f);
    float h6 = fmaxf(fmaf(bn[c+6][0], h2f(u1.z), bn[c+6][1]), 0.f);
    float h7 = fmaxf(fmaf(bn[c+7][0], h2f(u1.w), bn[c+7][1]), 0.f);
    uint4 pk;
    pk.x = (unsigned)f16r(h0) | ((unsigned)f16r(h1) << 16);
    pk.y = (unsigned)f16r(h2) | ((unsigned)f16r(h3) << 16);
    pk.z = (unsigned)f16r(h4) | ((unsigned)f16r(h5) << 16);
    pk.w = (unsigned)f16r(h6) | ((unsigned)f16r(h7) << 16);
    *(uint4*)(h2t + base + k * 8) = pk;
  }
}

// conv3 MFMA: block = (ot, b, n-half); 16 chunks of 64 n; staging = pure copy.
// Stats on RAW acc; bias folded at final reduction.
__global__ __launch_bounds__(256, 2) void k_conv3(const unsigned short* __restrict__ h2t,
    const unsigned short* __restrict__ w3h, const float* __restrict__ b3,
    float* __restrict__ mxb, float* __restrict__ mnb,
    float* __restrict__ sum3, float* __restrict__ sq3)
{
  __shared__ unsigned short w3s[16 * 128 * 8];  // 32 KB
  __shared__ unsigned short h2s[16 * 64 * 8];   // 16 KB
  __shared__ float sred[2][128][4];             // 4 KB
  int t = threadIdx.x;
  int bi = blockIdx.x;                 // 512: bi = ot*64 + b*2 + ns
  int ot_blk = bi >> 6;
  int b  = (bi >> 1) & 31;
  int ns = bi & 1;
  int o0 = ot_blk * 128;
  int n_base = ns * 1024;
  int w = t >> 6, lane = t & 63;
  int ow = w & 1, nw = w >> 1;
  int quad = lane >> 4, l15 = lane & 15;

  for (int i = 0; i < 8; ++i) {
    int idx = i * 256 + t;             // 2048 = 128 o x 16 cb
    int o = idx >> 4, cb = idx & 15;
    uint4 v = *(const uint4*)(w3h + (size_t)(o0 + o) * 128 + cb * 8);
    int op = (o + cb) & 127;
    *(uint4*)&w3s[(cb * 128 + op) * 8] = v;
  }
  __syncthreads();

  half8 af[4][4];
  #pragma unroll
  for (int ti = 0; ti < 4; ++ti)
    #pragma unroll
    for (int s = 0; s < 4; ++s) {
      int cb = s * 4 + quad;
      int o = ow * 64 + ti * 16 + l15;
      int op = (o + cb) & 127;
      af[ti][s] = *(const half8*)&w3s[(cb * 128 + op) * 8];
    }

  float mx[4][4], mn[4][4], sm[4][4], sq[4][4];
  #pragma unroll
  for (int ti = 0; ti < 4; ++ti)
    #pragma unroll
    for (int r = 0; r < 4; ++r) {
      mx[ti][r] = -3.4e38f; mn[ti][r] = 3.4e38f; sm[ti][r] = 0.f; sq[ti][r] = 0.f;
    }

  int sn = t & 63, cq = t >> 6;        // staging map: 64 n x 4 cb-quads
  for (int nc = 0; nc < 16; ++nc) {
    int n0 = n_base + nc * 64;
    __syncthreads();
    {
      const unsigned short* src = h2t + ((size_t)b * NPT + n0 + sn) * C2 + cq * 32;
      uint4 v0 = *(const uint4*)(src);
      uint4 v1 = *(const uint4*)(src + 8);
      uint4 v2 = *(const uint4*)(src + 16);
      uint4 v3 = *(const uint4*)(src + 24);
      int cb0 = cq * 4;
      *(uint4*)&h2s[((cb0 + 0) * 64 + SW(sn, cb0 + 0)) * 8] = v0;
      *(uint4*)&h2s[((cb0 + 1) * 64 + SW(sn, cb0 + 1)) * 8] = v1;
      *(uint4*)&h2s[((cb0 + 2) * 64 + SW(sn, cb0 + 2)) * 8] = v2;
      *(uint4*)&h2s[((cb0 + 3) * 64 + SW(sn, cb0 + 3)) * 8] = v3;
    }
    __syncthreads();

    floatx4 acc[4][2];
    #pragma unroll
    for (int ti = 0; ti < 4; ++ti)
      #pragma unroll
      for (int nt = 0; nt < 2; ++nt) acc[ti][nt] = (floatx4){0.f, 0.f, 0.f, 0.f};
    #pragma unroll
    for (int s = 0; s < 4; ++s) {
      int cb = s * 4 + quad;
      half8 bf[2];
      #pragma unroll
      for (int nt = 0; nt < 2; ++nt) {
        int n = nw * 32 + nt * 16 + l15;
        bf[nt] = *(const half8*)&h2s[(cb * 64 + SW(n, cb)) * 8];
      }
      #pragma unroll
      for (int ti = 0; ti < 4; ++ti) {
        acc[ti][0] = __builtin_amdgcn_mfma_f32_16x16x32_f16(af[ti][s], bf[0], acc[ti][0], 0, 0, 0);
        acc[ti][1] = __builtin_amdgcn_mfma_f32_16x16x32_f16(af[ti][s], bf[1], acc[ti][1], 0, 0, 0);
      }
    }
    #pragma unroll
    for (int ti = 0; ti < 4; ++ti)
      #pragma unroll
      for (int nt = 0; nt < 2; ++nt)
        #pragma unroll
        for (int r = 0; r < 4; ++r) {
          float v = acc[ti][nt][r];
          mx[ti][r] = fmaxf(mx[ti][r], v);
          mn[ti][r] = fminf(mn[ti][r], v);
          sm[ti][r] += v;
          sq[ti][r] = fmaf(v, v, sq[ti][r]);
        }
  }

  #pragma unroll
  for (int ti = 0; ti < 4; ++ti)
    #pragma unroll
    for (int r = 0; r < 4; ++r) {
      #pragma unroll
      for (int m = 1; m < 16; m <<= 1) {
        mx[ti][r] = fmaxf(mx[ti][r], __shfl_xor(mx[ti][r], m, 16));
        mn[ti][r] = fminf(mn[ti][r], __shfl_xor(mn[ti][r], m, 16));
        sm[ti][r] += __shfl_xor(sm[ti][r], m, 16);
        sq[ti][r] += __shfl_xor(sq[ti][r], m, 16);
      }
    }
  if (l15 == 0) {
    #pragma unroll
    for (int ti = 0; ti < 4; ++ti)
      #pragma unroll
      for (int r = 0; r < 4; ++r) {
        int oloc = ow * 64 + ti * 16 + quad * 4 + r;
        sred[nw][oloc][0] = mx[ti][r];
        sred[nw][oloc][1] = mn[ti][r];
        sred[nw][oloc][2] = sm[ti][r];
        sred[nw][oloc][3] = sq[ti][r];
      }
  }
  __syncthreads();
  if (t < 128) {
    int o = o0 + t;
    float bo = b3[o];
    float fmx = fmaxf(sred[0][t][0], sred[1][t][0]) + bo;
    float fmn = fminf(sred[0][t][1], sred[1][t][1]) + bo;
    float smr = sred[0][t][2] + sred[1][t][2];
    float sqr = sred[0][t][3] + sred[1][t][3];
    mxb[ns * 32768 + b * 1024 + o] = fmx;
    mnb[ns * 32768 + b * 1024 + o] = fmn;
    atomicAdd(&sum3[o], fmaf(1024.f, bo, smr));
    atomicAdd(&sq3[o],  fmaf(1024.f * bo, bo, fmaf(2.f * bo, smr, sqr)));
  }
}

// FC1 + pooled fused: pool slice derived inline from mxb/mnb/sum3/sq3 (BN3).
// grid (16 f-tiles of 32, 8 k-chunks of 128); unroll capped at 4.
__global__ __launch_bounds__(256) void k_fc1(const float* __restrict__ mxb,
    const float* __restrict__ mnb, const float* __restrict__ sum3,
    const float* __restrict__ sq3, const float* __restrict__ g3,
    const float* __restrict__ be3, const float* __restrict__ wf1,
    const float* __restrict__ bf1, float* __restrict__ f1r)
{
  __shared__ float ins[32 * 128];   // 16 KB
  __shared__ float bnA[128], bnS[128];
  int t = threadIdx.x;
  int f0 = blockIdx.x * 32;
  int k0 = blockIdx.y * 128;
  if (t < 128) {
    int c = k0 + t;
    float m = sum3[c] * (1.f / 65536.f);
    float v = fmaf(-m, m, sq3[c] * (1.f / 65536.f));
    float a = g3[c] * rsqrtf(v + EPSV);
    bnA[t] = a; bnS[t] = fmaf(-a, m, be3[c]);
  }
  __syncthreads();
  #pragma unroll
  for (int i = 0; i < 4; ++i) {
    int idx = i * 256 + t;
    int b = idx >> 5, k4 = idx & 31;
    float4 mxv = *(const float4*)(mxb + (size_t)b * 1024 + k0 + k4 * 4);
    float4 mx1 = *(const float4*)(mxb + 32768 + (size_t)b * 1024 + k0 + k4 * 4);
    float4 mnv = *(const float4*)(mnb + (size_t)b * 1024 + k0 + k4 * 4);
    float4 mn1 = *(const float4*)(mnb + 32768 + (size_t)b * 1024 + k0 + k4 * 4);
    float4 a = *(const float4*)&bnA[k4 * 4];
    float4 s = *(const float4*)&bnS[k4 * 4];
    float4 r;
    r.x = fmaf(a.x, (a.x >= 0.f ? fmaxf(mxv.x, mx1.x) : fminf(mnv.x, mn1.x)), s.x);
    r.y = fmaf(a.y, (a.y >= 0.f ? fmaxf(mxv.y, mx1.y) : fminf(mnv.y, mn1.y)), s.y);
    r.z = fmaf(a.z, (a.z >= 0.f ? fmaxf(mxv.z, mx1.z) : fminf(mnv.z, mn1.z)), s.z);
    r.w = fmaf(a.w, (a.w >= 0.f ? fmaxf(mxv.w, mx1.w) : fminf(mnv.w, mn1.w)), s.w);
    *(float4*)&ins[b * 128 + k4 * 4] = r;
  }
  __syncthreads();
  int f = t & 31, bq = t >> 5;
  int bl = bq * 4;
  const float4* wr = (const float4*)(wf1 + (size_t)(f0 + f) * 1024 + k0);
  float acc0 = 0.f, acc1 = 0.f, acc2 = 0.f, acc3 = 0.f;
  #pragma unroll 4
  for (int k4 = 0; k4 < 32; ++k4) {
    float4 wv = wr[k4];
    float4 i0 = *(const float4*)&ins[(bl + 0) * 128 + k4 * 4];
    float4 i1 = *(const float4*)&ins[(bl + 1) * 128 + k4 * 4];
    float4 i2 = *(const float4*)&ins[(bl + 2) * 128 + k4 * 4];
    float4 i3 = *(const float4*)&ins[(bl + 3) * 128 + k4 * 4];
    acc0 = fmaf(wv.x, i0.x, fmaf(wv.y, i0.y, fmaf(wv.z, i0.z, fmaf(wv.w, i0.w, acc0))));
    acc1 = fmaf(wv.x, i1.x, fmaf(wv.y, i1.y, fmaf(wv.z, i1.z, fmaf(wv.w, i1.w, acc1))));
    acc2 = fmaf(wv.x, i2.x, fmaf(wv.y, i2.y, fmaf(wv.z, i2.z, fmaf(wv.w, i2.w, acc2))));
    acc3 = fmaf(wv.x, i3.x, fmaf(wv.y, i3.y, fmaf(wv.z, i3.z, fmaf(wv.w, i3.w, acc3))));
  }
  float bs = (blockIdx.y == 0) ? bf1[f0 + f] : 0.f;
  atomicAdd(&f1r[(size_t)(bl + 0) * 512 + f0 + f], acc0 + bs);
  atomicAdd(&f1r[(size_t)(bl + 1) * 512 + f0 + f], acc1 + bs);
  atomicAdd(&f1r[(size_t)(bl + 2) * 512 + f0 + f], acc2 + bs);
  atomicAdd(&f1r[(size_t)(bl + 3) * 512 + f0 + f], acc3 + bs);
}

// FC2: BN1d(f1) stats inline per k-chunk; unroll capped at 4.
__global__ __launch_bounds__(256) void k_fc2(const float* __restrict__ f1r,
    const float* __restrict__ wf2, const float* __restrict__ bf2,
    const float* __restrict__ gf1, const float* __restrict__ bef1,
    float* __restrict__ f2r)
{
  __shared__ float ins[32 * 64];    // 8 KB
  __shared__ float bnA[64], bnS[64];
  int t = threadIdx.x;
  int f0 = blockIdx.x * 32;
  int k0 = blockIdx.y * 64;
  #pragma unroll
  for (int i = 0; i < 2; ++i) {
    int idx = i * 256 + t;
    int b = idx >> 4, k4 = idx & 15;
    *(float4*)&ins[b * 64 + k4 * 4] = *(const float4*)(f1r + (size_t)b * 512 + k0 + k4 * 4);
  }
  __syncthreads();
  if (t < 64) {
    float s = 0.f, q = 0.f;
    #pragma unroll
    for (int b = 0; b < 32; ++b) {
      float xx = ins[b * 64 + t];
      s += xx; q = fmaf(xx, xx, q);
    }
    float m = s * (1.f / 32.f);
    float v = fmaf(-m, m, q * (1.f / 32.f));
    float a = gf1[k0 + t] * rsqrtf(v + EPSV);
    bnA[t] = a; bnS[t] = fmaf(-a, m, bef1[k0 + t]);
  }
  __syncthreads();
  #pragma unroll
  for (int i = 0; i < 2; ++i) {
    int idx = i * 256 + t;
    int b = idx >> 4, k4 = idx & 15;
    float4 v = *(const float4*)&ins[b * 64 + k4 * 4];
    v.x = fmaxf(fmaf(bnA[k4*4+0], v.x, bnS[k4*4+0]), 0.f);
    v.y = fmaxf(fmaf(bnA[k4*4+1], v.y, bnS[k4*4+1]), 0.f);
    v.z = fmaxf(fmaf(bnA[k4*4+2], v.z, bnS[k4*4+2]), 0.f);
    v.w = fmaxf(fmaf(bnA[k4*4+3], v.w, bnS[k4*4+3]), 0.f);
    *(float4*)&ins[b * 64 + k4 * 4] = v;
  }
  __syncthreads();
  int f = t & 31, bq = t >> 5;
  int bl = bq * 4;
  const float4* wr = (const float4*)(wf2 + (size_t)(f0 + f) * 512 + k0);
  float acc0 = 0.f, acc1 = 0.f, acc2 = 0.f, acc3 = 0.f;
  #pragma unroll 4
  for (int k4 = 0; k4 < 16; ++k4) {
    float4 wv = wr[k4];
    float4 i0 = *(const float4*)&ins[(bl + 0) * 64 + k4 * 4];
    float4 i1 = *(const float4*)&ins[(bl + 1) * 64 + k4 * 4];
    float4 i2 = *(const float4*)&ins[(bl + 2) * 64 + k4 * 4];
    float4 i3 = *(const float4*)&ins[(bl + 3) * 64 + k4 * 4];
    acc0 = fmaf(wv.x, i0.x, fmaf(wv.y, i0.y, fmaf(wv.z, i0.z, fmaf(wv.w, i0.w, acc0))));
    acc1 = fmaf(wv.x, i1.x, fmaf(wv.y, i1.y, fmaf(wv.z, i1.z, fmaf(wv.w, i1.w, acc1))));
    acc2 = fmaf(wv.x, i2.x, fmaf(wv.y, i2.y, fmaf(wv.z, i2.z, fmaf(wv.w, i2.w, acc2))));
    acc3 = fmaf(wv.x, i3.x, fmaf(wv.y, i3.y, fmaf(wv.z, i3.z, fmaf(wv.w, i3.w, acc3))));
  }
  float bs = (blockIdx.y == 0) ? bf2[f0 + f] : 0.f;
  atomicAdd(&f2r[(size_t)(bl + 0) * 256 + f0 + f], acc0 + bs);
  atomicAdd(&f2r[(size_t)(bl + 1) * 256 + f0 + f], acc1 + bs);
  atomicAdd(&f2r[(size_t)(bl + 2) * 256 + f0 + f], acc2 + bs);
  atomicAdd(&f2r[(size_t)(bl + 3) * 256 + f0 + f], acc3 + bs);
}

// Head: BN-F2 stats inline; p = relu(BN(f2r)) @ wp.T + bp; Horn SO(3) -> [B,4,4].
__global__ __launch_bounds__(384) void k_head(const float* __restrict__ f2r,
    const float* __restrict__ gf2, const float* __restrict__ bef2,
    const float* __restrict__ wp, const float* __restrict__ bp,
    float* __restrict__ out)
{
  __shared__ float pS[32 * 12];
  __shared__ float bnf[256][2];
  int t = threadIdx.x;
  if (t < 256) {
    float s = 0.f, q = 0.f;
    #pragma unroll
    for (int b = 0; b < 32; ++b) {
      float xx = f2r[b * 256 + t];
      s += xx; q = fmaf(xx, xx, q);
    }
    float m = s * (1.f / 32.f);
    float v = fmaf(-m, m, q * (1.f / 32.f));
    float a = gf2[t] * rsqrtf(v + EPSV);
    bnf[t][0] = a; bnf[t][1] = fmaf(-a, m, bef2[t]);
  }
  __syncthreads();
  {
    int b = t / 12, j = t % 12;
    const float* w = wp + j * 256;
    const float* fr = f2r + b * 256;
    float acc = bp[j];
    #pragma unroll 8
    for (int c = 0; c < 256; ++c) {
      float h = fmaxf(fmaf(bnf[c][0], fr[c], bnf[c][1]), 0.f);
      acc = fmaf(w[c], h, acc);
    }
    pS[t] = acc;
  }
  __syncthreads();
  if (t < 32) {
    const float* p = &pS[t * 12];
    float m00=p[0],m01=p[1],m02=p[2],m10=p[3],m11=p[4],m12=p[5],m20=p[6],m21=p[7],m22=p[8];
    float P[4][4];
    P[0][0]=m00+m11+m22; P[0][1]=m21-m12;     P[0][2]=m02-m20;     P[0][3]=m10-m01;
    P[1][1]=m00-m11-m22; P[1][2]=m01+m10;     P[1][3]=m02+m20;
    P[2][2]=m11-m00-m22; P[2][3]=m12+m21;
    P[3][3]=m22-m00-m11;
    P[1][0]=P[0][1]; P[2][0]=P[0][2]; P[3][0]=P[0][3];
    P[2][1]=P[1][2]; P[3][1]=P[1][3]; P[3][2]=P[2][3];
    float fn = sqrtf(m00*m00+m01*m01+m02*m02+m10*m10+m11*m11+m12*m12+m20*m20+m21*m21+m22*m22);
    float inv = 1.f / (2.f * fn + 1e-30f);
    #pragma unroll
    for (int i = 0; i < 4; ++i)
      #pragma unroll
      for (int j = 0; j < 4; ++j) P[i][j] *= inv;
    P[0][0] += 1.f; P[1][1] += 1.f; P[2][2] += 1.f; P[3][3] += 1.f;
    for (int it = 0; it < 16; ++it) {
      float Q[4][4];
      #pragma unroll
      for (int i = 0; i < 4; ++i)
        #pragma unroll
        for (int j = 0; j < 4; ++j)
          Q[i][j] = P[i][0]*P[0][j] + P[i][1]*P[1][j] + P[i][2]*P[2][j] + P[i][3]*P[3][j];
      float mxa = 0.f;
      #pragma unroll
      for (int i = 0; i < 4; ++i)
        #pragma unroll
        for (int j = 0; j < 4; ++j) mxa = fmaxf(mxa, fabsf(Q[i][j]));
      float r = 1.f / mxa;
      #pragma unroll
      for (int i = 0; i < 4; ++i)
        #pragma unroll
        for (int j = 0; j < 4; ++j) P[i][j] = Q[i][j] * r;
    }
    float bestn = -1.f; int bj = 0;
    #pragma unroll
    for (int j = 0; j < 4; ++j) {
      float nn = P[0][j]*P[0][j] + P[1][j]*P[1][j] + P[2][j]*P[2][j] + P[3][j]*P[3][j];
      if (nn > bestn) { bestn = nn; bj = j; }
    }
    float qw = P[0][bj], qx = P[1][bj], qy = P[2][bj], qz = P[3][bj];
    float qn = rsqrtf(qw*qw + qx*qx + qy*qy + qz*qz);
    qw *= qn; qx *= qn; qy *= qn; qz *= qn;
    float* ob = out + t * 16;
    ob[0]  = 1.f - 2.f*(qy*qy + qz*qz);
    ob[1]  = 2.f*(qx*qy - qw*qz);
    ob[2]  = 2.f*(qx*qz + qw*qy);
    ob[3]  = p[9];
    ob[4]  = 2.f*(qx*qy + qw*qz);
    ob[5]  = 1.f - 2.f*(qx*qx + qz*qz);
    ob[6]  = 2.f*(qy*qz - qw*qx);
    ob[7]  = p[10];
    ob[8]  = 2.f*(qx*qz - qw*qy);
    ob[9]  = 2.f*(qy*qz + qw*qx);
    ob[10] = 1.f - 2.f*(qx*qx + qy*qy);
    ob[11] = p[11];
    ob[12] = 0.f; ob[13] = 0.f; ob[14] = 0.f; ob[15] = 1.f;
  }
}

extern "C" void kernel_launch(void* const* d_in, const int* in_sizes, int n_in,
                              void* d_out, int out_size, void* d_ws, size_t ws_size,
                              hipStream_t stream)
{
  (void)in_sizes; (void)n_in; (void)out_size;
  if (ws_size < (size_t)WS_FLOATS * sizeof(float)) return;
  const float* x   = (const float*)d_in[0];
  const float* w1  = (const float*)d_in[1];
  const float* b1  = (const float*)d_in[2];
  const float* g1  = (const float*)d_in[3];
  const float* be1 = (const float*)d_in[4];
  const float* w2  = (const float*)d_in[5];
  const float* b2  = (const float*)d_in[6];
  const float* g2  = (const float*)d_in[7];
  const float* be2 = (const float*)d_in[8];
  const float* w3  = (const float*)d_in[9];
  const float* b3  = (const float*)d_in[10];
  const float* g3  = (const float*)d_in[11];
  const float* be3 = (const float*)d_in[12];
  const float* wf1 = (const float*)d_in[13];
  const float* bf1 = (const float*)d_in[14];
  const float* gf1 = (const float*)d_in[15];
  const float* bef1= (const float*)d_in[16];
  const float* wf2 = (const float*)d_in[17];
  const float* bf2 = (const float*)d_in[18];
  const float* gf2 = (const float*)d_in[19];
  const float* bef2= (const float*)d_in[20];
  const float* wp  = (const float*)d_in[21];
  const float* bp  = (const float*)d_in[22];
  float* ws  = (float*)d_ws;
  float* out = (float*)d_out;
  unsigned short* y2t = (unsigned short*)(ws + OFF_Y2T);
  unsigned short* h2t = (unsigned short*)(ws + OFF_H2T);
  unsigned short* w3h = (unsigned short*)(ws + OFF_W3H);
  unsigned short* w2h = (unsigned short*)(ws + OFF_W2H);

  hipMemsetAsync((void*)(ws + OFF_Z), 0, ZN * sizeof(float), stream);
  k_prep<<<200, 256, 0, stream>>>(w3, w2, w3h, w2h, x, ws + OFF_XS);
  k_conv12<<<1024, 256, 0, stream>>>(x, w1, b1, g1, be1, ws + OFF_XS,
                                     w2h, b2, y2t, ws + OFF_SUM2, ws + OFF_SQ2);
  k_bnrelu2<<<1024, 256, 0, stream>>>(y2t, ws + OFF_SUM2, ws + OFF_SQ2, g2, be2, h2t);
  k_conv3<<<512, 256, 0, stream>>>(h2t, w3h, b3, ws + OFF_MX, ws + OFF_MN,
                                   ws + OFF_SUM3, ws + OFF_SQ3);
  k_fc1<<<dim3(16, 8), 256, 0, stream>>>(ws + OFF_MX, ws + OFF_MN, ws + OFF_SUM3,
                                         ws + OFF_SQ3, g3, be3, wf1, bf1, ws + OFF_F1R);
  k_fc2<<<dim3(8, 8), 256, 0, stream>>>(ws + OFF_F1R, wf2, bf2, gf1, bef1, ws + OFF_F2R);
  k_head<<<1, 384, 0, stream>>>(ws + OFF_F2R, gf2, bef2, wp, bp, out);
}

// Round 9
// 205.413 us; speedup vs baseline: 3.3949x; 1.0278x over previous
//
#include <hip/hip_runtime.h>

// PointNetRot9d. Round 9: conv3 K-loop restructure (everything else = r8).
//  - r8 profile blinded by harness 268MB ws-poison fills (43us each); model
//    says conv3 is barrier+staging-latency bound (2 barriers/chunk, global
//    load latency exposed between barrier and ds_write; stats-VALU > MFMA).
//  - conv3 now: DOUBLE-BUFFERED h2s (2x16KB) + register prefetch of chunk
//    nc+1 issued during MFMA of chunk nc -> ONE barrier per chunk, staging
//    loads covered by MFMA phase. LDS 68KB -> still 2 blocks/CU.
//  - r8 content kept: conv1 fused into conv12 (closed-form BN1 from x
//    moments), y2t/h2t transposed [b][n][c] fp16, pure-copy swizzled staging,
//    pooled fused into fc1, conv3 stats on raw acc w/ bias folded at the end.

#define NPT 2048
#define C1 64
#define C2 128
#define EPSV 1e-5f

typedef __attribute__((ext_vector_type(8))) _Float16 half8;
typedef __attribute__((ext_vector_type(4))) float floatx4;

// ---- workspace layout (float-slot offsets) ----
#define OFF_Y2T   0               // 32*2048*128 halves = 4194304 slots
#define OFF_H2T   4194304         // 32*2048*128 halves = 4194304 slots
#define OFF_Z     8388608         // zeroed region start
#define OFF_XS    (OFF_Z)         // 16: Sx[3], Sxx diag[3], Sxx off[3]
#define OFF_SUM2  (OFF_Z+16)
#define OFF_SQ2   (OFF_Z+144)
#define OFF_SUM3  (OFF_Z+272)
#define OFF_SQ3   (OFF_Z+1296)
#define OFF_F1R   (OFF_Z+2320)    // 32*512
#define OFF_F2R   (OFF_Z+18704)   // 32*256
#define ZN        26896
#define OFF_MX    (OFF_Z+26896)   // 2 ns-slots * 32*1024
#define OFF_MN    (OFF_MX+65536)
#define OFF_W3H   (OFF_MN+65536)  // 131072 halves = 65536 slots
#define OFF_W2H   (OFF_W3H+65536) // 8192 halves = 4096 slots
#define WS_FLOATS (OFF_W2H+4096)  // 8,550,160 floats = 34.2 MB

static __device__ inline unsigned short f16r(float f) {
  _Float16 h = (_Float16)f;
  return __builtin_bit_cast(unsigned short, h);
}
static __device__ inline float h2f(unsigned short u) {
  return (float)__builtin_bit_cast(_Float16, u);
}
// LDS staging swizzle (bijection on n per cb): conflict-free b128 write+read.
static __device__ inline int SW(int n, int cb) { return n ^ (((n >> 3) ^ cb) & 7); }

// k_prep: blocks [0,136) cvt w3/w2 -> fp16; blocks [136,200) x moments.
__global__ __launch_bounds__(256) void k_prep(const float* __restrict__ w3,
    const float* __restrict__ w2, unsigned short* __restrict__ w3h,
    unsigned short* __restrict__ w2h, const float* __restrict__ x,
    float* __restrict__ xs)
{
  int bi = blockIdx.x;
  int t = threadIdx.x;
  if (bi < 136) {
    int idx4 = bi * 256 + t;                   // 34816 f4
    const float4* src; ushort4* dst; int k;
    if (idx4 < 32768) { src = (const float4*)w3; dst = (ushort4*)w3h; k = idx4; }
    else               { src = (const float4*)w2; dst = (ushort4*)w2h; k = idx4 - 32768; }
    float4 v = src[k];
    ushort4 o;
    o.x = f16r(v.x); o.y = f16r(v.y); o.z = f16r(v.z); o.w = f16r(v.w);
    dst[k] = o;
    return;
  }
  int idx4 = (bi - 136) * 256 + t;             // 16384 f4 = [32 b][512 n4]
  int n4 = idx4 & 511, b = idx4 >> 9;
  const float4* xr = (const float4*)(x + (size_t)b * 3 * NPT);
  float4 x0 = xr[n4], x1 = xr[512 + n4], x2 = xr[1024 + n4];
  float v[9];
  v[0] = x0.x + x0.y + x0.z + x0.w;
  v[1] = x1.x + x1.y + x1.z + x1.w;
  v[2] = x2.x + x2.y + x2.z + x2.w;
  v[3] = x0.x*x0.x + x0.y*x0.y + x0.z*x0.z + x0.w*x0.w;
  v[4] = x1.x*x1.x + x1.y*x1.y + x1.z*x1.z + x1.w*x1.w;
  v[5] = x2.x*x2.x + x2.y*x2.y + x2.z*x2.z + x2.w*x2.w;
  v[6] = x0.x*x1.x + x0.y*x1.y + x0.z*x1.z + x0.w*x1.w;
  v[7] = x0.x*x2.x + x0.y*x2.y + x0.z*x2.z + x0.w*x2.w;
  v[8] = x1.x*x2.x + x1.y*x2.y + x1.z*x2.z + x1.w*x2.w;
  #pragma unroll
  for (int k = 0; k < 9; ++k)
    for (int off = 32; off; off >>= 1) v[k] += __shfl_down(v[k], off);
  __shared__ float red[4][9];
  int lane = t & 63, wv = t >> 6;
  if (!lane)
    #pragma unroll
    for (int k = 0; k < 9; ++k) red[wv][k] = v[k];
  __syncthreads();
  if (t < 9)
    atomicAdd(&xs[t], red[0][t] + red[1][t] + red[2][t] + red[3][t]);
}

// k_conv12: fused conv1(+BN1 closed form +relu, in-register) -> conv2 MFMA.
// Block = (b, 64-n slice) x all 128 o. y2t [b][n][128c] fp16 raw + BN2 stats.
__global__ __launch_bounds__(256, 4) void k_conv12(const float* __restrict__ x,
    const float* __restrict__ w1, const float* __restrict__ b1,
    const float* __restrict__ g1, const float* __restrict__ be1,
    const float* __restrict__ xs,
    const unsigned short* __restrict__ w2h, const float* __restrict__ b2,
    unsigned short* __restrict__ y2t, float* __restrict__ sum2, float* __restrict__ sq2)
{
  __shared__ unsigned short w2s[8 * 128 * 8];   // 16 KB
  __shared__ unsigned short h1s[8 * 64 * 8];    // 8 KB
  __shared__ float wc[64][4];
  __shared__ float sred[2][128][2];
  int t = threadIdx.x;
  int bi = blockIdx.x;                 // 1024 = 32 b x 32 ns
  int b = bi >> 5, ns = bi & 31;
  int n0 = ns * 64;
  int w = t >> 6, lane = t & 63;
  int ow = w & 1, nw = w >> 1;
  int quad = lane >> 4, l15 = lane & 15;

  // A: BN1 closed form -> folded conv1 coeffs
  if (t < 64) {
    float w0 = w1[t*3], w1_ = w1[t*3+1], w2_ = w1[t*3+2], bb = b1[t];
    const float invN = 1.f / 65536.f;
    float wsx = (w0*xs[0] + w1_*xs[1] + w2_*xs[2]) * invN;
    float mean = wsx + bb;
    float Ey2 = (w0*w0*xs[3] + w1_*w1_*xs[4] + w2_*w2_*xs[5]
               + 2.f*(w0*w1_*xs[6] + w0*w2_*xs[7] + w1_*w2_*xs[8])) * invN
               + 2.f*bb*wsx + bb*bb;
    float var = Ey2 - mean*mean;
    float a = g1[t] * rsqrtf(var + EPSV);
    wc[t][0] = a*w0; wc[t][1] = a*w1_; wc[t][2] = a*w2_;
    wc[t][3] = be1[t] + a*(bb - mean);
  }
  // B: stage w2 [cb][o'][8], o' = (o+cb)&127
  for (int i = 0; i < 4; ++i) {
    int idx = i * 256 + t;             // 1024 = 128 o x 8 cb
    int o = idx >> 3, cb = idx & 7;
    uint4 v = *(const uint4*)(w2h + o * 64 + cb * 8);
    int op = (o + cb) & 127;
    *(uint4*)&w2s[(cb * 128 + op) * 8] = v;
  }
  __syncthreads();                     // wc ready for C

  // C: compute h1 = relu(wc . x) for 8c x 2n per thread; pack to swizzled LDS
  {
    int cg = t >> 5, ng = t & 31;      // 8 c-groups x 32 n-pairs
    int c0 = cg * 8, nn = ng * 2;
    const float* xb = x + (size_t)b * 3 * NPT + n0 + nn;
    float2 xv0 = *(const float2*)(xb);
    float2 xv1 = *(const float2*)(xb + NPT);
    float2 xv2 = *(const float2*)(xb + 2 * NPT);
    uint4 p0, p1;
    unsigned* a0 = (unsigned*)&p0;
    unsigned* a1 = (unsigned*)&p1;
    #pragma unroll
    for (int j = 0; j < 4; ++j) {
      int c = c0 + j * 2;
      float hA0 = fmaxf(fmaf(wc[c][0], xv0.x, fmaf(wc[c][1], xv1.x, fmaf(wc[c][2], xv2.x, wc[c][3]))), 0.f);
      float hA1 = fmaxf(fmaf(wc[c][0], xv0.y, fmaf(wc[c][1], xv1.y, fmaf(wc[c][2], xv2.y, wc[c][3]))), 0.f);
      float hB0 = fmaxf(fmaf(wc[c+1][0], xv0.x, fmaf(wc[c+1][1], xv1.x, fmaf(wc[c+1][2], xv2.x, wc[c+1][3]))), 0.f);
      float hB1 = fmaxf(fmaf(wc[c+1][0], xv0.y, fmaf(wc[c+1][1], xv1.y, fmaf(wc[c+1][2], xv2.y, wc[c+1][3]))), 0.f);
      a0[j] = (unsigned)f16r(hA0) | ((unsigned)f16r(hB0) << 16);
      a1[j] = (unsigned)f16r(hA1) | ((unsigned)f16r(hB1) << 16);
    }
    *(uint4*)&h1s[(cg * 64 + SW(nn, cg)) * 8] = p0;
    *(uint4*)&h1s[(cg * 64 + SW(nn + 1, cg)) * 8] = p1;
  }
  __syncthreads();

  half8 af[4][2];
  #pragma unroll
  for (int ti = 0; ti < 4; ++ti)
    #pragma unroll
    for (int s = 0; s < 2; ++s) {
      int cb = s * 4 + quad;
      int o = ow * 64 + ti * 16 + l15;
      int op = (o + cb) & 127;
      af[ti][s] = *(const half8*)&w2s[(cb * 128 + op) * 8];
    }
  float breg[4][4];
  #pragma unroll
  for (int ti = 0; ti < 4; ++ti)
    #pragma unroll
    for (int r = 0; r < 4; ++r)
      breg[ti][r] = b2[ow * 64 + ti * 16 + quad * 4 + r];

  floatx4 acc[4][2];
  #pragma unroll
  for (int ti = 0; ti < 4; ++ti)
    #pragma unroll
    for (int nt = 0; nt < 2; ++nt) acc[ti][nt] = (floatx4){0.f, 0.f, 0.f, 0.f};
  #pragma unroll
  for (int s = 0; s < 2; ++s) {
    int cb = s * 4 + quad;
    half8 bf[2];
    #pragma unroll
    for (int nt = 0; nt < 2; ++nt) {
      int n = nw * 32 + nt * 16 + l15;
      bf[nt] = *(const half8*)&h1s[(cb * 64 + SW(n, cb)) * 8];
    }
    #pragma unroll
    for (int ti = 0; ti < 4; ++ti) {
      acc[ti][0] = __builtin_amdgcn_mfma_f32_16x16x32_f16(af[ti][s], bf[0], acc[ti][0], 0, 0, 0);
      acc[ti][1] = __builtin_amdgcn_mfma_f32_16x16x32_f16(af[ti][s], bf[1], acc[ti][1], 0, 0, 0);
    }
  }

  // epilogue: y2t[b][n][c] = fp16(acc + b2) via 8B stores; exact fp32 stats
  float sm[4][4], sq[4][4];
  #pragma unroll
  for (int ti = 0; ti < 4; ++ti)
    #pragma unroll
    for (int r = 0; r < 4; ++r) { sm[ti][r] = 0.f; sq[ti][r] = 0.f; }
  #pragma unroll
  for (int ti = 0; ti < 4; ++ti) {
    int o = ow * 64 + ti * 16 + quad * 4;
    #pragma unroll
    for (int nt = 0; nt < 2; ++nt) {
      int n = n0 + nw * 32 + nt * 16 + l15;
      float v0 = acc[ti][nt][0] + breg[ti][0];
      float v1 = acc[ti][nt][1] + breg[ti][1];
      float v2 = acc[ti][nt][2] + breg[ti][2];
      float v3 = acc[ti][nt][3] + breg[ti][3];
      ushort4 st;
      st.x = f16r(v0); st.y = f16r(v1); st.z = f16r(v2); st.w = f16r(v3);
      *(ushort4*)(y2t + ((size_t)b * NPT + n) * C2 + o) = st;
      sm[ti][0] += v0; sq[ti][0] = fmaf(v0, v0, sq[ti][0]);
      sm[ti][1] += v1; sq[ti][1] = fmaf(v1, v1, sq[ti][1]);
      sm[ti][2] += v2; sq[ti][2] = fmaf(v2, v2, sq[ti][2]);
      sm[ti][3] += v3; sq[ti][3] = fmaf(v3, v3, sq[ti][3]);
    }
  }
  #pragma unroll
  for (int ti = 0; ti < 4; ++ti)
    #pragma unroll
    for (int r = 0; r < 4; ++r) {
      #pragma unroll
      for (int m = 1; m < 16; m <<= 1) {
        sm[ti][r] += __shfl_xor(sm[ti][r], m, 16);
        sq[ti][r] += __shfl_xor(sq[ti][r], m, 16);
      }
    }
  if (l15 == 0) {
    #pragma unroll
    for (int ti = 0; ti < 4; ++ti)
      #pragma unroll
      for (int r = 0; r < 4; ++r) {
        int oloc = ow * 64 + ti * 16 + quad * 4 + r;
        sred[nw][oloc][0] = sm[ti][r];
        sred[nw][oloc][1] = sq[ti][r];
      }
  }
  __syncthreads();
  if (t < 128) {
    atomicAdd(&sum2[t], sred[0][t][0] + sred[1][t][0]);
    atomicAdd(&sq2[t],  sred[0][t][1] + sred[1][t][1]);
  }
}

// BN2+relu elementwise (linear, same layout): y2t -> h2t, fp32 BN math.
__global__ __launch_bounds__(256) void k_bnrelu2(const unsigned short* __restrict__ y2t,
    const float* __restrict__ sum2, const float* __restrict__ sq2,
    const float* __restrict__ g2, const float* __restrict__ be2,
    unsigned short* __restrict__ h2t)
{
  __shared__ float bn[128][2];
  int t = threadIdx.x;
  if (t < 128) {
    float m = sum2[t] * (1.f / 65536.f);
    float v = fmaf(-m, m, sq2[t] * (1.f / 65536.f));
    float a = g2[t] * rsqrtf(v + EPSV);
    bn[t][0] = a; bn[t][1] = fmaf(-a, m, be2[t]);
  }
  __syncthreads();
  size_t base = ((size_t)blockIdx.x * 256 + t) * 32;   // 32 halves/thread
  int c0 = (int)(base & 127);
  #pragma unroll
  for (int k = 0; k < 4; ++k) {
    ushort4 u0 = *(const ushort4*)(y2t + base + k * 8);
    ushort4 u1 = *(const ushort4*)(y2t + base + k * 8 + 4);
    int c = c0 + k * 8;
    float h0 = fmaxf(fmaf(bn[c+0][0], h2f(u0.x), bn[c+0][1]), 0.f);
    float h1 = fmaxf(fmaf(bn[c+1][0], h2f(u0.y), bn[c+1][1]), 0.f);
    float h2 = fmaxf(fmaf(bn[c+2][0], h2f(u0.z), bn[c+2][1]), 0.f);
    float h3 = fmaxf(fmaf(bn[c+3][0], h2f(u0.w), bn[c+3][1]), 0.f);
    float h4 = fmaxf(fmaf(bn[c+4][0], h2f(u1.x), bn[c+4][1]), 0.f);
    float h5 = fmaxf(fmaf(bn[c+5][0], h2f(u1.y), bn[c+5][1]), 0.f);
    float h6 = fmaxf(fmaf(bn[c+6][0], h2f(u1.z), bn[c+6][1]), 0.f);
    float h7 = fmaxf(fmaf(bn[c+7][0], h2f(u1.w), bn[c+7][1]), 0.f);
    uint4 pk;
    pk.x = (unsigned)f16r(h0) | ((unsigned)f16r(h1) << 16);
    pk.y = (unsigned)f16r(h2) | ((unsigned)f16r(h3) << 16);
    pk.z = (unsigned)f16r(h4) | ((unsigned)f16r(h5) << 16);
    pk.w = (unsigned)f16r(h6) | ((unsigned)f16r(h7) << 16);
    *(uint4*)(h2t + base + k * 8) = pk;
  }
}

// conv3 MFMA: block = (ot, b, n-half); 16 chunks of 64 n.
// DOUBLE-BUFFERED LDS + register prefetch: one barrier per chunk, next
// chunk's global loads issued during MFMA phase. Stats on RAW acc.
__global__ __launch_bounds__(256, 2) void k_conv3(const unsigned short* __restrict__ h2t,
    const unsigned short* __restrict__ w3h, const float* __restrict__ b3,
    float* __restrict__ mxb, float* __restrict__ mnb,
    float* __restrict__ sum3, float* __restrict__ sq3)
{
  __shared__ unsigned short w3s[16 * 128 * 8];  // 32 KB
  __shared__ unsigned short h2s[2][16 * 64 * 8];// 2 x 16 KB
  __shared__ float sred[2][128][4];             // 4 KB
  int t = threadIdx.x;
  int bi = blockIdx.x;                 // 512: bi = ot*64 + b*2 + ns
  int ot_blk = bi >> 6;
  int b  = (bi >> 1) & 31;
  int ns = bi & 1;
  int o0 = ot_blk * 128;
  int n_base = ns * 1024;
  int w = t >> 6, lane = t & 63;
  int ow = w & 1, nw = w >> 1;
  int quad = lane >> 4, l15 = lane & 15;

  for (int i = 0; i < 8; ++i) {
    int idx = i * 256 + t;             // 2048 = 128 o x 16 cb
    int o = idx >> 4, cb = idx & 15;
    uint4 v = *(const uint4*)(w3h + (size_t)(o0 + o) * 128 + cb * 8);
    int op = (o + cb) & 127;
    *(uint4*)&w3s[(cb * 128 + op) * 8] = v;
  }
  __syncthreads();

  half8 af[4][4];
  #pragma unroll
  for (int ti = 0; ti < 4; ++ti)
    #pragma unroll
    for (int s = 0; s < 4; ++s) {
      int cb = s * 4 + quad;
      int o = ow * 64 + ti * 16 + l15;
      int op = (o + cb) & 127;
      af[ti][s] = *(const half8*)&w3s[(cb * 128 + op) * 8];
    }

  float mx[4][4], mn[4][4], sm[4][4], sq[4][4];
  #pragma unroll
  for (int ti = 0; ti < 4; ++ti)
    #pragma unroll
    for (int r = 0; r < 4; ++r) {
      mx[ti][r] = -3.4e38f; mn[ti][r] = 3.4e38f; sm[ti][r] = 0.f; sq[ti][r] = 0.f;
    }

  int sn = t & 63, cq = t >> 6;        // staging map: 64 n x 4 cb-quads
  int cb0 = cq * 4;
  const unsigned short* sbase = h2t + ((size_t)b * NPT + n_base + sn) * C2 + cq * 32;
  // prologue: prefetch chunk 0 into regs
  uint4 v0 = *(const uint4*)(sbase);
  uint4 v1 = *(const uint4*)(sbase + 8);
  uint4 v2 = *(const uint4*)(sbase + 16);
  uint4 v3 = *(const uint4*)(sbase + 24);

  for (int nc = 0; nc < 16; ++nc) {
    unsigned short* buf = h2s[nc & 1];
    *(uint4*)&buf[((cb0 + 0) * 64 + SW(sn, cb0 + 0)) * 8] = v0;
    *(uint4*)&buf[((cb0 + 1) * 64 + SW(sn, cb0 + 1)) * 8] = v1;
    *(uint4*)&buf[((cb0 + 2) * 64 + SW(sn, cb0 + 2)) * 8] = v2;
    *(uint4*)&buf[((cb0 + 3) * 64 + SW(sn, cb0 + 3)) * 8] = v3;
    // issue prefetch for next chunk (clamped on last iter; completes during MFMA)
    {
      int nc1 = nc < 15 ? nc + 1 : 15;
      const unsigned short* src = sbase + (size_t)nc1 * 64 * C2;
      v0 = *(const uint4*)(src);
      v1 = *(const uint4*)(src + 8);
      v2 = *(const uint4*)(src + 16);
      v3 = *(const uint4*)(src + 24);
    }
    __syncthreads();

    const unsigned short* rbuf = h2s[nc & 1];
    floatx4 acc[4][2];
    #pragma unroll
    for (int ti = 0; ti < 4; ++ti)
      #pragma unroll
      for (int nt = 0; nt < 2; ++nt) acc[ti][nt] = (floatx4){0.f, 0.f, 0.f, 0.f};
    #pragma unroll
    for (int s = 0; s < 4; ++s) {
      int cb = s * 4 + quad;
      half8 bf[2];
      #pragma unroll
      for (int nt = 0; nt < 2; ++nt) {
        int n = nw * 32 + nt * 16 + l15;
        bf[nt] = *(const half8*)&rbuf[(cb * 64 + SW(n, cb)) * 8];
      }
      #pragma unroll
      for (int ti = 0; ti < 4; ++ti) {
        acc[ti][0] = __builtin_amdgcn_mfma_f32_16x16x32_f16(af[ti][s], bf[0], acc[ti][0], 0, 0, 0);
        acc[ti][1] = __builtin_amdgcn_mfma_f32_16x16x32_f16(af[ti][s], bf[1], acc[ti][1], 0, 0, 0);
      }
    }
    #pragma unroll
    for (int ti = 0; ti < 4; ++ti)
      #pragma unroll
      for (int nt = 0; nt < 2; ++nt)
        #pragma unroll
        for (int r = 0; r < 4; ++r) {
          float v = acc[ti][nt][r];
          mx[ti][r] = fmaxf(mx[ti][r], v);
          mn[ti][r] = fminf(mn[ti][r], v);
          sm[ti][r] += v;
          sq[ti][r] = fmaf(v, v, sq[ti][r]);
        }
  }

  #pragma unroll
  for (int ti = 0; ti < 4; ++ti)
    #pragma unroll
    for (int r = 0; r < 4; ++r) {
      #pragma unroll
      for (int m = 1; m < 16; m <<= 1) {
        mx[ti][r] = fmaxf(mx[ti][r], __shfl_xor(mx[ti][r], m, 16));
        mn[ti][r] = fminf(mn[ti][r], __shfl_xor(mn[ti][r], m, 16));
        sm[ti][r] += __shfl_xor(sm[ti][r], m, 16);
        sq[ti][r] += __shfl_xor(sq[ti][r], m, 16);
      }
    }
  if (l15 == 0) {
    #pragma unroll
    for (int ti = 0; ti < 4; ++ti)
      #pragma unroll
      for (int r = 0; r < 4; ++r) {
        int oloc = ow * 64 + ti * 16 + quad * 4 + r;
        sred[nw][oloc][0] = mx[ti][r];
        sred[nw][oloc][1] = mn[ti][r];
        sred[nw][oloc][2] = sm[ti][r];
        sred[nw][oloc][3] = sq[ti][r];
      }
  }
  __syncthreads();
  if (t < 128) {
    int o = o0 + t;
    float bo = b3[o];
    float fmx = fmaxf(sred[0][t][0], sred[1][t][0]) + bo;
    float fmn = fminf(sred[0][t][1], sred[1][t][1]) + bo;
    float smr = sred[0][t][2] + sred[1][t][2];
    float sqr = sred[0][t][3] + sred[1][t][3];
    mxb[ns * 32768 + b * 1024 + o] = fmx;
    mnb[ns * 32768 + b * 1024 + o] = fmn;
    atomicAdd(&sum3[o], fmaf(1024.f, bo, smr));
    atomicAdd(&sq3[o],  fmaf(1024.f * bo, bo, fmaf(2.f * bo, smr, sqr)));
  }
}

// FC1 + pooled fused: pool slice derived inline from mxb/mnb/sum3/sq3 (BN3).
// grid (16 f-tiles of 32, 8 k-chunks of 128); unroll capped at 4.
__global__ __launch_bounds__(256) void k_fc1(const float* __restrict__ mxb,
    const float* __restrict__ mnb, const float* __restrict__ sum3,
    const float* __restrict__ sq3, const float* __restrict__ g3,
    const float* __restrict__ be3, const float* __restrict__ wf1,
    const float* __restrict__ bf1, float* __restrict__ f1r)
{
  __shared__ float ins[32 * 128];   // 16 KB
  __shared__ float bnA[128], bnS[128];
  int t = threadIdx.x;
  int f0 = blockIdx.x * 32;
  int k0 = blockIdx.y * 128;
  if (t < 128) {
    int c = k0 + t;
    float m = sum3[c] * (1.f / 65536.f);
    float v = fmaf(-m, m, sq3[c] * (1.f / 65536.f));
    float a = g3[c] * rsqrtf(v + EPSV);
    bnA[t] = a; bnS[t] = fmaf(-a, m, be3[c]);
  }
  __syncthreads();
  #pragma unroll
  for (int i = 0; i < 4; ++i) {
    int idx = i * 256 + t;
    int b = idx >> 5, k4 = idx & 31;
    float4 mxv = *(const float4*)(mxb + (size_t)b * 1024 + k0 + k4 * 4);
    float4 mx1 = *(const float4*)(mxb + 32768 + (size_t)b * 1024 + k0 + k4 * 4);
    float4 mnv = *(const float4*)(mnb + (size_t)b * 1024 + k0 + k4 * 4);
    float4 mn1 = *(const float4*)(mnb + 32768 + (size_t)b * 1024 + k0 + k4 * 4);
    float4 a = *(const float4*)&bnA[k4 * 4];
    float4 s = *(const float4*)&bnS[k4 * 4];
    float4 r;
    r.x = fmaf(a.x, (a.x >= 0.f ? fmaxf(mxv.x, mx1.x) : fminf(mnv.x, mn1.x)), s.x);
    r.y = fmaf(a.y, (a.y >= 0.f ? fmaxf(mxv.y, mx1.y) : fminf(mnv.y, mn1.y)), s.y);
    r.z = fmaf(a.z, (a.z >= 0.f ? fmaxf(mxv.z, mx1.z) : fminf(mnv.z, mn1.z)), s.z);
    r.w = fmaf(a.w, (a.w >= 0.f ? fmaxf(mxv.w, mx1.w) : fminf(mnv.w, mn1.w)), s.w);
    *(float4*)&ins[b * 128 + k4 * 4] = r;
  }
  __syncthreads();
  int f = t & 31, bq = t >> 5;
  int bl = bq * 4;
  const float4* wr = (const float4*)(wf1 + (size_t)(f0 + f) * 1024 + k0);
  float acc0 = 0.f, acc1 = 0.f, acc2 = 0.f, acc3 = 0.f;
  #pragma unroll 4
  for (int k4 = 0; k4 < 32; ++k4) {
    float4 wv = wr[k4];
    float4 i0 = *(const float4*)&ins[(bl + 0) * 128 + k4 * 4];
    float4 i1 = *(const float4*)&ins[(bl + 1) * 128 + k4 * 4];
    float4 i2 = *(const float4*)&ins[(bl + 2) * 128 + k4 * 4];
    float4 i3 = *(const float4*)&ins[(bl + 3) * 128 + k4 * 4];
    acc0 = fmaf(wv.x, i0.x, fmaf(wv.y, i0.y, fmaf(wv.z, i0.z, fmaf(wv.w, i0.w, acc0))));
    acc1 = fmaf(wv.x, i1.x, fmaf(wv.y, i1.y, fmaf(wv.z, i1.z, fmaf(wv.w, i1.w, acc1))));
    acc2 = fmaf(wv.x, i2.x, fmaf(wv.y, i2.y, fmaf(wv.z, i2.z, fmaf(wv.w, i2.w, acc2))));
    acc3 = fmaf(wv.x, i3.x, fmaf(wv.y, i3.y, fmaf(wv.z, i3.z, fmaf(wv.w, i3.w, acc3))));
  }
  float bs = (blockIdx.y == 0) ? bf1[f0 + f] : 0.f;
  atomicAdd(&f1r[(size_t)(bl + 0) * 512 + f0 + f], acc0 + bs);
  atomicAdd(&f1r[(size_t)(bl + 1) * 512 + f0 + f], acc1 + bs);
  atomicAdd(&f1r[(size_t)(bl + 2) * 512 + f0 + f], acc2 + bs);
  atomicAdd(&f1r[(size_t)(bl + 3) * 512 + f0 + f], acc3 + bs);
}

// FC2: BN1d(f1) stats inline per k-chunk; unroll capped at 4.
__global__ __launch_bounds__(256) void k_fc2(const float* __restrict__ f1r,
    const float* __restrict__ wf2, const float* __restrict__ bf2,
    const float* __restrict__ gf1, const float* __restrict__ bef1,
    float* __restrict__ f2r)
{
  __shared__ float ins[32 * 64];    // 8 KB
  __shared__ float bnA[64], bnS[64];
  int t = threadIdx.x;
  int f0 = blockIdx.x * 32;
  int k0 = blockIdx.y * 64;
  #pragma unroll
  for (int i = 0; i < 2; ++i) {
    int idx = i * 256 + t;
    int b = idx >> 4, k4 = idx & 15;
    *(float4*)&ins[b * 64 + k4 * 4] = *(const float4*)(f1r + (size_t)b * 512 + k0 + k4 * 4);
  }
  __syncthreads();
  if (t < 64) {
    float s = 0.f, q = 0.f;
    #pragma unroll
    for (int b = 0; b < 32; ++b) {
      float xx = ins[b * 64 + t];
      s += xx; q = fmaf(xx, xx, q);
    }
    float m = s * (1.f / 32.f);
    float v = fmaf(-m, m, q * (1.f / 32.f));
    float a = gf1[k0 + t] * rsqrtf(v + EPSV);
    bnA[t] = a; bnS[t] = fmaf(-a, m, bef1[k0 + t]);
  }
  __syncthreads();
  #pragma unroll
  for (int i = 0; i < 2; ++i) {
    int idx = i * 256 + t;
    int b = idx >> 4, k4 = idx & 15;
    float4 v = *(const float4*)&ins[b * 64 + k4 * 4];
    v.x = fmaxf(fmaf(bnA[k4*4+0], v.x, bnS[k4*4+0]), 0.f);
    v.y = fmaxf(fmaf(bnA[k4*4+1], v.y, bnS[k4*4+1]), 0.f);
    v.z = fmaxf(fmaf(bnA[k4*4+2], v.z, bnS[k4*4+2]), 0.f);
    v.w = fmaxf(fmaf(bnA[k4*4+3], v.w, bnS[k4*4+3]), 0.f);
    *(float4*)&ins[b * 64 + k4 * 4] = v;
  }
  __syncthreads();
  int f = t & 31, bq = t >> 5;
  int bl = bq * 4;
  const float4* wr = (const float4*)(wf2 + (size_t)(f0 + f) * 512 + k0);
  float acc0 = 0.f, acc1 = 0.f, acc2 = 0.f, acc3 = 0.f;
  #pragma unroll 4
  for (int k4 = 0; k4 < 16; ++k4) {
    float4 wv = wr[k4];
    float4 i0 = *(const float4*)&ins[(bl + 0) * 64 + k4 * 4];
    float4 i1 = *(const float4*)&ins[(bl + 1) * 64 + k4 * 4];
    float4 i2 = *(const float4*)&ins[(bl + 2) * 64 + k4 * 4];
    float4 i3 = *(const float4*)&ins[(bl + 3) * 64 + k4 * 4];
    acc0 = fmaf(wv.x, i0.x, fmaf(wv.y, i0.y, fmaf(wv.z, i0.z, fmaf(wv.w, i0.w, acc0))));
    acc1 = fmaf(wv.x, i1.x, fmaf(wv.y, i1.y, fmaf(wv.z, i1.z, fmaf(wv.w, i1.w, acc1))));
    acc2 = fmaf(wv.x, i2.x, fmaf(wv.y, i2.y, fmaf(wv.z, i2.z, fmaf(wv.w, i2.w, acc2))));
    acc3 = fmaf(wv.x, i3.x, fmaf(wv.y, i3.y, fmaf(wv.z, i3.z, fmaf(wv.w, i3.w, acc3))));
  }
  float bs = (blockIdx.y == 0) ? bf2[f0 + f] : 0.f;
  atomicAdd(&f2r[(size_t)(bl + 0) * 256 + f0 + f], acc0 + bs);
  atomicAdd(&f2r[(size_t)(bl + 1) * 256 + f0 + f], acc1 + bs);
  atomicAdd(&f2r[(size_t)(bl + 2) * 256 + f0 + f], acc2 + bs);
  atomicAdd(&f2r[(size_t)(bl + 3) * 256 + f0 + f], acc3 + bs);
}

// Head: BN-F2 stats inline; p = relu(BN(f2r)) @ wp.T + bp; Horn SO(3) -> [B,4,4].
__global__ __launch_bounds__(384) void k_head(const float* __restrict__ f2r,
    const float* __restrict__ gf2, const float* __restrict__ bef2,
    const float* __restrict__ wp, const float* __restrict__ bp,
    float* __restrict__ out)
{
  __shared__ float pS[32 * 12];
  __shared__ float bnf[256][2];
  int t = threadIdx.x;
  if (t < 256) {
    float s = 0.f, q = 0.f;
    #pragma unroll
    for (int b = 0; b < 32; ++b) {
      float xx = f2r[b * 256 + t];
      s += xx; q = fmaf(xx, xx, q);
    }
    float m = s * (1.f / 32.f);
    float v = fmaf(-m, m, q * (1.f / 32.f));
    float a = gf2[t] * rsqrtf(v + EPSV);
    bnf[t][0] = a; bnf[t][1] = fmaf(-a, m, bef2[t]);
  }
  __syncthreads();
  {
    int b = t / 12, j = t % 12;
    const float* w = wp + j * 256;
    const float* fr = f2r + b * 256;
    float acc = bp[j];
    #pragma unroll 8
    for (int c = 0; c < 256; ++c) {
      float h = fmaxf(fmaf(bnf[c][0], fr[c], bnf[c][1]), 0.f);
      acc = fmaf(w[c], h, acc);
    }
    pS[t] = acc;
  }
  __syncthreads();
  if (t < 32) {
    const float* p = &pS[t * 12];
    float m00=p[0],m01=p[1],m02=p[2],m10=p[3],m11=p[4],m12=p[5],m20=p[6],m21=p[7],m22=p[8];
    float P[4][4];
    P[0][0]=m00+m11+m22; P[0][1]=m21-m12;     P[0][2]=m02-m20;     P[0][3]=m10-m01;
    P[1][1]=m00-m11-m22; P[1][2]=m01+m10;     P[1][3]=m02+m20;
    P[2][2]=m11-m00-m22; P[2][3]=m12+m21;
    P[3][3]=m22-m00-m11;
    P[1][0]=P[0][1]; P[2][0]=P[0][2]; P[3][0]=P[0][3];
    P[2][1]=P[1][2]; P[3][1]=P[1][3]; P[3][2]=P[2][3];
    float fn = sqrtf(m00*m00+m01*m01+m02*m02+m10*m10+m11*m11+m12*m12+m20*m20+m21*m21+m22*m22);
    float inv = 1.f / (2.f * fn + 1e-30f);
    #pragma unroll
    for (int i = 0; i < 4; ++i)
      #pragma unroll
      for (int j = 0; j < 4; ++j) P[i][j] *= inv;
    P[0][0] += 1.f; P[1][1] += 1.f; P[2][2] += 1.f; P[3][3] += 1.f;
    for (int it = 0; it < 16; ++it) {
      float Q[4][4];
      #pragma unroll
      for (int i = 0; i < 4; ++i)
        #pragma unroll
        for (int j = 0; j < 4; ++j)
          Q[i][j] = P[i][0]*P[0][j] + P[i][1]*P[1][j] + P[i][2]*P[2][j] + P[i][3]*P[3][j];
      float mxa = 0.f;
      #pragma unroll
      for (int i = 0; i < 4; ++i)
        #pragma unroll
        for (int j = 0; j < 4; ++j) mxa = fmaxf(mxa, fabsf(Q[i][j]));
      float r = 1.f / mxa;
      #pragma unroll
      for (int i = 0; i < 4; ++i)
        #pragma unroll
        for (int j = 0; j < 4; ++j) P[i][j] = Q[i][j] * r;
    }
    float bestn = -1.f; int bj = 0;
    #pragma unroll
    for (int j = 0; j < 4; ++j) {
      float nn = P[0][j]*P[0][j] + P[1][j]*P[1][j] + P[2][j]*P[2][j] + P[3][j]*P[3][j];
      if (nn > bestn) { bestn = nn; bj = j; }
    }
    float qw = P[0][bj], qx = P[1][bj], qy = P[2][bj], qz = P[3][bj];
    float qn = rsqrtf(qw*qw + qx*qx + qy*qy + qz*qz);
    qw *= qn; qx *= qn; qy *= qn; qz *= qn;
    float* ob = out + t * 16;
    ob[0]  = 1.f - 2.f*(qy*qy + qz*qz);
    ob[1]  = 2.f*(qx*qy - qw*qz);
    ob[2]  = 2.f*(qx*qz + qw*qy);
    ob[3]  = p[9];
    ob[4]  = 2.f*(qx*qy + qw*qz);
    ob[5]  = 1.f - 2.f*(qx*qx + qz*qz);
    ob[6]  = 2.f*(qy*qz - qw*qx);
    ob[7]  = p[10];
    ob[8]  = 2.f*(qx*qz - qw*qy);
    ob[9]  = 2.f*(qy*qz + qw*qx);
    ob[10] = 1.f - 2.f*(qx*qx + qy*qy);
    ob[11] = p[11];
    ob[12] = 0.f; ob[13] = 0.f; ob[14] = 0.f; ob[15] = 1.f;
  }
}

extern "C" void kernel_launch(void* const* d_in, const int* in_sizes, int n_in,
                              void* d_out, int out_size, void* d_ws, size_t ws_size,
                              hipStream_t stream)
{
  (void)in_sizes; (void)n_in; (void)out_size;
  if (ws_size < (size_t)WS_FLOATS * sizeof(float)) return;
  const float* x   = (const float*)d_in[0];
  const float* w1  = (const float*)d_in[1];
  const float* b1  = (const float*)d_in[2];
  const float* g1  = (const float*)d_in[3];
  const float* be1 = (const float*)d_in[4];
  const float* w2  = (const float*)d_in[5];
  const float* b2  = (const float*)d_in[6];
  const float* g2  = (const float*)d_in[7];
  const float* be2 = (const float*)d_in[8];
  const float* w3  = (const float*)d_in[9];
  const float* b3  = (const float*)d_in[10];
  const float* g3  = (const float*)d_in[11];
  const float* be3 = (const float*)d_in[12];
  const float* wf1 = (const float*)d_in[13];
  const float* bf1 = (const float*)d_in[14];
  const float* gf1 = (const float*)d_in[15];
  const float* bef1= (const float*)d_in[16];
  const float* wf2 = (const float*)d_in[17];
  const float* bf2 = (const float*)d_in[18];
  const float* gf2 = (const float*)d_in[19];
  const float* bef2= (const float*)d_in[20];
  const float* wp  = (const float*)d_in[21];
  const float* bp  = (const float*)d_in[22];
  float* ws  = (float*)d_ws;
  float* out = (float*)d_out;
  unsigned short* y2t = (unsigned short*)(ws + OFF_Y2T);
  unsigned short* h2t = (unsigned short*)(ws + OFF_H2T);
  unsigned short* w3h = (unsigned short*)(ws + OFF_W3H);
  unsigned short* w2h = (unsigned short*)(ws + OFF_W2H);

  hipMemsetAsync((void*)(ws + OFF_Z), 0, ZN * sizeof(float), stream);
  k_prep<<<200, 256, 0, stream>>>(w3, w2, w3h, w2h, x, ws + OFF_XS);
  k_conv12<<<1024, 256, 0, stream>>>(x, w1, b1, g1, be1, ws + OFF_XS,
                                     w2h, b2, y2t, ws + OFF_SUM2, ws + OFF_SQ2);
  k_bnrelu2<<<1024, 256, 0, stream>>>(y2t, ws + OFF_SUM2, ws + OFF_SQ2, g2, be2, h2t);
  k_conv3<<<512, 256, 0, stream>>>(h2t, w3h, b3, ws + OFF_MX, ws + OFF_MN,
                                   ws + OFF_SUM3, ws + OFF_SQ3);
  k_fc1<<<dim3(16, 8), 256, 0, stream>>>(ws + OFF_MX, ws + OFF_MN, ws + OFF_SUM3,
                                         ws + OFF_SQ3, g3, be3, wf1, bf1, ws + OFF_F1R);
  k_fc2<<<dim3(8, 8), 256, 0, stream>>>(ws + OFF_F1R, wf2, bf2, gf1, bef1, ws + OFF_F2R);
  k_head<<<1, 384, 0, stream>>>(ws + OFF_F2R, gf2, bef2, wp, bp, out);
}